// Round 14
// baseline (1224.483 us; speedup 1.0000x reference)
//
#include <hip/hip_runtime.h>
#include <math.h>

#define BB 4
#define TT 2048
#define DD 1024
#define HH 128
#define EPSF 1e-6f
#define BT (BB*TT)   // 8192
#define CC 128       // chunk length
#define NCH (TT/CC)  // 16 chunks per batch
#define NI (TT/2)    // 1024 double-steps
#define BAR_OFF ((size_t)20 << 20)   // barrier counter byte offset in d_out

typedef float f32x2 __attribute__((ext_vector_type(2)));

// 8-lane butterfly sum, pure DPP/VALU (no DS pipe)
__device__ __forceinline__ float red8(float x) {
    x += __int_as_float(__builtin_amdgcn_mov_dpp(__float_as_int(x), 0xB1,  0xF, 0xF, true));
    x += __int_as_float(__builtin_amdgcn_mov_dpp(__float_as_int(x), 0x4E,  0xF, 0xF, true));
    x += __int_as_float(__builtin_amdgcn_mov_dpp(__float_as_int(x), 0x141, 0xF, 0xF, true));
    return x;
}
// 16-lane butterfly sum (adds ROW_MIRROR)
__device__ __forceinline__ float red16(float x) {
    x = red8(x);
    x += __int_as_float(__builtin_amdgcn_mov_dpp(__float_as_int(x), 0x140, 0xF, 0xF, true));
    return x;
}

// Device-scope grid barrier for a co-resident 256-block grid.
// Release: threadfence (flush to device scope) + syncthreads, then tid0
// bumps the counter. Acquire: poll to target, then threadfence to
// invalidate stale cached lines. Counter zeroed per launch by memset.
__device__ __forceinline__ void gridbar(int* bar, int target) {
    __threadfence();
    __syncthreads();
    if (threadIdx.x == 0) {
        atomicAdd(bar, 1);
        while (atomicAdd(bar, 0) < target)
            __builtin_amdgcn_s_sleep(8);
    }
    __syncthreads();
    __threadfence();
}

// ---------------------------------------------------------------------------
// 512-thread projection tile (worker path of fused kernel, v12-verified):
// P[row0..row0+64][0..128) = x @ W^T + bias. mode 0 plain; mode 2 s=q.k.
// ---------------------------------------------------------------------------
__device__ __forceinline__ void proj512(
    const float* __restrict__ x, const float* __restrict__ W,
    const float* __restrict__ bias, float* __restrict__ P,
    int row0, int mode, float* __restrict__ aux,
    const float* __restrict__ Kmat)
{
    __shared__ float xT[32][68];
    __shared__ float wT[32][132];

    const int tid = threadIdx.x;
    const int tx = tid & 15;
    const int ty = tid >> 4;       // 0..31, rows ty*2 .. +2

    float acc[2][8];
    #pragma unroll
    for (int i = 0; i < 2; i++)
        #pragma unroll
        for (int j = 0; j < 8; j++) acc[i][j] = 0.f;

    for (int k0 = 0; k0 < DD; k0 += 32) {
        {   int r = tid >> 3, cg = tid & 7;
            float4 v = *(const float4*)(x + (size_t)(row0 + r) * DD + k0 + cg * 4);
            xT[cg*4+0][r] = v.x; xT[cg*4+1][r] = v.y;
            xT[cg*4+2][r] = v.z; xT[cg*4+3][r] = v.w;
        }
        #pragma unroll
        for (int l = 0; l < 2; l++) {
            int f = tid + l * 512;
            int h = f >> 3, cg = f & 7;
            float4 v = *(const float4*)(W + (size_t)h * DD + k0 + cg * 4);
            wT[cg*4+0][h] = v.x; wT[cg*4+1][h] = v.y;
            wT[cg*4+2][h] = v.z; wT[cg*4+3][h] = v.w;
        }
        __syncthreads();
        #pragma unroll
        for (int kk = 0; kk < 32; kk++) {
            float2 xv = *(const float2*)&xT[kk][ty * 2];
            float4 w0 = *(const float4*)&wT[kk][tx * 8];
            float4 w1 = *(const float4*)&wT[kk][tx * 8 + 4];
            float xa[2] = {xv.x, xv.y};
            float wa[8] = {w0.x, w0.y, w0.z, w0.w, w1.x, w1.y, w1.z, w1.w};
            #pragma unroll
            for (int i = 0; i < 2; i++)
                #pragma unroll
                for (int j = 0; j < 8; j++)
                    acc[i][j] += xa[i] * wa[j];
        }
        __syncthreads();
    }

    #pragma unroll
    for (int i = 0; i < 2; i++) {
        int row = row0 + ty * 2 + i;
        #pragma unroll
        for (int j = 0; j < 8; j++) acc[i][j] += bias[tx * 8 + j];
        float4 o0 = {acc[i][0], acc[i][1], acc[i][2], acc[i][3]};
        float4 o1 = {acc[i][4], acc[i][5], acc[i][6], acc[i][7]};
        *(float4*)(P + (size_t)row * HH + tx * 8)     = o0;
        *(float4*)(P + (size_t)row * HH + tx * 8 + 4) = o1;
    }

    if (mode == 2) {                 // s = q . k
        #pragma unroll
        for (int i = 0; i < 2; i++) {
            int row = row0 + ty * 2 + i;
            float4 ka = *(const float4*)(Kmat + (size_t)row * HH + tx * 8);
            float4 kb = *(const float4*)(Kmat + (size_t)row * HH + tx * 8 + 4);
            float p = acc[i][0]*ka.x + acc[i][1]*ka.y + acc[i][2]*ka.z + acc[i][3]*ka.w
                    + acc[i][4]*kb.x + acc[i][5]*kb.y + acc[i][6]*kb.z + acc[i][7]*kb.w;
            p = red16(p);
            if (tx == 0) aux[row] = p;
        }
    }
}

// ---------------------------------------------------------------------------
// K projection + rn epilogue, FULL-GPU: 256 blocks x 256 threads (v14).
// ---------------------------------------------------------------------------
__global__ __launch_bounds__(256) void projk_kernel(
    const float* __restrict__ x, const float* __restrict__ Wk,
    const float* __restrict__ bk, float* __restrict__ K,
    float* __restrict__ rn)
{
    const int row0 = blockIdx.x * 32;

    __shared__ float xT[32][36];
    __shared__ float wT[32][132];

    const int tid = threadIdx.x;
    const int tx = tid & 15;
    const int ty = tid >> 4;       // 0..15, rows ty*2..+2

    float acc[2][8];
    #pragma unroll
    for (int i = 0; i < 2; i++)
        #pragma unroll
        for (int j = 0; j < 8; j++) acc[i][j] = 0.f;

    for (int k0 = 0; k0 < DD; k0 += 32) {
        {   int r = tid >> 3, cg = tid & 7;
            float4 v = *(const float4*)(x + (size_t)(row0 + r) * DD + k0 + cg * 4);
            xT[cg*4+0][r] = v.x; xT[cg*4+1][r] = v.y;
            xT[cg*4+2][r] = v.z; xT[cg*4+3][r] = v.w;
        }
        #pragma unroll
        for (int l = 0; l < 4; l++) {
            int f = tid + l * 256;
            int h = f >> 3, cg = f & 7;
            float4 v = *(const float4*)(Wk + (size_t)h * DD + k0 + cg * 4);
            wT[cg*4+0][h] = v.x; wT[cg*4+1][h] = v.y;
            wT[cg*4+2][h] = v.z; wT[cg*4+3][h] = v.w;
        }
        __syncthreads();
        #pragma unroll
        for (int kk = 0; kk < 32; kk++) {
            float2 xv = *(const float2*)&xT[kk][ty * 2];
            float4 w0 = *(const float4*)&wT[kk][tx * 8];
            float4 w1 = *(const float4*)&wT[kk][tx * 8 + 4];
            float xa[2] = {xv.x, xv.y};
            float wa[8] = {w0.x, w0.y, w0.z, w0.w, w1.x, w1.y, w1.z, w1.w};
            #pragma unroll
            for (int i = 0; i < 2; i++)
                #pragma unroll
                for (int j = 0; j < 8; j++)
                    acc[i][j] += xa[i] * wa[j];
        }
        __syncthreads();
    }

    #pragma unroll
    for (int i = 0; i < 2; i++) {
        int row = row0 + ty * 2 + i;
        #pragma unroll
        for (int j = 0; j < 8; j++) acc[i][j] += bk[tx * 8 + j];
        float4 o0 = {acc[i][0], acc[i][1], acc[i][2], acc[i][3]};
        float4 o1 = {acc[i][4], acc[i][5], acc[i][6], acc[i][7]};
        *(float4*)(K + (size_t)row * HH + tx * 8)     = o0;
        *(float4*)(K + (size_t)row * HH + tx * 8 + 4) = o1;
        float p = 0.f;
        #pragma unroll
        for (int j = 0; j < 8; j++) p += acc[i][j] * acc[i][j];
        p = red16(p);
        if (tx == 0) rn[row] = 1.0f / (sqrtf(p) + EPSF);
    }
}

// ---------------------------------------------------------------------------
// Fused kernel (UNCHANGED v12/v14, verified 812us): blocks 0..3 = v8 scan;
// blocks 4..255 = Q (+s) and V projections on otherwise-idle CUs.
// ---------------------------------------------------------------------------
__global__ __launch_bounds__(512, 1) void fused_kernel(
    const float* __restrict__ x,
    const float* __restrict__ Wq, const float* __restrict__ bq,
    const float* __restrict__ Wv, const float* __restrict__ bv,
    const float* __restrict__ K, const float* __restrict__ rn,
    float* __restrict__ Q, float* __restrict__ V,
    float* __restrict__ Sarr, float* __restrict__ Z)
{
    __shared__ float Ybc[2][2][8 * 20];   // scan: [buf][y1/y2], padded
    __shared__ float kst[2][2][8 * 20];   // scan: [buf][k1/k2], padded

    if (blockIdx.x >= BB) {
        const int wb = blockIdx.x - BB;          // 0..251
        for (int t = wb; t < 256; t += 252) {
            const int which = t >> 7;            // 0 = Q, 1 = V
            const int tile  = t & 127;
            if (which == 0)
                proj512(x, Wq, bq, Q, tile * 64, 2, Sarr, K);
            else
                proj512(x, Wv, bv, V, tile * 64, 0, nullptr, nullptr);
        }
        return;
    }

    const int b   = blockIdx.x;
    const int tid = threadIdx.x;
    const int r2  = tid >> 3;
    const int o8  = tid & 7;
    const int c0  = o8 * 16;
    const int r0  = 2 * r2, r1 = r0 + 1;

    f32x2 Ar0[8], Ar1[8];
    #pragma unroll
    for (int j = 0; j < 8; j++) {
        Ar0[j].x = (c0 + 2*j     == r0) ? 1.f : 0.f;
        Ar0[j].y = (c0 + 2*j + 1 == r0) ? 1.f : 0.f;
        Ar1[j].x = (c0 + 2*j     == r1) ? 1.f : 0.f;
        Ar1[j].y = (c0 + 2*j + 1 == r1) ? 1.f : 0.f;
    }

    const float* Kb = K + (size_t)b * TT * HH;
    float*       Zb = Z + (size_t)b * TT * HH;
    const float* rn_b = rn + (size_t)b * TT;

    const int woff = (r0 >> 4) * 20 + (r0 & 15);
    const int roff = o8 * 20;

    const bool ldr    = tid < 64;
    const int  whichk = tid >> 5;
    const int  l32    = tid & 31;
    const int  lpoff  = (l32 >> 2) * 20 + (l32 & 3) * 4;   // v8 8x20 mapping

    float4 pld = {0.f, 0.f, 0.f, 0.f};
    if (ldr) {
        float4 d0 = *(const float4*)(Kb + (size_t)whichk * HH + l32 * 4);
        *(float4*)&kst[0][whichk][lpoff] = d0;
        pld = *(const float4*)(Kb + (size_t)(2 + whichk) * HH + l32 * 4);
    }
    float2 rs_cur = ((const float2*)rn_b)[0];
    float2 rs_nxt = ((const float2*)rn_b)[1];
    __syncthreads();

    f32x2 k1[8], k2[8];
    #pragma unroll
    for (int j = 0; j < 4; j++) {
        float4 t1 = *(const float4*)&kst[0][0][roff + 4 * j];
        float4 t2 = *(const float4*)&kst[0][1][roff + 4 * j];
        k1[2*j] = (f32x2){t1.x, t1.y}; k1[2*j+1] = (f32x2){t1.z, t1.w};
        k2[2*j] = (f32x2){t2.x, t2.y}; k2[2*j+1] = (f32x2){t2.z, t2.w};
    }

    for (int i = 0; i < NI; ++i) {
        const int yb = i & 1;
        const int nk = (i + 1) & 1;

        f32x2 y10 = {0,0}, y11 = {0,0}, y20 = {0,0}, y21 = {0,0};
        #pragma unroll
        for (int j = 0; j < 8; j++) {
            y10 += Ar0[j] * k1[j];
            y11 += Ar1[j] * k1[j];
            y20 += Ar0[j] * k2[j];
            y21 += Ar1[j] * k2[j];
        }
        float y1r0 = red8(y10.x + y10.y);
        float y1r1 = red8(y11.x + y11.y);
        float y2r0 = red8(y20.x + y20.y);
        float y2r1 = red8(y21.x + y21.y);
        if (o8 == 0) {
            *(float2*)&Ybc[yb][0][woff] = make_float2(y1r0, y1r1);
            *(float2*)&Ybc[yb][1][woff] = make_float2(y2r0, y2r1);
        }

        if (ldr && i + 1 < NI) {
            *(float4*)&kst[nk][whichk][lpoff] = pld;
            if (i + 2 < NI)
                pld = *(const float4*)(Kb + (size_t)(2*(i+2) + whichk) * HH + l32 * 4);
        }

        __syncthreads();

        f32x2 av1[8], av2[8];
        #pragma unroll
        for (int j = 0; j < 4; j++) {
            float4 t1 = *(const float4*)&Ybc[yb][0][roff + 4 * j];
            float4 t2 = *(const float4*)&Ybc[yb][1][roff + 4 * j];
            av1[2*j] = (f32x2){t1.x, t1.y}; av1[2*j+1] = (f32x2){t1.z, t1.w};
            av2[2*j] = (f32x2){t2.x, t2.y}; av2[2*j+1] = (f32x2){t2.z, t2.w};
        }

        f32x2 e11v = {0,0}, e21v = {0,0}, e22v = {0,0};
        #pragma unroll
        for (int j = 0; j < 8; j++) {
            e11v += av1[j] * k1[j];
            e21v += av1[j] * k2[j];
            e22v += av2[j] * k2[j];
        }
        float e11 = red8(e11v.x + e11v.y);
        float e21 = red8(e21v.x + e21v.y);
        float e22 = red8(e22v.x + e22v.y);

        #pragma unroll
        for (int j = 0; j < 4; j++) {
            float4 t1 = *(const float4*)&kst[nk][0][roff + 4 * j];
            float4 t2 = *(const float4*)&kst[nk][1][roff + 4 * j];
            k1[2*j] = (f32x2){t1.x, t1.y}; k1[2*j+1] = (f32x2){t1.z, t1.w};
            k2[2*j] = (f32x2){t2.x, t2.y}; k2[2*j+1] = (f32x2){t2.z, t2.w};
        }

        const float rn1 = rs_cur.x, rn2 = rs_cur.y;
        const float rn1sq = rn1 * rn1;
        const float rn2sq = rn2 * rn2;
        const float i1   = __builtin_amdgcn_rcpf(1.0f + rn1sq * e11);
        const float beta = rn1sq * e21 * i1;
        const float i2   = __builtin_amdgcn_rcpf(1.0f + rn2sq * (e22 - beta * e21));
        const float p2r0 = y2r0 - beta * y1r0;
        const float p2r1 = y2r1 - beta * y1r1;
        const float za1  = rn1 * i1;
        const float za2  = rn2 * i2;
        if (o8 == 0) {
            *(float2*)(Zb + (size_t)(2*i)     * HH + r0) =
                make_float2(za1 * y1r0, za1 * y1r1);
            *(float2*)(Zb + (size_t)(2*i + 1) * HH + r0) =
                make_float2(za2 * p2r0, za2 * p2r1);
        }

        const float cA1 = rn1sq * i1, cA2 = rn2sq * i2;
        const f32x2 u10 = {cA1 * y1r0, cA1 * y1r0};
        const f32x2 u11 = {cA1 * y1r1, cA1 * y1r1};
        const f32x2 u20 = {cA2 * p2r0, cA2 * p2r0};
        const f32x2 u21 = {cA2 * p2r1, cA2 * p2r1};
        const f32x2 bbv = {beta, beta};
        #pragma unroll
        for (int j = 0; j < 8; j++) {
            f32x2 pp = av2[j] - bbv * av1[j];
            Ar0[j] = Ar0[j] - u10 * av1[j] - u20 * pp;
            Ar1[j] = Ar1[j] - u11 * av1[j] - u21 * pp;
        }

        rs_cur = rs_nxt;
        if (i + 2 < NI) rs_nxt = ((const float2*)rn_b)[i + 2];
    }
}

// ---------------------------------------------------------------------------
// Phase-2 MEGAKERNEL: 256 blocks x 256 threads, guaranteed co-resident
// (<=38.4KB LDS, ~64 VGPR -> >=2 blocks/CU capacity). Four phases separated
// by device-scope grid barriers (counter @ d_out+20MB, memset per launch):
//   A: gram   G[b][c] = V^T (diag(s)Z)      (v14 body; blk>>2, (blk&3)*32)
//   B: prefix Mpre[b][c] = sum_{j<c} G[b][j] (v14 body; blk>>6, blk&63)
//   C: ochunk O = Q Mpre^T + tril(Q(sZ)^T) V (v14 body)
//   D: out    out = O Wo^T + bo              (v14 body; 4 tiles per block)
// Phase D overwrites the d_out scratch (incl. the barrier counter) -- all
// dead after the last barrier.
// ---------------------------------------------------------------------------
__global__ __launch_bounds__(256) void phase2_kernel(
    const float* __restrict__ Q, const float* __restrict__ Z,
    const float* __restrict__ Sarr, const float* __restrict__ V,
    float* __restrict__ G, float* __restrict__ Mpre, float* __restrict__ O,
    const float* __restrict__ Wo, const float* __restrict__ bo,
    float* __restrict__ out, int* bar)
{
    __shared__ float buf[9600];   // 38.4 KB, overlaid per phase

    const int blk = blockIdx.x;
    const int tid = threadIdx.x;
    const int tx = tid & 15, ty = tid >> 4;

    // ================= phase A: gram =================
    {
        float (*vT)[36]  = (float(*)[36])buf;
        float (*aT)[132] = (float(*)[132])(buf + 1152);
        const int bi = blk >> 2;
        const int r0 = (blk & 3) * 32;
        const float* Vc = V + (size_t)bi * CC * HH;
        const float* Zc = Z + (size_t)bi * CC * HH;
        const float* Sc = Sarr + (size_t)bi * CC;

        float acc[2][8];
        #pragma unroll
        for (int i = 0; i < 2; i++)
            #pragma unroll
            for (int j = 0; j < 8; j++) acc[i][j] = 0.f;

        for (int s0 = 0; s0 < CC; s0 += 32) {
            {   int sr = tid >> 3, rc = tid & 7;
                float4 v = *(const float4*)(Vc + (size_t)(s0 + sr) * HH + r0 + rc * 4);
                *(float4*)&vT[sr][rc * 4] = v;
            }
            #pragma unroll
            for (int l = 0; l < 4; l++) {
                int f = tid + l * 256;
                int sr = f >> 5, cc = f & 31;
                float sv = Sc[s0 + sr];
                float4 v = *(const float4*)(Zc + (size_t)(s0 + sr) * HH + cc * 4);
                v.x *= sv; v.y *= sv; v.z *= sv; v.w *= sv;
                *(float4*)&aT[sr][cc * 4] = v;
            }
            __syncthreads();
            #pragma unroll
            for (int ss = 0; ss < 32; ss++) {
                float2 vv = *(const float2*)&vT[ss][ty * 2];
                float4 a0 = *(const float4*)&aT[ss][tx * 8];
                float4 a1 = *(const float4*)&aT[ss][tx * 8 + 4];
                float va[2] = {vv.x, vv.y};
                float aa[8] = {a0.x, a0.y, a0.z, a0.w, a1.x, a1.y, a1.z, a1.w};
                #pragma unroll
                for (int i = 0; i < 2; i++)
                    #pragma unroll
                    for (int j = 0; j < 8; j++)
                        acc[i][j] += va[i] * aa[j];
            }
            __syncthreads();
        }

        #pragma unroll
        for (int i = 0; i < 2; i++) {
            float* gp = G + ((size_t)bi * HH + r0 + ty * 2 + i) * HH + tx * 8;
            float4 o0 = {acc[i][0], acc[i][1], acc[i][2], acc[i][3]};
            float4 o1 = {acc[i][4], acc[i][5], acc[i][6], acc[i][7]};
            *(float4*)gp       = o0;
            *(float4*)(gp + 4) = o1;
        }
    }
    gridbar(bar, 256);

    // ================= phase B: prefix =================
    {
        const int b   = blk >> 6;
        const int idx = (blk & 63) * 256 + tid;
        float run = 0.f;
        for (int i = 0; i < NCH; i++) {
            size_t off = ((size_t)b * NCH + i) * HH * HH + idx;
            Mpre[off] = run;
            run += G[off];
        }
    }
    gridbar(bar, 512);

    // ================= phase C: ochunk =================
    {
        float (*S)[132]  = (float(*)[132])buf;
        float (*xT)[36]  = (float(*)[36])(buf + 4224);
        float (*wT)[132] = (float(*)[132])(buf + 5376);
        const int bi = blk >> 2;
        const int t0 = (blk & 3) * 32;
        const float* Qc = Q    + (size_t)bi * CC * HH;
        const float* Zc = Z    + (size_t)bi * CC * HH;
        const float* Vc = V    + (size_t)bi * CC * HH;
        const float* Sc = Sarr + (size_t)bi * CC;
        const float* Mp = Mpre + (size_t)bi * HH * HH;
        float*       Oc = O    + (size_t)bi * CC * HH;

        float acc[2][8];

        // phase 1: S = tril(Q (sZ)^T)
        #pragma unroll
        for (int i = 0; i < 2; i++)
            #pragma unroll
            for (int j = 0; j < 8; j++) acc[i][j] = 0.f;
        for (int k0 = 0; k0 < HH; k0 += 32) {
            {   int r = tid >> 3, cg = tid & 7;
                float4 v = *(const float4*)(Qc + (size_t)(t0 + r) * HH + k0 + cg * 4);
                xT[cg*4+0][r] = v.x; xT[cg*4+1][r] = v.y;
                xT[cg*4+2][r] = v.z; xT[cg*4+3][r] = v.w;
            }
            #pragma unroll
            for (int l = 0; l < 4; l++) {
                int f = tid + l * 256;
                int sr = f >> 3, cg = f & 7;
                float sv = Sc[sr];
                float4 v = *(const float4*)(Zc + (size_t)sr * HH + k0 + cg * 4);
                wT[cg*4+0][sr] = v.x * sv; wT[cg*4+1][sr] = v.y * sv;
                wT[cg*4+2][sr] = v.z * sv; wT[cg*4+3][sr] = v.w * sv;
            }
            __syncthreads();
            #pragma unroll
            for (int kk = 0; kk < 32; kk++) {
                float2 xv = *(const float2*)&xT[kk][ty * 2];
                float4 w0 = *(const float4*)&wT[kk][tx * 8];
                float4 w1 = *(const float4*)&wT[kk][tx * 8 + 4];
                float xa[2] = {xv.x, xv.y};
                float wa[8] = {w0.x, w0.y, w0.z, w0.w, w1.x, w1.y, w1.z, w1.w};
                #pragma unroll
                for (int i = 0; i < 2; i++)
                    #pragma unroll
                    for (int j = 0; j < 8; j++)
                        acc[i][j] += xa[i] * wa[j];
            }
            __syncthreads();
        }
        #pragma unroll
        for (int i = 0; i < 2; i++) {
            int tl = t0 + ty * 2 + i;
            float m[8];
            #pragma unroll
            for (int j = 0; j < 8; j++)
                m[j] = (tx * 8 + j <= tl) ? acc[i][j] : 0.f;
            float4 o0 = {m[0], m[1], m[2], m[3]};
            float4 o1 = {m[4], m[5], m[6], m[7]};
            *(float4*)&S[ty*2+i][tx*8]     = o0;
            *(float4*)&S[ty*2+i][tx*8 + 4] = o1;
        }

        // phase 2: acc = Q @ Mpre^T
        #pragma unroll
        for (int i = 0; i < 2; i++)
            #pragma unroll
            for (int j = 0; j < 8; j++) acc[i][j] = 0.f;
        for (int k0 = 0; k0 < HH; k0 += 32) {
            {   int r = tid >> 3, cg = tid & 7;
                float4 v = *(const float4*)(Qc + (size_t)(t0 + r) * HH + k0 + cg * 4);
                xT[cg*4+0][r] = v.x; xT[cg*4+1][r] = v.y;
                xT[cg*4+2][r] = v.z; xT[cg*4+3][r] = v.w;
            }
            #pragma unroll
            for (int l = 0; l < 4; l++) {
                int f = tid + l * 256;
                int h = f >> 3, cg = f & 7;
                float4 v = *(const float4*)(Mp + (size_t)h * HH + k0 + cg * 4);
                wT[cg*4+0][h] = v.x; wT[cg*4+1][h] = v.y;
                wT[cg*4+2][h] = v.z; wT[cg*4+3][h] = v.w;
            }
            __syncthreads();
            #pragma unroll
            for (int kk = 0; kk < 32; kk++) {
                float2 xv = *(const float2*)&xT[kk][ty * 2];
                float4 w0 = *(const float4*)&wT[kk][tx * 8];
                float4 w1 = *(const float4*)&wT[kk][tx * 8 + 4];
                float xa[2] = {xv.x, xv.y};
                float wa[8] = {w0.x, w0.y, w0.z, w0.w, w1.x, w1.y, w1.z, w1.w};
                #pragma unroll
                for (int i = 0; i < 2; i++)
                    #pragma unroll
                    for (int j = 0; j < 8; j++)
                        acc[i][j] += xa[i] * wa[j];
            }
            __syncthreads();
        }

        // phase 3: acc += S @ V
        for (int s0 = 0; s0 < CC; s0 += 32) {
            #pragma unroll
            for (int l = 0; l < 4; l++) {
                int f = tid + l * 256;
                int sr = f >> 5, cc = f & 31;
                float4 v = *(const float4*)(Vc + (size_t)(s0 + sr) * HH + cc * 4);
                *(float4*)&wT[sr][cc * 4] = v;
            }
            __syncthreads();
            #pragma unroll
            for (int ss = 0; ss < 32; ss++) {
                float4 w0 = *(const float4*)&wT[ss][tx * 8];
                float4 w1 = *(const float4*)&wT[ss][tx * 8 + 4];
                float wa[8] = {w0.x, w0.y, w0.z, w0.w, w1.x, w1.y, w1.z, w1.w};
                float sv[2] = {S[ty*2][s0 + ss], S[ty*2+1][s0 + ss]};
                #pragma unroll
                for (int i = 0; i < 2; i++)
                    #pragma unroll
                    for (int j = 0; j < 8; j++)
                        acc[i][j] += sv[i] * wa[j];
            }
            __syncthreads();
        }

        #pragma unroll
        for (int i = 0; i < 2; i++) {
            float* op = Oc + (size_t)(t0 + ty * 2 + i) * HH + tx * 8;
            float4 o0 = {acc[i][0], acc[i][1], acc[i][2], acc[i][3]};
            float4 o1 = {acc[i][4], acc[i][5], acc[i][6], acc[i][7]};
            *(float4*)op       = o0;
            *(float4*)(op + 4) = o1;
        }
    }
    gridbar(bar, 768);

    // ================= phase D: out (4 tiles per block) =================
    {
        float (*oT)[68]   = (float(*)[68])buf;
        float (*woT)[132] = (float(*)[132])(buf + 2176);
        for (int tt = 0; tt < 4; tt++) {
            const int tile = blk * 4 + tt;
            const int row0 = (tile >> 3) * 64;
            const int d0   = (tile & 7) * 128;

            float acc[4][8];
            #pragma unroll
            for (int i = 0; i < 4; i++)
                #pragma unroll
                for (int j = 0; j < 8; j++) acc[i][j] = 0.f;

            for (int k0 = 0; k0 < HH; k0 += 32) {
                #pragma unroll
                for (int l = 0; l < 2; l++) {
                    int f = tid + l * 256;
                    int r = f >> 3;
                    int cg = f & 7;
                    float4 v = *(const float4*)(O + (size_t)(row0 + r) * HH + k0 + cg * 4);
                    oT[cg*4+0][r] = v.x; oT[cg*4+1][r] = v.y;
                    oT[cg*4+2][r] = v.z; oT[cg*4+3][r] = v.w;
                }
                #pragma unroll
                for (int l = 0; l < 4; l++) {
                    int f = tid + l * 256;
                    int d = f >> 3;
                    int cg = f & 7;
                    float4 v = *(const float4*)(Wo + (size_t)(d0 + d) * HH + k0 + cg * 4);
                    woT[cg*4+0][d] = v.x; woT[cg*4+1][d] = v.y;
                    woT[cg*4+2][d] = v.z; woT[cg*4+3][d] = v.w;
                }
                __syncthreads();
                #pragma unroll
                for (int kk = 0; kk < 32; kk++) {
                    float4 ov = *(const float4*)&oT[kk][ty * 4];
                    float4 w0 = *(const float4*)&woT[kk][tx * 8];
                    float4 w1 = *(const float4*)&woT[kk][tx * 8 + 4];
                    float oa[4] = {ov.x, ov.y, ov.z, ov.w};
                    float wa[8] = {w0.x, w0.y, w0.z, w0.w, w1.x, w1.y, w1.z, w1.w};
                    #pragma unroll
                    for (int i = 0; i < 4; i++)
                        #pragma unroll
                        for (int j = 0; j < 8; j++)
                            acc[i][j] += oa[i] * wa[j];
                }
                __syncthreads();
            }

            #pragma unroll
            for (int i = 0; i < 4; i++) {
                int row = row0 + ty * 4 + i;
                #pragma unroll
                for (int j = 0; j < 8; j++) acc[i][j] += bo[d0 + tx * 8 + j];
                float4 o0 = {acc[i][0], acc[i][1], acc[i][2], acc[i][3]};
                float4 o1 = {acc[i][4], acc[i][5], acc[i][6], acc[i][7]};
                *(float4*)(out + (size_t)row * DD + d0 + tx * 8)     = o0;
                *(float4*)(out + (size_t)row * DD + d0 + tx * 8 + 4) = o1;
            }
        }
    }
}

extern "C" void kernel_launch(void* const* d_in, const int* in_sizes, int n_in,
                              void* d_out, int out_size, void* d_ws, size_t ws_size,
                              hipStream_t stream) {
    const float* x  = (const float*)d_in[0];
    const float* Wq = (const float*)d_in[1];
    const float* bq = (const float*)d_in[2];
    const float* Wk = (const float*)d_in[3];
    const float* bk = (const float*)d_in[4];
    const float* Wv = (const float*)d_in[5];
    const float* bv = (const float*)d_in[6];
    const float* Wo = (const float*)d_in[7];
    const float* bo = (const float*)d_in[8];
    float* out = (float*)d_out;

    float* ws = (float*)d_ws;
    float* Q = ws;
    float* K = ws + (size_t)BT * HH;
    float* V = ws + (size_t)2 * BT * HH;
    float* O = ws + (size_t)3 * BT * HH;

    // scratch in d_out (32 MB), all dead before phase D overwrites it:
    //   rn @0 (32KB) | s @32KB | Z @1MB (4MB) | G @8MB (4MB) | Mpre @12MB
    //   barrier counter @20MB (zeroed per launch; captured in graph)
    float* db   = (float*)d_out;
    float* rn   = db;
    float* Sarr = db + BT;
    float* Z    = db + (1u << 18);
    float* G    = db + (1u << 21);
    float* Mpre = db + 3u * (1u << 20);
    int*   bar  = (int*)((char*)d_out + BAR_OFF);

    hipMemsetAsync((void*)bar, 0, sizeof(int), stream);

    // 1. K projection (+rn) — the scan's only dependency
    projk_kernel<<<BT / 32, 256, 0, stream>>>(x, Wk, bk, K, rn);

    // 2. fused: 4 scan blocks + 252 worker blocks (Q proj + s, V proj)
    fused_kernel<<<256, 512, 0, stream>>>(
        x, Wq, bq, Wv, bv, K, rn, Q, V, Sarr, Z);

    // 3. phase-2 megakernel: gram -> prefix -> ochunk -> out (grid barriers)
    phase2_kernel<<<256, 256, 0, stream>>>(
        Q, Z, Sarr, V, G, Mpre, O, Wo, bo, out, bar);
}

// Round 15
// 1102.956 us; speedup vs baseline: 1.1102x; 1.1102x over previous
//
#include <hip/hip_runtime.h>
#include <math.h>

#define BB 4
#define TT 2048
#define DD 1024
#define HH 128
#define EPSF 1e-6f
#define BT (BB*TT)   // 8192
#define CC 128       // chunk length
#define NCH (TT/CC)  // 16 chunks per batch
#define NI (TT/2)    // 1024 double-steps

typedef float f32x2 __attribute__((ext_vector_type(2)));

// 8-lane butterfly sum, pure DPP/VALU (no DS pipe)
__device__ __forceinline__ float red8(float x) {
    x += __int_as_float(__builtin_amdgcn_mov_dpp(__float_as_int(x), 0xB1,  0xF, 0xF, true));
    x += __int_as_float(__builtin_amdgcn_mov_dpp(__float_as_int(x), 0x4E,  0xF, 0xF, true));
    x += __int_as_float(__builtin_amdgcn_mov_dpp(__float_as_int(x), 0x141, 0xF, 0xF, true));
    return x;
}
// 16-lane butterfly sum (adds ROW_MIRROR)
__device__ __forceinline__ float red16(float x) {
    x = red8(x);
    x += __int_as_float(__builtin_amdgcn_mov_dpp(__float_as_int(x), 0x140, 0xF, 0xF, true));
    return x;
}

// ---------------------------------------------------------------------------
// 512-thread projection tile (worker path of fused kernel, v12-verified):
// P[row0..row0+64][0..128) = x @ W^T + bias. mode 0 plain; mode 2 s=q.k.
// ---------------------------------------------------------------------------
__device__ __forceinline__ void proj512(
    const float* __restrict__ x, const float* __restrict__ W,
    const float* __restrict__ bias, float* __restrict__ P,
    int row0, int mode, float* __restrict__ aux,
    const float* __restrict__ Kmat)
{
    __shared__ float xT[32][68];
    __shared__ float wT[32][132];

    const int tid = threadIdx.x;
    const int tx = tid & 15;
    const int ty = tid >> 4;       // 0..31, rows ty*2 .. +2

    float acc[2][8];
    #pragma unroll
    for (int i = 0; i < 2; i++)
        #pragma unroll
        for (int j = 0; j < 8; j++) acc[i][j] = 0.f;

    for (int k0 = 0; k0 < DD; k0 += 32) {
        {   int r = tid >> 3, cg = tid & 7;
            float4 v = *(const float4*)(x + (size_t)(row0 + r) * DD + k0 + cg * 4);
            xT[cg*4+0][r] = v.x; xT[cg*4+1][r] = v.y;
            xT[cg*4+2][r] = v.z; xT[cg*4+3][r] = v.w;
        }
        #pragma unroll
        for (int l = 0; l < 2; l++) {
            int f = tid + l * 512;
            int h = f >> 3, cg = f & 7;
            float4 v = *(const float4*)(W + (size_t)h * DD + k0 + cg * 4);
            wT[cg*4+0][h] = v.x; wT[cg*4+1][h] = v.y;
            wT[cg*4+2][h] = v.z; wT[cg*4+3][h] = v.w;
        }
        __syncthreads();
        #pragma unroll
        for (int kk = 0; kk < 32; kk++) {
            float2 xv = *(const float2*)&xT[kk][ty * 2];
            float4 w0 = *(const float4*)&wT[kk][tx * 8];
            float4 w1 = *(const float4*)&wT[kk][tx * 8 + 4];
            float xa[2] = {xv.x, xv.y};
            float wa[8] = {w0.x, w0.y, w0.z, w0.w, w1.x, w1.y, w1.z, w1.w};
            #pragma unroll
            for (int i = 0; i < 2; i++)
                #pragma unroll
                for (int j = 0; j < 8; j++)
                    acc[i][j] += xa[i] * wa[j];
        }
        __syncthreads();
    }

    #pragma unroll
    for (int i = 0; i < 2; i++) {
        int row = row0 + ty * 2 + i;
        #pragma unroll
        for (int j = 0; j < 8; j++) acc[i][j] += bias[tx * 8 + j];
        float4 o0 = {acc[i][0], acc[i][1], acc[i][2], acc[i][3]};
        float4 o1 = {acc[i][4], acc[i][5], acc[i][6], acc[i][7]};
        *(float4*)(P + (size_t)row * HH + tx * 8)     = o0;
        *(float4*)(P + (size_t)row * HH + tx * 8 + 4) = o1;
    }

    if (mode == 2) {                 // s = q . k
        #pragma unroll
        for (int i = 0; i < 2; i++) {
            int row = row0 + ty * 2 + i;
            float4 ka = *(const float4*)(Kmat + (size_t)row * HH + tx * 8);
            float4 kb = *(const float4*)(Kmat + (size_t)row * HH + tx * 8 + 4);
            float p = acc[i][0]*ka.x + acc[i][1]*ka.y + acc[i][2]*ka.z + acc[i][3]*ka.w
                    + acc[i][4]*kb.x + acc[i][5]*kb.y + acc[i][6]*kb.z + acc[i][7]*kb.w;
            p = red16(p);
            if (tx == 0) aux[row] = p;
        }
    }
}

// ---------------------------------------------------------------------------
// K projection + rn epilogue, FULL-GPU: 256 blocks x 256 threads (v14).
// ---------------------------------------------------------------------------
__global__ __launch_bounds__(256) void projk_kernel(
    const float* __restrict__ x, const float* __restrict__ Wk,
    const float* __restrict__ bk, float* __restrict__ K,
    float* __restrict__ rn)
{
    const int row0 = blockIdx.x * 32;

    __shared__ float xT[32][36];
    __shared__ float wT[32][132];

    const int tid = threadIdx.x;
    const int tx = tid & 15;
    const int ty = tid >> 4;       // 0..15, rows ty*2..+2

    float acc[2][8];
    #pragma unroll
    for (int i = 0; i < 2; i++)
        #pragma unroll
        for (int j = 0; j < 8; j++) acc[i][j] = 0.f;

    for (int k0 = 0; k0 < DD; k0 += 32) {
        {   int r = tid >> 3, cg = tid & 7;
            float4 v = *(const float4*)(x + (size_t)(row0 + r) * DD + k0 + cg * 4);
            xT[cg*4+0][r] = v.x; xT[cg*4+1][r] = v.y;
            xT[cg*4+2][r] = v.z; xT[cg*4+3][r] = v.w;
        }
        #pragma unroll
        for (int l = 0; l < 4; l++) {
            int f = tid + l * 256;
            int h = f >> 3, cg = f & 7;
            float4 v = *(const float4*)(Wk + (size_t)h * DD + k0 + cg * 4);
            wT[cg*4+0][h] = v.x; wT[cg*4+1][h] = v.y;
            wT[cg*4+2][h] = v.z; wT[cg*4+3][h] = v.w;
        }
        __syncthreads();
        #pragma unroll
        for (int kk = 0; kk < 32; kk++) {
            float2 xv = *(const float2*)&xT[kk][ty * 2];
            float4 w0 = *(const float4*)&wT[kk][tx * 8];
            float4 w1 = *(const float4*)&wT[kk][tx * 8 + 4];
            float xa[2] = {xv.x, xv.y};
            float wa[8] = {w0.x, w0.y, w0.z, w0.w, w1.x, w1.y, w1.z, w1.w};
            #pragma unroll
            for (int i = 0; i < 2; i++)
                #pragma unroll
                for (int j = 0; j < 8; j++)
                    acc[i][j] += xa[i] * wa[j];
        }
        __syncthreads();
    }

    #pragma unroll
    for (int i = 0; i < 2; i++) {
        int row = row0 + ty * 2 + i;
        #pragma unroll
        for (int j = 0; j < 8; j++) acc[i][j] += bk[tx * 8 + j];
        float4 o0 = {acc[i][0], acc[i][1], acc[i][2], acc[i][3]};
        float4 o1 = {acc[i][4], acc[i][5], acc[i][6], acc[i][7]};
        *(float4*)(K + (size_t)row * HH + tx * 8)     = o0;
        *(float4*)(K + (size_t)row * HH + tx * 8 + 4) = o1;
        float p = 0.f;
        #pragma unroll
        for (int j = 0; j < 8; j++) p += acc[i][j] * acc[i][j];
        p = red16(p);
        if (tx == 0) rn[row] = 1.0f / (sqrtf(p) + EPSF);
    }
}

// ---------------------------------------------------------------------------
// Fused kernel (UNCHANGED v12/v14, verified 812us): blocks 0..3 = v8 scan;
// blocks 4..255 = Q (+s) and V projections on otherwise-idle CUs.
// ---------------------------------------------------------------------------
__global__ __launch_bounds__(512, 1) void fused_kernel(
    const float* __restrict__ x,
    const float* __restrict__ Wq, const float* __restrict__ bq,
    const float* __restrict__ Wv, const float* __restrict__ bv,
    const float* __restrict__ K, const float* __restrict__ rn,
    float* __restrict__ Q, float* __restrict__ V,
    float* __restrict__ Sarr, float* __restrict__ Z)
{
    __shared__ float Ybc[2][2][8 * 20];   // scan: [buf][y1/y2], padded
    __shared__ float kst[2][2][8 * 20];   // scan: [buf][k1/k2], padded

    if (blockIdx.x >= BB) {
        const int wb = blockIdx.x - BB;          // 0..251
        for (int t = wb; t < 256; t += 252) {
            const int which = t >> 7;            // 0 = Q, 1 = V
            const int tile  = t & 127;
            if (which == 0)
                proj512(x, Wq, bq, Q, tile * 64, 2, Sarr, K);
            else
                proj512(x, Wv, bv, V, tile * 64, 0, nullptr, nullptr);
        }
        return;
    }

    const int b   = blockIdx.x;
    const int tid = threadIdx.x;
    const int r2  = tid >> 3;
    const int o8  = tid & 7;
    const int c0  = o8 * 16;
    const int r0  = 2 * r2, r1 = r0 + 1;

    f32x2 Ar0[8], Ar1[8];
    #pragma unroll
    for (int j = 0; j < 8; j++) {
        Ar0[j].x = (c0 + 2*j     == r0) ? 1.f : 0.f;
        Ar0[j].y = (c0 + 2*j + 1 == r0) ? 1.f : 0.f;
        Ar1[j].x = (c0 + 2*j     == r1) ? 1.f : 0.f;
        Ar1[j].y = (c0 + 2*j + 1 == r1) ? 1.f : 0.f;
    }

    const float* Kb = K + (size_t)b * TT * HH;
    float*       Zb = Z + (size_t)b * TT * HH;
    const float* rn_b = rn + (size_t)b * TT;

    const int woff = (r0 >> 4) * 20 + (r0 & 15);
    const int roff = o8 * 20;

    const bool ldr    = tid < 64;
    const int  whichk = tid >> 5;
    const int  l32    = tid & 31;
    const int  lpoff  = (l32 >> 2) * 20 + (l32 & 3) * 4;   // v8 8x20 mapping

    float4 pld = {0.f, 0.f, 0.f, 0.f};
    if (ldr) {
        float4 d0 = *(const float4*)(Kb + (size_t)whichk * HH + l32 * 4);
        *(float4*)&kst[0][whichk][lpoff] = d0;
        pld = *(const float4*)(Kb + (size_t)(2 + whichk) * HH + l32 * 4);
    }
    float2 rs_cur = ((const float2*)rn_b)[0];
    float2 rs_nxt = ((const float2*)rn_b)[1];
    __syncthreads();

    f32x2 k1[8], k2[8];
    #pragma unroll
    for (int j = 0; j < 4; j++) {
        float4 t1 = *(const float4*)&kst[0][0][roff + 4 * j];
        float4 t2 = *(const float4*)&kst[0][1][roff + 4 * j];
        k1[2*j] = (f32x2){t1.x, t1.y}; k1[2*j+1] = (f32x2){t1.z, t1.w};
        k2[2*j] = (f32x2){t2.x, t2.y}; k2[2*j+1] = (f32x2){t2.z, t2.w};
    }

    for (int i = 0; i < NI; ++i) {
        const int yb = i & 1;
        const int nk = (i + 1) & 1;

        f32x2 y10 = {0,0}, y11 = {0,0}, y20 = {0,0}, y21 = {0,0};
        #pragma unroll
        for (int j = 0; j < 8; j++) {
            y10 += Ar0[j] * k1[j];
            y11 += Ar1[j] * k1[j];
            y20 += Ar0[j] * k2[j];
            y21 += Ar1[j] * k2[j];
        }
        float y1r0 = red8(y10.x + y10.y);
        float y1r1 = red8(y11.x + y11.y);
        float y2r0 = red8(y20.x + y20.y);
        float y2r1 = red8(y21.x + y21.y);
        if (o8 == 0) {
            *(float2*)&Ybc[yb][0][woff] = make_float2(y1r0, y1r1);
            *(float2*)&Ybc[yb][1][woff] = make_float2(y2r0, y2r1);
        }

        if (ldr && i + 1 < NI) {
            *(float4*)&kst[nk][whichk][lpoff] = pld;
            if (i + 2 < NI)
                pld = *(const float4*)(Kb + (size_t)(2*(i+2) + whichk) * HH + l32 * 4);
        }

        __syncthreads();

        f32x2 av1[8], av2[8];
        #pragma unroll
        for (int j = 0; j < 4; j++) {
            float4 t1 = *(const float4*)&Ybc[yb][0][roff + 4 * j];
            float4 t2 = *(const float4*)&Ybc[yb][1][roff + 4 * j];
            av1[2*j] = (f32x2){t1.x, t1.y}; av1[2*j+1] = (f32x2){t1.z, t1.w};
            av2[2*j] = (f32x2){t2.x, t2.y}; av2[2*j+1] = (f32x2){t2.z, t2.w};
        }

        f32x2 e11v = {0,0}, e21v = {0,0}, e22v = {0,0};
        #pragma unroll
        for (int j = 0; j < 8; j++) {
            e11v += av1[j] * k1[j];
            e21v += av1[j] * k2[j];
            e22v += av2[j] * k2[j];
        }
        float e11 = red8(e11v.x + e11v.y);
        float e21 = red8(e21v.x + e21v.y);
        float e22 = red8(e22v.x + e22v.y);

        #pragma unroll
        for (int j = 0; j < 4; j++) {
            float4 t1 = *(const float4*)&kst[nk][0][roff + 4 * j];
            float4 t2 = *(const float4*)&kst[nk][1][roff + 4 * j];
            k1[2*j] = (f32x2){t1.x, t1.y}; k1[2*j+1] = (f32x2){t1.z, t1.w};
            k2[2*j] = (f32x2){t2.x, t2.y}; k2[2*j+1] = (f32x2){t2.z, t2.w};
        }

        const float rn1 = rs_cur.x, rn2 = rs_cur.y;
        const float rn1sq = rn1 * rn1;
        const float rn2sq = rn2 * rn2;
        const float i1   = __builtin_amdgcn_rcpf(1.0f + rn1sq * e11);
        const float beta = rn1sq * e21 * i1;
        const float i2   = __builtin_amdgcn_rcpf(1.0f + rn2sq * (e22 - beta * e21));
        const float p2r0 = y2r0 - beta * y1r0;
        const float p2r1 = y2r1 - beta * y1r1;
        const float za1  = rn1 * i1;
        const float za2  = rn2 * i2;
        if (o8 == 0) {
            *(float2*)(Zb + (size_t)(2*i)     * HH + r0) =
                make_float2(za1 * y1r0, za1 * y1r1);
            *(float2*)(Zb + (size_t)(2*i + 1) * HH + r0) =
                make_float2(za2 * p2r0, za2 * p2r1);
        }

        const float cA1 = rn1sq * i1, cA2 = rn2sq * i2;
        const f32x2 u10 = {cA1 * y1r0, cA1 * y1r0};
        const f32x2 u11 = {cA1 * y1r1, cA1 * y1r1};
        const f32x2 u20 = {cA2 * p2r0, cA2 * p2r0};
        const f32x2 u21 = {cA2 * p2r1, cA2 * p2r1};
        const f32x2 bbv = {beta, beta};
        #pragma unroll
        for (int j = 0; j < 8; j++) {
            f32x2 pp = av2[j] - bbv * av1[j];
            Ar0[j] = Ar0[j] - u10 * av1[j] - u20 * pp;
            Ar1[j] = Ar1[j] - u11 * av1[j] - u21 * pp;
        }

        rs_cur = rs_nxt;
        if (i + 2 < NI) rs_nxt = ((const float2*)rn_b)[i + 2];
    }
}

// ---------------------------------------------------------------------------
// Phase 2a: G[b][c] = V_chunk^T @ (diag(s) Z_chunk). Grid (64,4), 256 thr.
// (v14-verified body.)
// ---------------------------------------------------------------------------
__global__ __launch_bounds__(256) void gram_kernel(
    const float* __restrict__ V, const float* __restrict__ Z,
    const float* __restrict__ Sarr, float* __restrict__ G)
{
    const int bi = blockIdx.x;                 // b*NCH + chunk
    const int r0 = blockIdx.y * 32;

    const float* Vc = V + (size_t)bi * CC * HH;
    const float* Zc = Z + (size_t)bi * CC * HH;
    const float* Sc = Sarr + (size_t)bi * CC;

    __shared__ float vT[32][36];
    __shared__ float aT[32][132];

    const int tid = threadIdx.x;
    const int tx = tid & 15, ty = tid >> 4;

    float acc[2][8];
    #pragma unroll
    for (int i = 0; i < 2; i++)
        #pragma unroll
        for (int j = 0; j < 8; j++) acc[i][j] = 0.f;

    for (int s0 = 0; s0 < CC; s0 += 32) {
        {   int sr = tid >> 3, rc = tid & 7;
            float4 v = *(const float4*)(Vc + (size_t)(s0 + sr) * HH + r0 + rc * 4);
            *(float4*)&vT[sr][rc * 4] = v;
        }
        #pragma unroll
        for (int l = 0; l < 4; l++) {
            int f = tid + l * 256;
            int sr = f >> 5, cc = f & 31;
            float sv = Sc[s0 + sr];
            float4 v = *(const float4*)(Zc + (size_t)(s0 + sr) * HH + cc * 4);
            v.x *= sv; v.y *= sv; v.z *= sv; v.w *= sv;
            *(float4*)&aT[sr][cc * 4] = v;
        }
        __syncthreads();
        #pragma unroll
        for (int ss = 0; ss < 32; ss++) {
            float2 vv = *(const float2*)&vT[ss][ty * 2];
            float4 a0 = *(const float4*)&aT[ss][tx * 8];
            float4 a1 = *(const float4*)&aT[ss][tx * 8 + 4];
            float va[2] = {vv.x, vv.y};
            float aa[8] = {a0.x, a0.y, a0.z, a0.w, a1.x, a1.y, a1.z, a1.w};
            #pragma unroll
            for (int i = 0; i < 2; i++)
                #pragma unroll
                for (int j = 0; j < 8; j++)
                    acc[i][j] += va[i] * aa[j];
        }
        __syncthreads();
    }

    #pragma unroll
    for (int i = 0; i < 2; i++) {
        float* gp = G + ((size_t)bi * HH + r0 + ty * 2 + i) * HH + tx * 8;
        float4 o0 = {acc[i][0], acc[i][1], acc[i][2], acc[i][3]};
        float4 o1 = {acc[i][4], acc[i][5], acc[i][6], acc[i][7]};
        *(float4*)gp       = o0;
        *(float4*)(gp + 4) = o1;
    }
}

// ---------------------------------------------------------------------------
// Phase 2b: exclusive prefix over chunks (v14-verified).
// ---------------------------------------------------------------------------
__global__ __launch_bounds__(256) void prefix_kernel(
    const float* __restrict__ G, float* __restrict__ Mpre)
{
    const int b   = blockIdx.x;
    const int idx = blockIdx.y * 256 + threadIdx.x;
    float run = 0.f;
    for (int i = 0; i < NCH; i++) {
        size_t off = ((size_t)b * NCH + i) * HH * HH + idx;
        Mpre[off] = run;
        run += G[off];
    }
}

// ---------------------------------------------------------------------------
// Phase 2c+D: ochunk_out. Grid (64,4), 256 threads. Computes O rows
// t0..t0+32 of chunk bi IN REGISTERS (v14 ochunk body), then applies the
// output projection locally: out[rows][:] = Otile @ Wo^T + bo.
// No O global round-trip, no separate out_kernel, no cross-block sync.
// LDS overlay: buf[9600] = S(4224) | xT(1152) | wT(4224); epilogue reuses
// S+xT region as oT2[128][36] (O-tile transposed, 4608 floats <= 5376).
// ---------------------------------------------------------------------------
__global__ __launch_bounds__(256) void ochunk_out_kernel(
    const float* __restrict__ Q, const float* __restrict__ Z,
    const float* __restrict__ Sarr, const float* __restrict__ V,
    const float* __restrict__ Mpre,
    const float* __restrict__ Wo, const float* __restrict__ bo,
    float* __restrict__ out)
{
    __shared__ float buf[9600];
    float (*S)[132] = (float(*)[132])buf;              // scores
    float (*xT)[36] = (float(*)[36])(buf + 4224);
    float (*wT)[132] = (float(*)[132])(buf + 5376);
    float* oT2 = buf;                                   // epilogue overlay

    const int bi = blockIdx.x;
    const int t0 = blockIdx.y * 32;            // local t base within chunk

    const float* Qc = Q    + (size_t)bi * CC * HH;
    const float* Zc = Z    + (size_t)bi * CC * HH;
    const float* Vc = V    + (size_t)bi * CC * HH;
    const float* Sc = Sarr + (size_t)bi * CC;
    const float* Mp = Mpre + (size_t)bi * HH * HH;

    const int tid = threadIdx.x;
    const int tx = tid & 15, ty = tid >> 4;    // ty 0..15, rows ty*2..+2

    float acc[2][8];

    // ---- phase 1: S = tril(Q (sZ)^T), K = h
    #pragma unroll
    for (int i = 0; i < 2; i++)
        #pragma unroll
        for (int j = 0; j < 8; j++) acc[i][j] = 0.f;
    for (int k0 = 0; k0 < HH; k0 += 32) {
        {   int r = tid >> 3, cg = tid & 7;
            float4 v = *(const float4*)(Qc + (size_t)(t0 + r) * HH + k0 + cg * 4);
            xT[cg*4+0][r] = v.x; xT[cg*4+1][r] = v.y;
            xT[cg*4+2][r] = v.z; xT[cg*4+3][r] = v.w;
        }
        #pragma unroll
        for (int l = 0; l < 4; l++) {
            int f = tid + l * 256;
            int sr = f >> 3, cg = f & 7;
            float sv = Sc[sr];
            float4 v = *(const float4*)(Zc + (size_t)sr * HH + k0 + cg * 4);
            wT[cg*4+0][sr] = v.x * sv; wT[cg*4+1][sr] = v.y * sv;
            wT[cg*4+2][sr] = v.z * sv; wT[cg*4+3][sr] = v.w * sv;
        }
        __syncthreads();
        #pragma unroll
        for (int kk = 0; kk < 32; kk++) {
            float2 xv = *(const float2*)&xT[kk][ty * 2];
            float4 w0 = *(const float4*)&wT[kk][tx * 8];
            float4 w1 = *(const float4*)&wT[kk][tx * 8 + 4];
            float xa[2] = {xv.x, xv.y};
            float wa[8] = {w0.x, w0.y, w0.z, w0.w, w1.x, w1.y, w1.z, w1.w};
            #pragma unroll
            for (int i = 0; i < 2; i++)
                #pragma unroll
                for (int j = 0; j < 8; j++)
                    acc[i][j] += xa[i] * wa[j];
        }
        __syncthreads();
    }
    #pragma unroll
    for (int i = 0; i < 2; i++) {
        int tl = t0 + ty * 2 + i;
        float m[8];
        #pragma unroll
        for (int j = 0; j < 8; j++)
            m[j] = (tx * 8 + j <= tl) ? acc[i][j] : 0.f;
        float4 o0 = {m[0], m[1], m[2], m[3]};
        float4 o1 = {m[4], m[5], m[6], m[7]};
        *(float4*)&S[ty*2+i][tx*8]     = o0;
        *(float4*)&S[ty*2+i][tx*8 + 4] = o1;
    }

    // ---- phase 2: acc = Q @ Mpre^T, K = h
    #pragma unroll
    for (int i = 0; i < 2; i++)
        #pragma unroll
        for (int j = 0; j < 8; j++) acc[i][j] = 0.f;
    for (int k0 = 0; k0 < HH; k0 += 32) {
        {   int r = tid >> 3, cg = tid & 7;
            float4 v = *(const float4*)(Qc + (size_t)(t0 + r) * HH + k0 + cg * 4);
            xT[cg*4+0][r] = v.x; xT[cg*4+1][r] = v.y;
            xT[cg*4+2][r] = v.z; xT[cg*4+3][r] = v.w;
        }
        #pragma unroll
        for (int l = 0; l < 4; l++) {
            int f = tid + l * 256;
            int h = f >> 3, cg = f & 7;
            float4 v = *(const float4*)(Mp + (size_t)h * HH + k0 + cg * 4);
            wT[cg*4+0][h] = v.x; wT[cg*4+1][h] = v.y;
            wT[cg*4+2][h] = v.z; wT[cg*4+3][h] = v.w;
        }
        __syncthreads();
        #pragma unroll
        for (int kk = 0; kk < 32; kk++) {
            float2 xv = *(const float2*)&xT[kk][ty * 2];
            float4 w0 = *(const float4*)&wT[kk][tx * 8];
            float4 w1 = *(const float4*)&wT[kk][tx * 8 + 4];
            float xa[2] = {xv.x, xv.y};
            float wa[8] = {w0.x, w0.y, w0.z, w0.w, w1.x, w1.y, w1.z, w1.w};
            #pragma unroll
            for (int i = 0; i < 2; i++)
                #pragma unroll
                for (int j = 0; j < 8; j++)
                    acc[i][j] += xa[i] * wa[j];
        }
        __syncthreads();
    }

    // ---- phase 3: acc += S @ V, K = s   (acc now = O rows, all 128 h)
    for (int s0 = 0; s0 < CC; s0 += 32) {
        #pragma unroll
        for (int l = 0; l < 4; l++) {
            int f = tid + l * 256;
            int sr = f >> 5, cc = f & 31;
            float4 v = *(const float4*)(Vc + (size_t)(s0 + sr) * HH + cc * 4);
            *(float4*)&wT[sr][cc * 4] = v;
        }
        __syncthreads();
        #pragma unroll
        for (int ss = 0; ss < 32; ss++) {
            float4 w0 = *(const float4*)&wT[ss][tx * 8];
            float4 w1 = *(const float4*)&wT[ss][tx * 8 + 4];
            float wa[8] = {w0.x, w0.y, w0.z, w0.w, w1.x, w1.y, w1.z, w1.w};
            float sv[2] = {S[ty*2][s0 + ss], S[ty*2+1][s0 + ss]};
            #pragma unroll
            for (int i = 0; i < 2; i++)
                #pragma unroll
                for (int j = 0; j < 8; j++)
                    acc[i][j] += sv[i] * wa[j];
        }
        __syncthreads();
    }

    // ---- epilogue: out[rows][:] = Otile @ Wo^T + bo  (block-local)
    // store O tile transposed: oT2[h*36 + row], rows contiguous -> float2
    #pragma unroll
    for (int j = 0; j < 8; j++) {
        float2 p = {acc[0][j], acc[1][j]};
        *(float2*)&oT2[(tx * 8 + j) * 36 + ty * 2] = p;
    }
    __syncthreads();

    const int grow0 = bi * CC + t0;            // global row base
    for (int d0 = 0; d0 < DD; d0 += 128) {
        float a2[2][8];
        #pragma unroll
        for (int i = 0; i < 2; i++)
            #pragma unroll
            for (int j = 0; j < 8; j++) a2[i][j] = 0.f;

        for (int k0 = 0; k0 < HH; k0 += 32) {
            #pragma unroll
            for (int l = 0; l < 4; l++) {      // stage Wo[d0+d][k0..+32]
                int f = tid + l * 256;
                int d = f >> 3, cg = f & 7;
                float4 v = *(const float4*)(Wo + (size_t)(d0 + d) * HH + k0 + cg * 4);
                wT[cg*4+0][d] = v.x; wT[cg*4+1][d] = v.y;
                wT[cg*4+2][d] = v.z; wT[cg*4+3][d] = v.w;
            }
            __syncthreads();
            #pragma unroll
            for (int kk = 0; kk < 32; kk++) {
                float2 xv = *(const float2*)&oT2[(k0 + kk) * 36 + ty * 2];
                float4 w0 = *(const float4*)&wT[kk][tx * 8];
                float4 w1 = *(const float4*)&wT[kk][tx * 8 + 4];
                float xa[2] = {xv.x, xv.y};
                float wa[8] = {w0.x, w0.y, w0.z, w0.w, w1.x, w1.y, w1.z, w1.w};
                #pragma unroll
                for (int i = 0; i < 2; i++)
                    #pragma unroll
                    for (int j = 0; j < 8; j++)
                        a2[i][j] += xa[i] * wa[j];
            }
            __syncthreads();
        }

        #pragma unroll
        for (int i = 0; i < 2; i++) {
            int row = grow0 + ty * 2 + i;
            #pragma unroll
            for (int j = 0; j < 8; j++) a2[i][j] += bo[d0 + tx * 8 + j];
            float4 o0 = {a2[i][0], a2[i][1], a2[i][2], a2[i][3]};
            float4 o1 = {a2[i][4], a2[i][5], a2[i][6], a2[i][7]};
            *(float4*)(out + (size_t)row * DD + d0 + tx * 8)     = o0;
            *(float4*)(out + (size_t)row * DD + d0 + tx * 8 + 4) = o1;
        }
    }
}

extern "C" void kernel_launch(void* const* d_in, const int* in_sizes, int n_in,
                              void* d_out, int out_size, void* d_ws, size_t ws_size,
                              hipStream_t stream) {
    const float* x  = (const float*)d_in[0];
    const float* Wq = (const float*)d_in[1];
    const float* bq = (const float*)d_in[2];
    const float* Wk = (const float*)d_in[3];
    const float* bk = (const float*)d_in[4];
    const float* Wv = (const float*)d_in[5];
    const float* bv = (const float*)d_in[6];
    const float* Wo = (const float*)d_in[7];
    const float* bo = (const float*)d_in[8];
    float* out = (float*)d_out;

    float* ws = (float*)d_ws;
    float* Q = ws;
    float* K = ws + (size_t)BT * HH;
    float* V = ws + (size_t)2 * BT * HH;

    // scratch in ws (O slot now unused) and d_out (dead before epilogue
    // writes of out begin... NOTE: Z/G/Mpre live in ws to avoid any overlap
    // with out, since ochunk_out writes `out` while other blocks still read
    // their Z/Mpre):
    float* Z    = ws + (size_t)3 * BT * HH;          // 4 MB
    float* G    = ws + (size_t)4 * BT * HH;          // 4 MB
    float* Mpre = ws + (size_t)5 * BT * HH;          // 4 MB
    float* rn   = ws + (size_t)6 * BT * HH;          // 32 KB
    float* Sarr = rn + BT;                            // 32 KB

    // 1. K projection (+rn) — the scan's only dependency
    projk_kernel<<<BT / 32, 256, 0, stream>>>(x, Wk, bk, K, rn);

    // 2. fused: 4 scan blocks + 252 worker blocks (Q proj + s, V proj)
    fused_kernel<<<256, 512, 0, stream>>>(
        x, Wq, bq, Wv, bv, K, rn, Q, V, Sarr, Z);

    // 3. chunked phase-2
    dim3 ggrid(BB * NCH, 4);
    gram_kernel<<<ggrid, 256, 0, stream>>>(V, Z, Sarr, G);

    dim3 fgrid(BB, HH * HH / 256);
    prefix_kernel<<<fgrid, 256, 0, stream>>>(G, Mpre);

    // 4. ochunk + fused output projection (writes `out` directly)
    dim3 cgrid(BB * NCH, 4);
    ochunk_out_kernel<<<cgrid, 256, 0, stream>>>(
        Q, Z, Sarr, V, Mpre, Wo, bo, out);
}

// Round 16
// 1094.685 us; speedup vs baseline: 1.1186x; 1.0076x over previous
//
#include <hip/hip_runtime.h>
#include <math.h>

#define BB 4
#define TT 2048
#define DD 1024
#define HH 128
#define EPSF 1e-6f
#define BT (BB*TT)   // 8192
#define CC 128       // chunk length
#define NCH (TT/CC)  // 16 chunks per batch
#define NIC (CC/2)   // 64 double-steps per chunk
#define NSCAN (BB*NCH)  // 64 chunk-scan blocks

typedef float f32x2 __attribute__((ext_vector_type(2)));

// 8-lane butterfly sum, pure DPP/VALU (no DS pipe)
__device__ __forceinline__ float red8(float x) {
    x += __int_as_float(__builtin_amdgcn_mov_dpp(__float_as_int(x), 0xB1,  0xF, 0xF, true));
    x += __int_as_float(__builtin_amdgcn_mov_dpp(__float_as_int(x), 0x4E,  0xF, 0xF, true));
    x += __int_as_float(__builtin_amdgcn_mov_dpp(__float_as_int(x), 0x141, 0xF, 0xF, true));
    return x;
}
// 16-lane butterfly sum (adds ROW_MIRROR)
__device__ __forceinline__ float red16(float x) {
    x = red8(x);
    x += __int_as_float(__builtin_amdgcn_mov_dpp(__float_as_int(x), 0x140, 0xF, 0xF, true));
    return x;
}

// ---------------------------------------------------------------------------
// 512-thread projection tile (v12-verified): P[row0..+64][0..128) = xW^T + b.
// mode 0 plain; mode 2: s = q.k epilogue (P is Q).
// ---------------------------------------------------------------------------
__device__ __forceinline__ void proj512(
    const float* __restrict__ x, const float* __restrict__ W,
    const float* __restrict__ bias, float* __restrict__ P,
    int row0, int mode, float* __restrict__ aux,
    const float* __restrict__ Kmat)
{
    __shared__ float xT[32][68];
    __shared__ float wT[32][132];

    const int tid = threadIdx.x;
    const int tx = tid & 15;
    const int ty = tid >> 4;       // 0..31, rows ty*2 .. +2

    float acc[2][8];
    #pragma unroll
    for (int i = 0; i < 2; i++)
        #pragma unroll
        for (int j = 0; j < 8; j++) acc[i][j] = 0.f;

    for (int k0 = 0; k0 < DD; k0 += 32) {
        {   int r = tid >> 3, cg = tid & 7;
            float4 v = *(const float4*)(x + (size_t)(row0 + r) * DD + k0 + cg * 4);
            xT[cg*4+0][r] = v.x; xT[cg*4+1][r] = v.y;
            xT[cg*4+2][r] = v.z; xT[cg*4+3][r] = v.w;
        }
        #pragma unroll
        for (int l = 0; l < 2; l++) {
            int f = tid + l * 512;
            int h = f >> 3, cg = f & 7;
            float4 v = *(const float4*)(W + (size_t)h * DD + k0 + cg * 4);
            wT[cg*4+0][h] = v.x; wT[cg*4+1][h] = v.y;
            wT[cg*4+2][h] = v.z; wT[cg*4+3][h] = v.w;
        }
        __syncthreads();
        #pragma unroll
        for (int kk = 0; kk < 32; kk++) {
            float2 xv = *(const float2*)&xT[kk][ty * 2];
            float4 w0 = *(const float4*)&wT[kk][tx * 8];
            float4 w1 = *(const float4*)&wT[kk][tx * 8 + 4];
            float xa[2] = {xv.x, xv.y};
            float wa[8] = {w0.x, w0.y, w0.z, w0.w, w1.x, w1.y, w1.z, w1.w};
            #pragma unroll
            for (int i = 0; i < 2; i++)
                #pragma unroll
                for (int j = 0; j < 8; j++)
                    acc[i][j] += xa[i] * wa[j];
        }
        __syncthreads();
    }

    #pragma unroll
    for (int i = 0; i < 2; i++) {
        int row = row0 + ty * 2 + i;
        #pragma unroll
        for (int j = 0; j < 8; j++) acc[i][j] += bias[tx * 8 + j];
        float4 o0 = {acc[i][0], acc[i][1], acc[i][2], acc[i][3]};
        float4 o1 = {acc[i][4], acc[i][5], acc[i][6], acc[i][7]};
        *(float4*)(P + (size_t)row * HH + tx * 8)     = o0;
        *(float4*)(P + (size_t)row * HH + tx * 8 + 4) = o1;
    }

    if (mode == 2) {                 // s = q . k
        #pragma unroll
        for (int i = 0; i < 2; i++) {
            int row = row0 + ty * 2 + i;
            float4 ka = *(const float4*)(Kmat + (size_t)row * HH + tx * 8);
            float4 kb = *(const float4*)(Kmat + (size_t)row * HH + tx * 8 + 4);
            float p = acc[i][0]*ka.x + acc[i][1]*ka.y + acc[i][2]*ka.z + acc[i][3]*ka.w
                    + acc[i][4]*kb.x + acc[i][5]*kb.y + acc[i][6]*kb.z + acc[i][7]*kb.w;
            p = red16(p);
            if (tx == 0) aux[row] = p;
        }
    }
}

// ---------------------------------------------------------------------------
// K projection + rn epilogue (v14-verified): 256 blocks x 256 threads.
// ---------------------------------------------------------------------------
__global__ __launch_bounds__(256) void projk_kernel(
    const float* __restrict__ x, const float* __restrict__ Wk,
    const float* __restrict__ bk, float* __restrict__ K,
    float* __restrict__ rn)
{
    const int row0 = blockIdx.x * 32;

    __shared__ float xT[32][36];
    __shared__ float wT[32][132];

    const int tid = threadIdx.x;
    const int tx = tid & 15;
    const int ty = tid >> 4;       // 0..15, rows ty*2..+2

    float acc[2][8];
    #pragma unroll
    for (int i = 0; i < 2; i++)
        #pragma unroll
        for (int j = 0; j < 8; j++) acc[i][j] = 0.f;

    for (int k0 = 0; k0 < DD; k0 += 32) {
        {   int r = tid >> 3, cg = tid & 7;
            float4 v = *(const float4*)(x + (size_t)(row0 + r) * DD + k0 + cg * 4);
            xT[cg*4+0][r] = v.x; xT[cg*4+1][r] = v.y;
            xT[cg*4+2][r] = v.z; xT[cg*4+3][r] = v.w;
        }
        #pragma unroll
        for (int l = 0; l < 4; l++) {
            int f = tid + l * 256;
            int h = f >> 3, cg = f & 7;
            float4 v = *(const float4*)(Wk + (size_t)h * DD + k0 + cg * 4);
            wT[cg*4+0][h] = v.x; wT[cg*4+1][h] = v.y;
            wT[cg*4+2][h] = v.z; wT[cg*4+3][h] = v.w;
        }
        __syncthreads();
        #pragma unroll
        for (int kk = 0; kk < 32; kk++) {
            float2 xv = *(const float2*)&xT[kk][ty * 2];
            float4 w0 = *(const float4*)&wT[kk][tx * 8];
            float4 w1 = *(const float4*)&wT[kk][tx * 8 + 4];
            float xa[2] = {xv.x, xv.y};
            float wa[8] = {w0.x, w0.y, w0.z, w0.w, w1.x, w1.y, w1.z, w1.w};
            #pragma unroll
            for (int i = 0; i < 2; i++)
                #pragma unroll
                for (int j = 0; j < 8; j++)
                    acc[i][j] += xa[i] * wa[j];
        }
        __syncthreads();
    }

    #pragma unroll
    for (int i = 0; i < 2; i++) {
        int row = row0 + ty * 2 + i;
        #pragma unroll
        for (int j = 0; j < 8; j++) acc[i][j] += bk[tx * 8 + j];
        float4 o0 = {acc[i][0], acc[i][1], acc[i][2], acc[i][3]};
        float4 o1 = {acc[i][4], acc[i][5], acc[i][6], acc[i][7]};
        *(float4*)(K + (size_t)row * HH + tx * 8)     = o0;
        *(float4*)(K + (size_t)row * HH + tx * 8 + 4) = o1;
        float p = 0.f;
        #pragma unroll
        for (int j = 0; j < 8; j++) p += acc[i][j] * acc[i][j];
        p = red16(p);
        if (tx == 0) rn[row] = 1.0f / (sqrtf(p) + EPSF);
    }
}

// ---------------------------------------------------------------------------
// H[b][c] = sum_{t in chunk} (rn k)(rn k)^T. Grid (64, 4), 32 rows/block.
// (gram_kernel structure with both operands rn-scaled K.)
// ---------------------------------------------------------------------------
__global__ __launch_bounds__(256) void ugram_kernel(
    const float* __restrict__ K, const float* __restrict__ rn,
    float* __restrict__ H)
{
    const int bi = blockIdx.x;
    const int r0 = blockIdx.y * 32;

    const float* Kc = K + (size_t)bi * CC * HH;
    const float* Rc = rn + (size_t)bi * CC;

    __shared__ float vT[32][36];
    __shared__ float aT[32][132];

    const int tid = threadIdx.x;
    const int tx = tid & 15, ty = tid >> 4;

    float acc[2][8];
    #pragma unroll
    for (int i = 0; i < 2; i++)
        #pragma unroll
        for (int j = 0; j < 8; j++) acc[i][j] = 0.f;

    for (int s0 = 0; s0 < CC; s0 += 32) {
        {   int sr = tid >> 3, rc4 = tid & 7;
            float sc = Rc[s0 + sr];
            float4 v = *(const float4*)(Kc + (size_t)(s0 + sr) * HH + r0 + rc4 * 4);
            v.x *= sc; v.y *= sc; v.z *= sc; v.w *= sc;
            *(float4*)&vT[sr][rc4 * 4] = v;
        }
        #pragma unroll
        for (int l = 0; l < 4; l++) {
            int f = tid + l * 256;
            int sr = f >> 5, cc = f & 31;
            float sc = Rc[s0 + sr];
            float4 v = *(const float4*)(Kc + (size_t)(s0 + sr) * HH + cc * 4);
            v.x *= sc; v.y *= sc; v.z *= sc; v.w *= sc;
            *(float4*)&aT[sr][cc * 4] = v;
        }
        __syncthreads();
        #pragma unroll
        for (int ss = 0; ss < 32; ss++) {
            float2 vv = *(const float2*)&vT[ss][ty * 2];
            float4 a0 = *(const float4*)&aT[ss][tx * 8];
            float4 a1 = *(const float4*)&aT[ss][tx * 8 + 4];
            float va[2] = {vv.x, vv.y};
            float aa[8] = {a0.x, a0.y, a0.z, a0.w, a1.x, a1.y, a1.z, a1.w};
            #pragma unroll
            for (int i = 0; i < 2; i++)
                #pragma unroll
                for (int j = 0; j < 8; j++)
                    acc[i][j] += va[i] * aa[j];
        }
        __syncthreads();
    }

    #pragma unroll
    for (int i = 0; i < 2; i++) {
        float* hp = H + ((size_t)bi * HH + r0 + ty * 2 + i) * HH + tx * 8;
        float4 o0 = {acc[i][0], acc[i][1], acc[i][2], acc[i][3]};
        float4 o1 = {acc[i][4], acc[i][5], acc[i][6], acc[i][7]};
        *(float4*)hp       = o0;
        *(float4*)(hp + 4) = o1;
    }
}

// ---------------------------------------------------------------------------
// B_start(c) = I + sum_{c'<c} H[c'] (lambda0 = 1). Exclusive prefix.
// ---------------------------------------------------------------------------
__global__ __launch_bounds__(256) void bprefix_kernel(
    const float* __restrict__ H, float* __restrict__ Bm)
{
    const int b   = blockIdx.x;
    const int idx = blockIdx.y * 256 + threadIdx.x;
    const int row = idx >> 7, col = idx & 127;
    float run = (row == col) ? 1.0f : 0.0f;
    for (int i = 0; i < NCH; i++) {
        size_t off = ((size_t)b * NCH + i) * HH * HH + idx;
        Bm[off] = run;
        run += H[off];
    }
}

// ---------------------------------------------------------------------------
// Invert 128x128 SPD B -> Ainv, one block per matrix. Register-blocked
// Gauss-Jordan: thread (tr,tc) owns the 8x8 block rows tr*8.. cols tc*8..
// No pivoting needed: B = I + PSD => every pivot (Schur complement diag)
// >= lambda_min(B) >= 1. In-place GJ (verified on 2x2):
//   p=M[k][k]; row k: M[k][j!=k]/=p, M[k][k]=1/p;
//   rows i!=k: f=M[i][k]; M[i][j!=k]-=f*M[k][j]; M[i][k]=-f/p.
// Row-k / col-k exchanged via 128-float LDS buffers.
// ---------------------------------------------------------------------------
__global__ __launch_bounds__(256) void invert_kernel(
    const float* __restrict__ Bm, float* __restrict__ Ainv)
{
    const int bi  = blockIdx.x;
    const int tid = threadIdx.x;
    const int tr  = tid >> 4;      // row block 0..15
    const int tc  = tid & 15;      // col block 0..15
    const float* Bp = Bm  + (size_t)bi * HH * HH;
    float*       Ap = Ainv + (size_t)bi * HH * HH;

    __shared__ float rowk[HH];
    __shared__ float colk[HH];
    __shared__ float dsh;

    float M[8][8];
    #pragma unroll
    for (int ii = 0; ii < 8; ii++) {
        float4 a = *(const float4*)(Bp + (size_t)(tr*8+ii) * HH + tc*8);
        float4 b = *(const float4*)(Bp + (size_t)(tr*8+ii) * HH + tc*8 + 4);
        M[ii][0]=a.x; M[ii][1]=a.y; M[ii][2]=a.z; M[ii][3]=a.w;
        M[ii][4]=b.x; M[ii][5]=b.y; M[ii][6]=b.z; M[ii][7]=b.w;
    }

    for (int k = 0; k < HH; k++) {
        const int krb = k >> 3, kl = k & 7;
        if (tr == krb && tc == krb) dsh = M[kl][kl];
        __syncthreads();
        const float ip = 1.0f / dsh;
        if (tr == krb) {           // scale row k in-register + publish
            #pragma unroll
            for (int jj = 0; jj < 8; jj++) {
                float v = (tc == krb && jj == kl) ? ip : M[kl][jj] * ip;
                M[kl][jj] = v;
                rowk[tc*8 + jj] = v;
            }
        }
        if (tc == krb) {           // publish pre-update column k (f values)
            #pragma unroll
            for (int ii = 0; ii < 8; ii++)
                colk[tr*8 + ii] = M[ii][kl];
        }
        __syncthreads();
        float rk[8];
        #pragma unroll
        for (int jj = 0; jj < 8; jj++) rk[jj] = rowk[tc*8 + jj];
        #pragma unroll
        for (int ii = 0; ii < 8; ii++) {
            const int gr = tr*8 + ii;
            if (gr == k) continue;            // row k already final
            const float f = colk[gr];
            #pragma unroll
            for (int jj = 0; jj < 8; jj++) {
                if (tc == krb && jj == kl) M[ii][jj] = -f * ip;
                else                       M[ii][jj] = fmaf(-f, rk[jj], M[ii][jj]);
            }
        }
        __syncthreads();
    }

    #pragma unroll
    for (int ii = 0; ii < 8; ii++) {
        float4 a = {M[ii][0], M[ii][1], M[ii][2], M[ii][3]};
        float4 b = {M[ii][4], M[ii][5], M[ii][6], M[ii][7]};
        *(float4*)(Ap + (size_t)(tr*8+ii) * HH + tc*8)     = a;
        *(float4*)(Ap + (size_t)(tr*8+ii) * HH + tc*8 + 4) = b;
    }
}

// ---------------------------------------------------------------------------
// scanqv: blocks 0..63 = PARALLEL chunk-scans (v8 double-step body, verified;
// 64 steps each; A initialized from Ainv = B_start^{-1}); blocks 64..255 =
// Q (+s) and V projection workers (v12 pattern, zero dependency, no polling).
// ---------------------------------------------------------------------------
__global__ __launch_bounds__(512, 1) void scanqv_kernel(
    const float* __restrict__ x,
    const float* __restrict__ Wq, const float* __restrict__ bq,
    const float* __restrict__ Wv, const float* __restrict__ bv,
    const float* __restrict__ K, const float* __restrict__ rn,
    const float* __restrict__ Ainv,
    float* __restrict__ Q, float* __restrict__ V,
    float* __restrict__ Sarr, float* __restrict__ Z)
{
    __shared__ float Ybc[2][2][8 * 20];   // [buf][y1/y2], padded
    __shared__ float kst[2][2][8 * 20];   // [buf][k1/k2], padded

    if (blockIdx.x >= NSCAN) {
        const int wb = blockIdx.x - NSCAN;       // 0..191
        for (int t = wb; t < 256; t += 256 - NSCAN) {
            const int which = t >> 7;            // 0 = Q, 1 = V
            const int tile  = t & 127;
            if (which == 0)
                proj512(x, Wq, bq, Q, tile * 64, 2, Sarr, K);
            else
                proj512(x, Wv, bv, V, tile * 64, 0, nullptr, nullptr);
        }
        return;
    }

    // ---- chunk-scan path (v8 rank-2 A-only body; A from Ainv)
    const int bi  = blockIdx.x;          // b*NCH + c
    const int tid = threadIdx.x;
    const int r2  = tid >> 3;
    const int o8  = tid & 7;
    const int c0  = o8 * 16;
    const int r0  = 2 * r2, r1 = r0 + 1;

    const float* Kb   = K  + (size_t)bi * CC * HH;
    float*       Zb   = Z  + (size_t)bi * CC * HH;
    const float* rn_b = rn + (size_t)bi * CC;
    const float* Ap   = Ainv + (size_t)bi * HH * HH;

    f32x2 Ar0[8], Ar1[8];
    #pragma unroll
    for (int j = 0; j < 4; j++) {
        float4 a0 = *(const float4*)(Ap + (size_t)r0 * HH + c0 + 4 * j);
        float4 a1 = *(const float4*)(Ap + (size_t)r1 * HH + c0 + 4 * j);
        Ar0[2*j] = (f32x2){a0.x, a0.y}; Ar0[2*j+1] = (f32x2){a0.z, a0.w};
        Ar1[2*j] = (f32x2){a1.x, a1.y}; Ar1[2*j+1] = (f32x2){a1.z, a1.w};
    }

    const int woff = (r0 >> 4) * 20 + (r0 & 15);
    const int roff = o8 * 20;

    const bool ldr    = tid < 64;
    const int  whichk = tid >> 5;
    const int  l32    = tid & 31;
    const int  lpoff  = (l32 >> 2) * 20 + (l32 & 3) * 4;   // v8 8x20 mapping

    float4 pld = {0.f, 0.f, 0.f, 0.f};
    if (ldr) {
        float4 d0 = *(const float4*)(Kb + (size_t)whichk * HH + l32 * 4);
        *(float4*)&kst[0][whichk][lpoff] = d0;
        pld = *(const float4*)(Kb + (size_t)(2 + whichk) * HH + l32 * 4);
    }
    float2 rs_cur = ((const float2*)rn_b)[0];
    float2 rs_nxt = ((const float2*)rn_b)[1];
    __syncthreads();

    f32x2 k1[8], k2[8];
    #pragma unroll
    for (int j = 0; j < 4; j++) {
        float4 t1 = *(const float4*)&kst[0][0][roff + 4 * j];
        float4 t2 = *(const float4*)&kst[0][1][roff + 4 * j];
        k1[2*j] = (f32x2){t1.x, t1.y}; k1[2*j+1] = (f32x2){t1.z, t1.w};
        k2[2*j] = (f32x2){t2.x, t2.y}; k2[2*j+1] = (f32x2){t2.z, t2.w};
    }

    for (int i = 0; i < NIC; ++i) {
        const int yb = i & 1;
        const int nk = (i + 1) & 1;

        f32x2 y10 = {0,0}, y11 = {0,0}, y20 = {0,0}, y21 = {0,0};
        #pragma unroll
        for (int j = 0; j < 8; j++) {
            y10 += Ar0[j] * k1[j];
            y11 += Ar1[j] * k1[j];
            y20 += Ar0[j] * k2[j];
            y21 += Ar1[j] * k2[j];
        }
        float y1r0 = red8(y10.x + y10.y);
        float y1r1 = red8(y11.x + y11.y);
        float y2r0 = red8(y20.x + y20.y);
        float y2r1 = red8(y21.x + y21.y);
        if (o8 == 0) {
            *(float2*)&Ybc[yb][0][woff] = make_float2(y1r0, y1r1);
            *(float2*)&Ybc[yb][1][woff] = make_float2(y2r0, y2r1);
        }

        if (ldr && i + 1 < NIC) {
            *(float4*)&kst[nk][whichk][lpoff] = pld;
            if (i + 2 < NIC)
                pld = *(const float4*)(Kb + (size_t)(2*(i+2) + whichk) * HH + l32 * 4);
        }

        __syncthreads();

        f32x2 av1[8], av2[8];
        #pragma unroll
        for (int j = 0; j < 4; j++) {
            float4 t1 = *(const float4*)&Ybc[yb][0][roff + 4 * j];
            float4 t2 = *(const float4*)&Ybc[yb][1][roff + 4 * j];
            av1[2*j] = (f32x2){t1.x, t1.y}; av1[2*j+1] = (f32x2){t1.z, t1.w};
            av2[2*j] = (f32x2){t2.x, t2.y}; av2[2*j+1] = (f32x2){t2.z, t2.w};
        }

        f32x2 e11v = {0,0}, e21v = {0,0}, e22v = {0,0};
        #pragma unroll
        for (int j = 0; j < 8; j++) {
            e11v += av1[j] * k1[j];
            e21v += av1[j] * k2[j];
            e22v += av2[j] * k2[j];
        }
        float e11 = red8(e11v.x + e11v.y);
        float e21 = red8(e21v.x + e21v.y);
        float e22 = red8(e22v.x + e22v.y);

        #pragma unroll
        for (int j = 0; j < 4; j++) {
            float4 t1 = *(const float4*)&kst[nk][0][roff + 4 * j];
            float4 t2 = *(const float4*)&kst[nk][1][roff + 4 * j];
            k1[2*j] = (f32x2){t1.x, t1.y}; k1[2*j+1] = (f32x2){t1.z, t1.w};
            k2[2*j] = (f32x2){t2.x, t2.y}; k2[2*j+1] = (f32x2){t2.z, t2.w};
        }

        const float rn1 = rs_cur.x, rn2 = rs_cur.y;
        const float rn1sq = rn1 * rn1;
        const float rn2sq = rn2 * rn2;
        const float i1   = __builtin_amdgcn_rcpf(1.0f + rn1sq * e11);
        const float beta = rn1sq * e21 * i1;
        const float i2   = __builtin_amdgcn_rcpf(1.0f + rn2sq * (e22 - beta * e21));
        const float p2r0 = y2r0 - beta * y1r0;
        const float p2r1 = y2r1 - beta * y1r1;
        const float za1  = rn1 * i1;
        const float za2  = rn2 * i2;
        if (o8 == 0) {
            *(float2*)(Zb + (size_t)(2*i)     * HH + r0) =
                make_float2(za1 * y1r0, za1 * y1r1);
            *(float2*)(Zb + (size_t)(2*i + 1) * HH + r0) =
                make_float2(za2 * p2r0, za2 * p2r1);
        }

        const float cA1 = rn1sq * i1, cA2 = rn2sq * i2;
        const f32x2 u10 = {cA1 * y1r0, cA1 * y1r0};
        const f32x2 u11 = {cA1 * y1r1, cA1 * y1r1};
        const f32x2 u20 = {cA2 * p2r0, cA2 * p2r0};
        const f32x2 u21 = {cA2 * p2r1, cA2 * p2r1};
        const f32x2 bbv = {beta, beta};
        #pragma unroll
        for (int j = 0; j < 8; j++) {
            f32x2 pp = av2[j] - bbv * av1[j];
            Ar0[j] = Ar0[j] - u10 * av1[j] - u20 * pp;
            Ar1[j] = Ar1[j] - u11 * av1[j] - u21 * pp;
        }

        rs_cur = rs_nxt;
        if (i + 2 < NIC) rs_nxt = ((const float2*)rn_b)[i + 2];
    }
}

// ---------------------------------------------------------------------------
// Phase 2a (v14-verified): G[b][c] = V_chunk^T @ (diag(s) Z_chunk).
// ---------------------------------------------------------------------------
__global__ __launch_bounds__(256) void gram_kernel(
    const float* __restrict__ V, const float* __restrict__ Z,
    const float* __restrict__ Sarr, float* __restrict__ G)
{
    const int bi = blockIdx.x;
    const int r0 = blockIdx.y * 32;

    const float* Vc = V + (size_t)bi * CC * HH;
    const float* Zc = Z + (size_t)bi * CC * HH;
    const float* Sc = Sarr + (size_t)bi * CC;

    __shared__ float vT[32][36];
    __shared__ float aT[32][132];

    const int tid = threadIdx.x;
    const int tx = tid & 15, ty = tid >> 4;

    float acc[2][8];
    #pragma unroll
    for (int i = 0; i < 2; i++)
        #pragma unroll
        for (int j = 0; j < 8; j++) acc[i][j] = 0.f;

    for (int s0 = 0; s0 < CC; s0 += 32) {
        {   int sr = tid >> 3, rc = tid & 7;
            float4 v = *(const float4*)(Vc + (size_t)(s0 + sr) * HH + r0 + rc * 4);
            *(float4*)&vT[sr][rc * 4] = v;
        }
        #pragma unroll
        for (int l = 0; l < 4; l++) {
            int f = tid + l * 256;
            int sr = f >> 5, cc = f & 31;
            float sv = Sc[s0 + sr];
            float4 v = *(const float4*)(Zc + (size_t)(s0 + sr) * HH + cc * 4);
            v.x *= sv; v.y *= sv; v.z *= sv; v.w *= sv;
            *(float4*)&aT[sr][cc * 4] = v;
        }
        __syncthreads();
        #pragma unroll
        for (int ss = 0; ss < 32; ss++) {
            float2 vv = *(const float2*)&vT[ss][ty * 2];
            float4 a0 = *(const float4*)&aT[ss][tx * 8];
            float4 a1 = *(const float4*)&aT[ss][tx * 8 + 4];
            float va[2] = {vv.x, vv.y};
            float aa[8] = {a0.x, a0.y, a0.z, a0.w, a1.x, a1.y, a1.z, a1.w};
            #pragma unroll
            for (int i = 0; i < 2; i++)
                #pragma unroll
                for (int j = 0; j < 8; j++)
                    acc[i][j] += va[i] * aa[j];
        }
        __syncthreads();
    }

    #pragma unroll
    for (int i = 0; i < 2; i++) {
        float* gp = G + ((size_t)bi * HH + r0 + ty * 2 + i) * HH + tx * 8;
        float4 o0 = {acc[i][0], acc[i][1], acc[i][2], acc[i][3]};
        float4 o1 = {acc[i][4], acc[i][5], acc[i][6], acc[i][7]};
        *(float4*)gp       = o0;
        *(float4*)(gp + 4) = o1;
    }
}

// ---------------------------------------------------------------------------
// Phase 2b (v14-verified): exclusive prefix Mpre.
// ---------------------------------------------------------------------------
__global__ __launch_bounds__(256) void prefix_kernel(
    const float* __restrict__ G, float* __restrict__ Mpre)
{
    const int b   = blockIdx.x;
    const int idx = blockIdx.y * 256 + threadIdx.x;
    float run = 0.f;
    for (int i = 0; i < NCH; i++) {
        size_t off = ((size_t)b * NCH + i) * HH * HH + idx;
        Mpre[off] = run;
        run += G[off];
    }
}

// ---------------------------------------------------------------------------
// Phase 2c (v14-verified): O = Q Mpre^T + tril(Q (sZ)^T) V. Grid (64,4).
// ---------------------------------------------------------------------------
__global__ __launch_bounds__(256) void ochunk_kernel(
    const float* __restrict__ Q, const float* __restrict__ Z,
    const float* __restrict__ Sarr, const float* __restrict__ V,
    const float* __restrict__ Mpre, float* __restrict__ O)
{
    const int bi = blockIdx.x;
    const int t0 = blockIdx.y * 32;

    const float* Qc = Q    + (size_t)bi * CC * HH;
    const float* Zc = Z    + (size_t)bi * CC * HH;
    const float* Vc = V    + (size_t)bi * CC * HH;
    const float* Sc = Sarr + (size_t)bi * CC;
    const float* Mp = Mpre + (size_t)bi * HH * HH;
    float*       Oc = O    + (size_t)bi * CC * HH;

    __shared__ float S[32][132];
    __shared__ float xT[32][36];
    __shared__ float wT[32][132];

    const int tid = threadIdx.x;
    const int tx = tid & 15, ty = tid >> 4;

    float acc[2][8];

    // ---- phase 1: S = tril(Q (sZ)^T)
    #pragma unroll
    for (int i = 0; i < 2; i++)
        #pragma unroll
        for (int j = 0; j < 8; j++) acc[i][j] = 0.f;
    for (int k0 = 0; k0 < HH; k0 += 32) {
        {   int r = tid >> 3, cg = tid & 7;
            float4 v = *(const float4*)(Qc + (size_t)(t0 + r) * HH + k0 + cg * 4);
            xT[cg*4+0][r] = v.x; xT[cg*4+1][r] = v.y;
            xT[cg*4+2][r] = v.z; xT[cg*4+3][r] = v.w;
        }
        #pragma unroll
        for (int l = 0; l < 4; l++) {
            int f = tid + l * 256;
            int sr = f >> 3, cg = f & 7;
            float sv = Sc[sr];
            float4 v = *(const float4*)(Zc + (size_t)sr * HH + k0 + cg * 4);
            wT[cg*4+0][sr] = v.x * sv; wT[cg*4+1][sr] = v.y * sv;
            wT[cg*4+2][sr] = v.z * sv; wT[cg*4+3][sr] = v.w * sv;
        }
        __syncthreads();
        #pragma unroll
        for (int kk = 0; kk < 32; kk++) {
            float2 xv = *(const float2*)&xT[kk][ty * 2];
            float4 w0 = *(const float4*)&wT[kk][tx * 8];
            float4 w1 = *(const float4*)&wT[kk][tx * 8 + 4];
            float xa[2] = {xv.x, xv.y};
            float wa[8] = {w0.x, w0.y, w0.z, w0.w, w1.x, w1.y, w1.z, w1.w};
            #pragma unroll
            for (int i = 0; i < 2; i++)
                #pragma unroll
                for (int j = 0; j < 8; j++)
                    acc[i][j] += xa[i] * wa[j];
        }
        __syncthreads();
    }
    #pragma unroll
    for (int i = 0; i < 2; i++) {
        int tl = t0 + ty * 2 + i;
        float m[8];
        #pragma unroll
        for (int j = 0; j < 8; j++)
            m[j] = (tx * 8 + j <= tl) ? acc[i][j] : 0.f;
        float4 o0 = {m[0], m[1], m[2], m[3]};
        float4 o1 = {m[4], m[5], m[6], m[7]};
        *(float4*)&S[ty*2+i][tx*8]     = o0;
        *(float4*)&S[ty*2+i][tx*8 + 4] = o1;
    }

    // ---- phase 2: acc = Q @ Mpre^T
    #pragma unroll
    for (int i = 0; i < 2; i++)
        #pragma unroll
        for (int j = 0; j < 8; j++) acc[i][j] = 0.f;
    for (int k0 = 0; k0 < HH; k0 += 32) {
        {   int r = tid >> 3, cg = tid & 7;
            float4 v = *(const float4*)(Qc + (size_t)(t0 + r) * HH + k0 + cg * 4);
            xT[cg*4+0][r] = v.x; xT[cg*4+1][r] = v.y;
            xT[cg*4+2][r] = v.z; xT[cg*4+3][r] = v.w;
        }
        #pragma unroll
        for (int l = 0; l < 4; l++) {
            int f = tid + l * 256;
            int h = f >> 3, cg = f & 7;
            float4 v = *(const float4*)(Mp + (size_t)h * HH + k0 + cg * 4);
            wT[cg*4+0][h] = v.x; wT[cg*4+1][h] = v.y;
            wT[cg*4+2][h] = v.z; wT[cg*4+3][h] = v.w;
        }
        __syncthreads();
        #pragma unroll
        for (int kk = 0; kk < 32; kk++) {
            float2 xv = *(const float2*)&xT[kk][ty * 2];
            float4 w0 = *(const float4*)&wT[kk][tx * 8];
            float4 w1 = *(const float4*)&wT[kk][tx * 8 + 4];
            float xa[2] = {xv.x, xv.y};
            float wa[8] = {w0.x, w0.y, w0.z, w0.w, w1.x, w1.y, w1.z, w1.w};
            #pragma unroll
            for (int i = 0; i < 2; i++)
                #pragma unroll
                for (int j = 0; j < 8; j++)
                    acc[i][j] += xa[i] * wa[j];
        }
        __syncthreads();
    }

    // ---- phase 3: acc += S @ V
    for (int s0 = 0; s0 < CC; s0 += 32) {
        #pragma unroll
        for (int l = 0; l < 4; l++) {
            int f = tid + l * 256;
            int sr = f >> 5, cc = f & 31;
            float4 v = *(const float4*)(Vc + (size_t)(s0 + sr) * HH + cc * 4);
            *(float4*)&wT[sr][cc * 4] = v;
        }
        __syncthreads();
        #pragma unroll
        for (int ss = 0; ss < 32; ss++) {
            float4 w0 = *(const float4*)&wT[ss][tx * 8];
            float4 w1 = *(const float4*)&wT[ss][tx * 8 + 4];
            float wa[8] = {w0.x, w0.y, w0.z, w0.w, w1.x, w1.y, w1.z, w1.w};
            float sv[2] = {S[ty*2][s0 + ss], S[ty*2+1][s0 + ss]};
            #pragma unroll
            for (int i = 0; i < 2; i++)
                #pragma unroll
                for (int j = 0; j < 8; j++)
                    acc[i][j] += sv[i] * wa[j];
        }
        __syncthreads();
    }

    #pragma unroll
    for (int i = 0; i < 2; i++) {
        float* op = Oc + (size_t)(t0 + ty * 2 + i) * HH + tx * 8;
        float4 o0 = {acc[i][0], acc[i][1], acc[i][2], acc[i][3]};
        float4 o1 = {acc[i][4], acc[i][5], acc[i][6], acc[i][7]};
        *(float4*)op       = o0;
        *(float4*)(op + 4) = o1;
    }
}

// ---------------------------------------------------------------------------
// Output (v14-verified): out = O Wo^T + bo.
// ---------------------------------------------------------------------------
__global__ __launch_bounds__(256) void out_kernel(
    const float* __restrict__ O, const float* __restrict__ Wo,
    const float* __restrict__ bo, float* __restrict__ out)
{
    const int row0 = blockIdx.x * 64;
    const int d0   = blockIdx.y * 128;

    __shared__ float oT[32][68];
    __shared__ float woT[32][132];

    const int tid = threadIdx.x;
    const int tx = tid & 15;
    const int ty = tid >> 4;

    float acc[4][8];
    #pragma unroll
    for (int i = 0; i < 4; i++)
        #pragma unroll
        for (int j = 0; j < 8; j++) acc[i][j] = 0.f;

    for (int k0 = 0; k0 < HH; k0 += 32) {
        #pragma unroll
        for (int l = 0; l < 2; l++) {
            int f = tid + l * 256;
            int r = f >> 3;
            int cg = f & 7;
            float4 v = *(const float4*)(O + (size_t)(row0 + r) * HH + k0 + cg * 4);
            oT[cg*4+0][r] = v.x; oT[cg*4+1][r] = v.y;
            oT[cg*4+2][r] = v.z; oT[cg*4+3][r] = v.w;
        }
        #pragma unroll
        for (int l = 0; l < 4; l++) {
            int f = tid + l * 256;
            int d = f >> 3;
            int cg = f & 7;
            float4 v = *(const float4*)(Wo + (size_t)(d0 + d) * HH + k0 + cg * 4);
            woT[cg*4+0][d] = v.x; woT[cg*4+1][d] = v.y;
            woT[cg*4+2][d] = v.z; woT[cg*4+3][d] = v.w;
        }
        __syncthreads();
        #pragma unroll
        for (int kk = 0; kk < 32; kk++) {
            float4 ov = *(const float4*)&oT[kk][ty * 4];
            float4 w0 = *(const float4*)&woT[kk][tx * 8];
            float4 w1 = *(const float4*)&woT[kk][tx * 8 + 4];
            float oa[4] = {ov.x, ov.y, ov.z, ov.w};
            float wa[8] = {w0.x, w0.y, w0.z, w0.w, w1.x, w1.y, w1.z, w1.w};
            #pragma unroll
            for (int i = 0; i < 4; i++)
                #pragma unroll
                for (int j = 0; j < 8; j++)
                    acc[i][j] += oa[i] * wa[j];
        }
        __syncthreads();
    }

    #pragma unroll
    for (int i = 0; i < 4; i++) {
        int row = row0 + ty * 4 + i;
        #pragma unroll
        for (int j = 0; j < 8; j++) acc[i][j] += bo[d0 + tx * 8 + j];
        float4 o0 = {acc[i][0], acc[i][1], acc[i][2], acc[i][3]};
        float4 o1 = {acc[i][4], acc[i][5], acc[i][6], acc[i][7]};
        *(float4*)(out + (size_t)row * DD + d0 + tx * 8)     = o0;
        *(float4*)(out + (size_t)row * DD + d0 + tx * 8 + 4) = o1;
    }
}

extern "C" void kernel_launch(void* const* d_in, const int* in_sizes, int n_in,
                              void* d_out, int out_size, void* d_ws, size_t ws_size,
                              hipStream_t stream) {
    const float* x  = (const float*)d_in[0];
    const float* Wq = (const float*)d_in[1];
    const float* bq = (const float*)d_in[2];
    const float* Wk = (const float*)d_in[3];
    const float* bk = (const float*)d_in[4];
    const float* Wv = (const float*)d_in[5];
    const float* bv = (const float*)d_in[6];
    const float* Wo = (const float*)d_in[7];
    const float* bo = (const float*)d_in[8];
    float* out = (float*)d_out;

    float* ws = (float*)d_ws;
    float* Q = ws;
    float* K = ws + (size_t)BT * HH;
    float* V = ws + (size_t)2 * BT * HH;
    float* O = ws + (size_t)3 * BT * HH;

    // d_out scratch (32 MB), all dead before out_kernel writes out:
    //   rn @0 | Sarr @32KB | Z @1MB | G @8MB | Mpre @12MB | H @16MB
    //   Bmat @20MB | Ainv @24MB
    float* db   = (float*)d_out;
    float* rn   = db;
    float* Sarr = db + BT;
    float* Z    = db + (size_t)(1u << 18);
    float* G    = db + (size_t)(1u << 21);
    float* Mpre = db + (size_t)3 * (1u << 20);
    float* H    = db + (size_t)4 * (1u << 20);
    float* Bmat = db + (size_t)5 * (1u << 20);
    float* Ainv = db + (size_t)6 * (1u << 20);

    // 1. K projection (+rn)
    projk_kernel<<<BT / 32, 256, 0, stream>>>(x, Wk, bk, K, rn);

    // 2. chunk-start inverse-Gram pipeline: H -> B_start -> A_start
    dim3 hg(NSCAN, 4);
    ugram_kernel<<<hg, 256, 0, stream>>>(K, rn, H);
    dim3 bp(BB, HH * HH / 256);
    bprefix_kernel<<<bp, 256, 0, stream>>>(H, Bmat);
    invert_kernel<<<NSCAN, 256, 0, stream>>>(Bmat, Ainv);

    // 3. 64 parallel chunk-scans + Q/V projection workers
    scanqv_kernel<<<256, 512, 0, stream>>>(
        x, Wq, bq, Wv, bv, K, rn, Ainv, Q, V, Sarr, Z);

    // 4. phase-2 (alpha = s*z folded into staging) + output
    dim3 gg(NSCAN, 4);
    gram_kernel<<<gg, 256, 0, stream>>>(V, Z, Sarr, G);
    prefix_kernel<<<bp, 256, 0, stream>>>(G, Mpre);
    dim3 cg(NSCAN, 4);
    ochunk_kernel<<<cg, 256, 0, stream>>>(Q, Z, Sarr, V, Mpre, O);
    dim3 og(BT / 64, DD / 128);
    out_kernel<<<og, 256, 0, stream>>>(O, Wo, bo, out);
}

// Round 17
// 499.991 us; speedup vs baseline: 2.4490x; 2.1894x over previous
//
#include <hip/hip_runtime.h>
#include <math.h>

#define BB 4
#define TT 2048
#define DD 1024
#define HH 128
#define EPSF 1e-6f
#define BT (BB*TT)   // 8192
#define CC 128       // chunk length
#define NCH (TT/CC)  // 16 chunks per batch
#define NIC (CC/2)   // 64 double-steps per chunk
#define NSCAN (BB*NCH)  // 64 chunk-scan blocks

typedef float f32x2 __attribute__((ext_vector_type(2)));

// 8-lane butterfly sum, pure DPP/VALU (no DS pipe)
__device__ __forceinline__ float red8(float x) {
    x += __int_as_float(__builtin_amdgcn_mov_dpp(__float_as_int(x), 0xB1,  0xF, 0xF, true));
    x += __int_as_float(__builtin_amdgcn_mov_dpp(__float_as_int(x), 0x4E,  0xF, 0xF, true));
    x += __int_as_float(__builtin_amdgcn_mov_dpp(__float_as_int(x), 0x141, 0xF, 0xF, true));
    return x;
}
// 16-lane butterfly sum (adds ROW_MIRROR)
__device__ __forceinline__ float red16(float x) {
    x = red8(x);
    x += __int_as_float(__builtin_amdgcn_mov_dpp(__float_as_int(x), 0x140, 0xF, 0xF, true));
    return x;
}

// ---------------------------------------------------------------------------
// 512-thread projection tile (v12-verified): P[row0..+64][0..128) = xW^T + b.
// mode 0 plain; mode 2: s = q.k epilogue (P is Q).
// ---------------------------------------------------------------------------
__device__ __forceinline__ void proj512(
    const float* __restrict__ x, const float* __restrict__ W,
    const float* __restrict__ bias, float* __restrict__ P,
    int row0, int mode, float* __restrict__ aux,
    const float* __restrict__ Kmat)
{
    __shared__ float xT[32][68];
    __shared__ float wT[32][132];

    const int tid = threadIdx.x;
    const int tx = tid & 15;
    const int ty = tid >> 4;       // 0..31, rows ty*2 .. +2

    float acc[2][8];
    #pragma unroll
    for (int i = 0; i < 2; i++)
        #pragma unroll
        for (int j = 0; j < 8; j++) acc[i][j] = 0.f;

    for (int k0 = 0; k0 < DD; k0 += 32) {
        {   int r = tid >> 3, cg = tid & 7;
            float4 v = *(const float4*)(x + (size_t)(row0 + r) * DD + k0 + cg * 4);
            xT[cg*4+0][r] = v.x; xT[cg*4+1][r] = v.y;
            xT[cg*4+2][r] = v.z; xT[cg*4+3][r] = v.w;
        }
        #pragma unroll
        for (int l = 0; l < 2; l++) {
            int f = tid + l * 512;
            int h = f >> 3, cg = f & 7;
            float4 v = *(const float4*)(W + (size_t)h * DD + k0 + cg * 4);
            wT[cg*4+0][h] = v.x; wT[cg*4+1][h] = v.y;
            wT[cg*4+2][h] = v.z; wT[cg*4+3][h] = v.w;
        }
        __syncthreads();
        #pragma unroll
        for (int kk = 0; kk < 32; kk++) {
            float2 xv = *(const float2*)&xT[kk][ty * 2];
            float4 w0 = *(const float4*)&wT[kk][tx * 8];
            float4 w1 = *(const float4*)&wT[kk][tx * 8 + 4];
            float xa[2] = {xv.x, xv.y};
            float wa[8] = {w0.x, w0.y, w0.z, w0.w, w1.x, w1.y, w1.z, w1.w};
            #pragma unroll
            for (int i = 0; i < 2; i++)
                #pragma unroll
                for (int j = 0; j < 8; j++)
                    acc[i][j] += xa[i] * wa[j];
        }
        __syncthreads();
    }

    #pragma unroll
    for (int i = 0; i < 2; i++) {
        int row = row0 + ty * 2 + i;
        #pragma unroll
        for (int j = 0; j < 8; j++) acc[i][j] += bias[tx * 8 + j];
        float4 o0 = {acc[i][0], acc[i][1], acc[i][2], acc[i][3]};
        float4 o1 = {acc[i][4], acc[i][5], acc[i][6], acc[i][7]};
        *(float4*)(P + (size_t)row * HH + tx * 8)     = o0;
        *(float4*)(P + (size_t)row * HH + tx * 8 + 4) = o1;
    }

    if (mode == 2) {                 // s = q . k
        #pragma unroll
        for (int i = 0; i < 2; i++) {
            int row = row0 + ty * 2 + i;
            float4 ka = *(const float4*)(Kmat + (size_t)row * HH + tx * 8);
            float4 kb = *(const float4*)(Kmat + (size_t)row * HH + tx * 8 + 4);
            float p = acc[i][0]*ka.x + acc[i][1]*ka.y + acc[i][2]*ka.z + acc[i][3]*ka.w
                    + acc[i][4]*kb.x + acc[i][5]*kb.y + acc[i][6]*kb.z + acc[i][7]*kb.w;
            p = red16(p);
            if (tx == 0) aux[row] = p;
        }
    }
}

// ---------------------------------------------------------------------------
// K projection + rn epilogue (v14-verified): 256 blocks x 256 threads.
// ---------------------------------------------------------------------------
__global__ __launch_bounds__(256) void projk_kernel(
    const float* __restrict__ x, const float* __restrict__ Wk,
    const float* __restrict__ bk, float* __restrict__ K,
    float* __restrict__ rn)
{
    const int row0 = blockIdx.x * 32;

    __shared__ float xT[32][36];
    __shared__ float wT[32][132];

    const int tid = threadIdx.x;
    const int tx = tid & 15;
    const int ty = tid >> 4;       // 0..15, rows ty*2..+2

    float acc[2][8];
    #pragma unroll
    for (int i = 0; i < 2; i++)
        #pragma unroll
        for (int j = 0; j < 8; j++) acc[i][j] = 0.f;

    for (int k0 = 0; k0 < DD; k0 += 32) {
        {   int r = tid >> 3, cg = tid & 7;
            float4 v = *(const float4*)(x + (size_t)(row0 + r) * DD + k0 + cg * 4);
            xT[cg*4+0][r] = v.x; xT[cg*4+1][r] = v.y;
            xT[cg*4+2][r] = v.z; xT[cg*4+3][r] = v.w;
        }
        #pragma unroll
        for (int l = 0; l < 4; l++) {
            int f = tid + l * 256;
            int h = f >> 3, cg = f & 7;
            float4 v = *(const float4*)(Wk + (size_t)h * DD + k0 + cg * 4);
            wT[cg*4+0][h] = v.x; wT[cg*4+1][h] = v.y;
            wT[cg*4+2][h] = v.z; wT[cg*4+3][h] = v.w;
        }
        __syncthreads();
        #pragma unroll
        for (int kk = 0; kk < 32; kk++) {
            float2 xv = *(const float2*)&xT[kk][ty * 2];
            float4 w0 = *(const float4*)&wT[kk][tx * 8];
            float4 w1 = *(const float4*)&wT[kk][tx * 8 + 4];
            float xa[2] = {xv.x, xv.y};
            float wa[8] = {w0.x, w0.y, w0.z, w0.w, w1.x, w1.y, w1.z, w1.w};
            #pragma unroll
            for (int i = 0; i < 2; i++)
                #pragma unroll
                for (int j = 0; j < 8; j++)
                    acc[i][j] += xa[i] * wa[j];
        }
        __syncthreads();
    }

    #pragma unroll
    for (int i = 0; i < 2; i++) {
        int row = row0 + ty * 2 + i;
        #pragma unroll
        for (int j = 0; j < 8; j++) acc[i][j] += bk[tx * 8 + j];
        float4 o0 = {acc[i][0], acc[i][1], acc[i][2], acc[i][3]};
        float4 o1 = {acc[i][4], acc[i][5], acc[i][6], acc[i][7]};
        *(float4*)(K + (size_t)row * HH + tx * 8)     = o0;
        *(float4*)(K + (size_t)row * HH + tx * 8 + 4) = o1;
        float p = 0.f;
        #pragma unroll
        for (int j = 0; j < 8; j++) p += acc[i][j] * acc[i][j];
        p = red16(p);
        if (tx == 0) rn[row] = 1.0f / (sqrtf(p) + EPSF);
    }
}

// ---------------------------------------------------------------------------
// H[b][c] = sum_{t in chunk} (rn k)(rn k)^T. Grid (64, 4), 32 rows/block.
// ---------------------------------------------------------------------------
__global__ __launch_bounds__(256) void ugram_kernel(
    const float* __restrict__ K, const float* __restrict__ rn,
    float* __restrict__ H)
{
    const int bi = blockIdx.x;
    const int r0 = blockIdx.y * 32;

    const float* Kc = K + (size_t)bi * CC * HH;
    const float* Rc = rn + (size_t)bi * CC;

    __shared__ float vT[32][36];
    __shared__ float aT[32][132];

    const int tid = threadIdx.x;
    const int tx = tid & 15, ty = tid >> 4;

    float acc[2][8];
    #pragma unroll
    for (int i = 0; i < 2; i++)
        #pragma unroll
        for (int j = 0; j < 8; j++) acc[i][j] = 0.f;

    for (int s0 = 0; s0 < CC; s0 += 32) {
        {   int sr = tid >> 3, rc4 = tid & 7;
            float sc = Rc[s0 + sr];
            float4 v = *(const float4*)(Kc + (size_t)(s0 + sr) * HH + r0 + rc4 * 4);
            v.x *= sc; v.y *= sc; v.z *= sc; v.w *= sc;
            *(float4*)&vT[sr][rc4 * 4] = v;
        }
        #pragma unroll
        for (int l = 0; l < 4; l++) {
            int f = tid + l * 256;
            int sr = f >> 5, cc = f & 31;
            float sc = Rc[s0 + sr];
            float4 v = *(const float4*)(Kc + (size_t)(s0 + sr) * HH + cc * 4);
            v.x *= sc; v.y *= sc; v.z *= sc; v.w *= sc;
            *(float4*)&aT[sr][cc * 4] = v;
        }
        __syncthreads();
        #pragma unroll
        for (int ss = 0; ss < 32; ss++) {
            float2 vv = *(const float2*)&vT[ss][ty * 2];
            float4 a0 = *(const float4*)&aT[ss][tx * 8];
            float4 a1 = *(const float4*)&aT[ss][tx * 8 + 4];
            float va[2] = {vv.x, vv.y};
            float aa[8] = {a0.x, a0.y, a0.z, a0.w, a1.x, a1.y, a1.z, a1.w};
            #pragma unroll
            for (int i = 0; i < 2; i++)
                #pragma unroll
                for (int j = 0; j < 8; j++)
                    acc[i][j] += va[i] * aa[j];
        }
        __syncthreads();
    }

    #pragma unroll
    for (int i = 0; i < 2; i++) {
        float* hp = H + ((size_t)bi * HH + r0 + ty * 2 + i) * HH + tx * 8;
        float4 o0 = {acc[i][0], acc[i][1], acc[i][2], acc[i][3]};
        float4 o1 = {acc[i][4], acc[i][5], acc[i][6], acc[i][7]};
        *(float4*)hp       = o0;
        *(float4*)(hp + 4) = o1;
    }
}

// ---------------------------------------------------------------------------
// B_start(c) = I + sum_{c'<c} H[c'] (lambda0 = 1). Exclusive prefix.
// ---------------------------------------------------------------------------
__global__ __launch_bounds__(256) void bprefix_kernel(
    const float* __restrict__ H, float* __restrict__ Bm)
{
    const int b   = blockIdx.x;
    const int idx = blockIdx.y * 256 + threadIdx.x;
    const int row = idx >> 7, col = idx & 127;
    float run = (row == col) ? 1.0f : 0.0f;
    for (int i = 0; i < NCH; i++) {
        size_t off = ((size_t)b * NCH + i) * HH * HH + idx;
        Bm[off] = run;
        run += H[off];
    }
}

// ---------------------------------------------------------------------------
// Invert 128x128 SPD B -> Ainv, one block per matrix. Register-blocked
// Gauss-Jordan, thread (tr,tc) owns 8x8 block. v18 algorithm (verified),
// restructured so ALL M-indices are COMPILE-TIME (krb runtime x kl unrolled)
// -> M stays in VGPRs (v18 had runtime kl -> scratch spill, 654us).
// No pivoting needed: B = I + PSD => pivots >= 1.
// ---------------------------------------------------------------------------
__global__ __launch_bounds__(256) void invert_kernel(
    const float* __restrict__ Bm, float* __restrict__ Ainv)
{
    const int bi  = blockIdx.x;
    const int tid = threadIdx.x;
    const int tr  = tid >> 4;      // row block 0..15
    const int tc  = tid & 15;      // col block 0..15
    const float* Bp = Bm  + (size_t)bi * HH * HH;
    float*       Ap = Ainv + (size_t)bi * HH * HH;

    __shared__ float rowk[HH];
    __shared__ float colk[HH];
    __shared__ float dsh;

    float M[8][8];
    #pragma unroll
    for (int ii = 0; ii < 8; ii++) {
        float4 a = *(const float4*)(Bp + (size_t)(tr*8+ii) * HH + tc*8);
        float4 b = *(const float4*)(Bp + (size_t)(tr*8+ii) * HH + tc*8 + 4);
        M[ii][0]=a.x; M[ii][1]=a.y; M[ii][2]=a.z; M[ii][3]=a.w;
        M[ii][4]=b.x; M[ii][5]=b.y; M[ii][6]=b.z; M[ii][7]=b.w;
    }

    for (int krb = 0; krb < 16; krb++) {
        const bool myrow = (tr == krb);
        const bool mycol = (tc == krb);
        #pragma unroll
        for (int kl = 0; kl < 8; kl++) {
            if (myrow && mycol) dsh = M[kl][kl];
            __syncthreads();
            const float ip = 1.0f / dsh;
            if (myrow) {               // scale row k + publish
                #pragma unroll
                for (int jj = 0; jj < 8; jj++) {
                    float v = (mycol && jj == kl) ? ip : M[kl][jj] * ip;
                    M[kl][jj] = v;
                    rowk[tc*8 + jj] = v;
                }
            }
            if (mycol) {               // publish pre-update column k entries
                #pragma unroll
                for (int ii = 0; ii < 8; ii++)
                    colk[tr*8 + ii] = M[ii][kl];
            }
            __syncthreads();
            float rk[8];
            #pragma unroll
            for (int jj = 0; jj < 8; jj++) rk[jj] = rowk[tc*8 + jj];
            #pragma unroll
            for (int ii = 0; ii < 8; ii++) {
                const bool isk = myrow && (ii == kl);   // row k already final
                const float f = colk[tr*8 + ii];
                #pragma unroll
                for (int jj = 0; jj < 8; jj++) {
                    float upd = (mycol && jj == kl)
                              ? (-f * ip)
                              : fmaf(-f, rk[jj], M[ii][jj]);
                    M[ii][jj] = isk ? M[ii][jj] : upd;
                }
            }
            __syncthreads();
        }
    }

    #pragma unroll
    for (int ii = 0; ii < 8; ii++) {
        float4 a = {M[ii][0], M[ii][1], M[ii][2], M[ii][3]};
        float4 b = {M[ii][4], M[ii][5], M[ii][6], M[ii][7]};
        *(float4*)(Ap + (size_t)(tr*8+ii) * HH + tc*8)     = a;
        *(float4*)(Ap + (size_t)(tr*8+ii) * HH + tc*8 + 4) = b;
    }
}

// ---------------------------------------------------------------------------
// scanqv: blocks 0..63 = PARALLEL chunk-scans (v8 double-step body, verified;
// 64 steps each; A initialized from Ainv = B_start^{-1}); blocks 64..255 =
// Q (+s) and V projection workers (v12 pattern, zero dependency, no polling).
// ---------------------------------------------------------------------------
__global__ __launch_bounds__(512, 1) void scanqv_kernel(
    const float* __restrict__ x,
    const float* __restrict__ Wq, const float* __restrict__ bq,
    const float* __restrict__ Wv, const float* __restrict__ bv,
    const float* __restrict__ K, const float* __restrict__ rn,
    const float* __restrict__ Ainv,
    float* __restrict__ Q, float* __restrict__ V,
    float* __restrict__ Sarr, float* __restrict__ Z)
{
    __shared__ float Ybc[2][2][8 * 20];   // [buf][y1/y2], padded
    __shared__ float kst[2][2][8 * 20];   // [buf][k1/k2], padded

    if (blockIdx.x >= NSCAN) {
        const int wb = blockIdx.x - NSCAN;       // 0..191
        for (int t = wb; t < 256; t += 256 - NSCAN) {
            const int which = t >> 7;            // 0 = Q, 1 = V
            const int tile  = t & 127;
            if (which == 0)
                proj512(x, Wq, bq, Q, tile * 64, 2, Sarr, K);
            else
                proj512(x, Wv, bv, V, tile * 64, 0, nullptr, nullptr);
        }
        return;
    }

    // ---- chunk-scan path (v8 rank-2 A-only body; A from Ainv)
    const int bi  = blockIdx.x;          // b*NCH + c
    const int tid = threadIdx.x;
    const int r2  = tid >> 3;
    const int o8  = tid & 7;
    const int c0  = o8 * 16;
    const int r0  = 2 * r2, r1 = r0 + 1;

    const float* Kb   = K  + (size_t)bi * CC * HH;
    float*       Zb   = Z  + (size_t)bi * CC * HH;
    const float* rn_b = rn + (size_t)bi * CC;
    const float* Ap   = Ainv + (size_t)bi * HH * HH;

    f32x2 Ar0[8], Ar1[8];
    #pragma unroll
    for (int j = 0; j < 4; j++) {
        float4 a0 = *(const float4*)(Ap + (size_t)r0 * HH + c0 + 4 * j);
        float4 a1 = *(const float4*)(Ap + (size_t)r1 * HH + c0 + 4 * j);
        Ar0[2*j] = (f32x2){a0.x, a0.y}; Ar0[2*j+1] = (f32x2){a0.z, a0.w};
        Ar1[2*j] = (f32x2){a1.x, a1.y}; Ar1[2*j+1] = (f32x2){a1.z, a1.w};
    }

    const int woff = (r0 >> 4) * 20 + (r0 & 15);
    const int roff = o8 * 20;

    const bool ldr    = tid < 64;
    const int  whichk = tid >> 5;
    const int  l32    = tid & 31;
    const int  lpoff  = (l32 >> 2) * 20 + (l32 & 3) * 4;   // v8 8x20 mapping

    float4 pld = {0.f, 0.f, 0.f, 0.f};
    if (ldr) {
        float4 d0 = *(const float4*)(Kb + (size_t)whichk * HH + l32 * 4);
        *(float4*)&kst[0][whichk][lpoff] = d0;
        pld = *(const float4*)(Kb + (size_t)(2 + whichk) * HH + l32 * 4);
    }
    float2 rs_cur = ((const float2*)rn_b)[0];
    float2 rs_nxt = ((const float2*)rn_b)[1];
    __syncthreads();

    f32x2 k1[8], k2[8];
    #pragma unroll
    for (int j = 0; j < 4; j++) {
        float4 t1 = *(const float4*)&kst[0][0][roff + 4 * j];
        float4 t2 = *(const float4*)&kst[0][1][roff + 4 * j];
        k1[2*j] = (f32x2){t1.x, t1.y}; k1[2*j+1] = (f32x2){t1.z, t1.w};
        k2[2*j] = (f32x2){t2.x, t2.y}; k2[2*j+1] = (f32x2){t2.z, t2.w};
    }

    for (int i = 0; i < NIC; ++i) {
        const int yb = i & 1;
        const int nk = (i + 1) & 1;

        f32x2 y10 = {0,0}, y11 = {0,0}, y20 = {0,0}, y21 = {0,0};
        #pragma unroll
        for (int j = 0; j < 8; j++) {
            y10 += Ar0[j] * k1[j];
            y11 += Ar1[j] * k1[j];
            y20 += Ar0[j] * k2[j];
            y21 += Ar1[j] * k2[j];
        }
        float y1r0 = red8(y10.x + y10.y);
        float y1r1 = red8(y11.x + y11.y);
        float y2r0 = red8(y20.x + y20.y);
        float y2r1 = red8(y21.x + y21.y);
        if (o8 == 0) {
            *(float2*)&Ybc[yb][0][woff] = make_float2(y1r0, y1r1);
            *(float2*)&Ybc[yb][1][woff] = make_float2(y2r0, y2r1);
        }

        if (ldr && i + 1 < NIC) {
            *(float4*)&kst[nk][whichk][lpoff] = pld;
            if (i + 2 < NIC)
                pld = *(const float4*)(Kb + (size_t)(2*(i+2) + whichk) * HH + l32 * 4);
        }

        __syncthreads();

        f32x2 av1[8], av2[8];
        #pragma unroll
        for (int j = 0; j < 4; j++) {
            float4 t1 = *(const float4*)&Ybc[yb][0][roff + 4 * j];
            float4 t2 = *(const float4*)&Ybc[yb][1][roff + 4 * j];
            av1[2*j] = (f32x2){t1.x, t1.y}; av1[2*j+1] = (f32x2){t1.z, t1.w};
            av2[2*j] = (f32x2){t2.x, t2.y}; av2[2*j+1] = (f32x2){t2.z, t2.w};
        }

        f32x2 e11v = {0,0}, e21v = {0,0}, e22v = {0,0};
        #pragma unroll
        for (int j = 0; j < 8; j++) {
            e11v += av1[j] * k1[j];
            e21v += av1[j] * k2[j];
            e22v += av2[j] * k2[j];
        }
        float e11 = red8(e11v.x + e11v.y);
        float e21 = red8(e21v.x + e21v.y);
        float e22 = red8(e22v.x + e22v.y);

        #pragma unroll
        for (int j = 0; j < 4; j++) {
            float4 t1 = *(const float4*)&kst[nk][0][roff + 4 * j];
            float4 t2 = *(const float4*)&kst[nk][1][roff + 4 * j];
            k1[2*j] = (f32x2){t1.x, t1.y}; k1[2*j+1] = (f32x2){t1.z, t1.w};
            k2[2*j] = (f32x2){t2.x, t2.y}; k2[2*j+1] = (f32x2){t2.z, t2.w};
        }

        const float rn1 = rs_cur.x, rn2 = rs_cur.y;
        const float rn1sq = rn1 * rn1;
        const float rn2sq = rn2 * rn2;
        const float i1   = __builtin_amdgcn_rcpf(1.0f + rn1sq * e11);
        const float beta = rn1sq * e21 * i1;
        const float i2   = __builtin_amdgcn_rcpf(1.0f + rn2sq * (e22 - beta * e21));
        const float p2r0 = y2r0 - beta * y1r0;
        const float p2r1 = y2r1 - beta * y1r1;
        const float za1  = rn1 * i1;
        const float za2  = rn2 * i2;
        if (o8 == 0) {
            *(float2*)(Zb + (size_t)(2*i)     * HH + r0) =
                make_float2(za1 * y1r0, za1 * y1r1);
            *(float2*)(Zb + (size_t)(2*i + 1) * HH + r0) =
                make_float2(za2 * p2r0, za2 * p2r1);
        }

        const float cA1 = rn1sq * i1, cA2 = rn2sq * i2;
        const f32x2 u10 = {cA1 * y1r0, cA1 * y1r0};
        const f32x2 u11 = {cA1 * y1r1, cA1 * y1r1};
        const f32x2 u20 = {cA2 * p2r0, cA2 * p2r0};
        const f32x2 u21 = {cA2 * p2r1, cA2 * p2r1};
        const f32x2 bbv = {beta, beta};
        #pragma unroll
        for (int j = 0; j < 8; j++) {
            f32x2 pp = av2[j] - bbv * av1[j];
            Ar0[j] = Ar0[j] - u10 * av1[j] - u20 * pp;
            Ar1[j] = Ar1[j] - u11 * av1[j] - u21 * pp;
        }

        rs_cur = rs_nxt;
        if (i + 2 < NIC) rs_nxt = ((const float2*)rn_b)[i + 2];
    }
}

// ---------------------------------------------------------------------------
// Phase 2a (v14-verified): G[b][c] = V_chunk^T @ (diag(s) Z_chunk).
// ---------------------------------------------------------------------------
__global__ __launch_bounds__(256) void gram_kernel(
    const float* __restrict__ V, const float* __restrict__ Z,
    const float* __restrict__ Sarr, float* __restrict__ G)
{
    const int bi = blockIdx.x;
    const int r0 = blockIdx.y * 32;

    const float* Vc = V + (size_t)bi * CC * HH;
    const float* Zc = Z + (size_t)bi * CC * HH;
    const float* Sc = Sarr + (size_t)bi * CC;

    __shared__ float vT[32][36];
    __shared__ float aT[32][132];

    const int tid = threadIdx.x;
    const int tx = tid & 15, ty = tid >> 4;

    float acc[2][8];
    #pragma unroll
    for (int i = 0; i < 2; i++)
        #pragma unroll
        for (int j = 0; j < 8; j++) acc[i][j] = 0.f;

    for (int s0 = 0; s0 < CC; s0 += 32) {
        {   int sr = tid >> 3, rc = tid & 7;
            float4 v = *(const float4*)(Vc + (size_t)(s0 + sr) * HH + r0 + rc * 4);
            *(float4*)&vT[sr][rc * 4] = v;
        }
        #pragma unroll
        for (int l = 0; l < 4; l++) {
            int f = tid + l * 256;
            int sr = f >> 5, cc = f & 31;
            float sv = Sc[s0 + sr];
            float4 v = *(const float4*)(Zc + (size_t)(s0 + sr) * HH + cc * 4);
            v.x *= sv; v.y *= sv; v.z *= sv; v.w *= sv;
            *(float4*)&aT[sr][cc * 4] = v;
        }
        __syncthreads();
        #pragma unroll
        for (int ss = 0; ss < 32; ss++) {
            float2 vv = *(const float2*)&vT[ss][ty * 2];
            float4 a0 = *(const float4*)&aT[ss][tx * 8];
            float4 a1 = *(const float4*)&aT[ss][tx * 8 + 4];
            float va[2] = {vv.x, vv.y};
            float aa[8] = {a0.x, a0.y, a0.z, a0.w, a1.x, a1.y, a1.z, a1.w};
            #pragma unroll
            for (int i = 0; i < 2; i++)
                #pragma unroll
                for (int j = 0; j < 8; j++)
                    acc[i][j] += va[i] * aa[j];
        }
        __syncthreads();
    }

    #pragma unroll
    for (int i = 0; i < 2; i++) {
        float* gp = G + ((size_t)bi * HH + r0 + ty * 2 + i) * HH + tx * 8;
        float4 o0 = {acc[i][0], acc[i][1], acc[i][2], acc[i][3]};
        float4 o1 = {acc[i][4], acc[i][5], acc[i][6], acc[i][7]};
        *(float4*)gp       = o0;
        *(float4*)(gp + 4) = o1;
    }
}

// ---------------------------------------------------------------------------
// Phase 2b (v14-verified): exclusive prefix Mpre.
// ---------------------------------------------------------------------------
__global__ __launch_bounds__(256) void prefix_kernel(
    const float* __restrict__ G, float* __restrict__ Mpre)
{
    const int b   = blockIdx.x;
    const int idx = blockIdx.y * 256 + threadIdx.x;
    float run = 0.f;
    for (int i = 0; i < NCH; i++) {
        size_t off = ((size_t)b * NCH + i) * HH * HH + idx;
        Mpre[off] = run;
        run += G[off];
    }
}

// ---------------------------------------------------------------------------
// Phase 2c (v14-verified): O = Q Mpre^T + tril(Q (sZ)^T) V. Grid (64,4).
// ---------------------------------------------------------------------------
__global__ __launch_bounds__(256) void ochunk_kernel(
    const float* __restrict__ Q, const float* __restrict__ Z,
    const float* __restrict__ Sarr, const float* __restrict__ V,
    const float* __restrict__ Mpre, float* __restrict__ O)
{
    const int bi = blockIdx.x;
    const int t0 = blockIdx.y * 32;

    const float* Qc = Q    + (size_t)bi * CC * HH;
    const float* Zc = Z    + (size_t)bi * CC * HH;
    const float* Vc = V    + (size_t)bi * CC * HH;
    const float* Sc = Sarr + (size_t)bi * CC;
    const float* Mp = Mpre + (size_t)bi * HH * HH;
    float*       Oc = O    + (size_t)bi * CC * HH;

    __shared__ float S[32][132];
    __shared__ float xT[32][36];
    __shared__ float wT[32][132];

    const int tid = threadIdx.x;
    const int tx = tid & 15, ty = tid >> 4;

    float acc[2][8];

    // ---- phase 1: S = tril(Q (sZ)^T)
    #pragma unroll
    for (int i = 0; i < 2; i++)
        #pragma unroll
        for (int j = 0; j < 8; j++) acc[i][j] = 0.f;
    for (int k0 = 0; k0 < HH; k0 += 32) {
        {   int r = tid >> 3, cg = tid & 7;
            float4 v = *(const float4*)(Qc + (size_t)(t0 + r) * HH + k0 + cg * 4);
            xT[cg*4+0][r] = v.x; xT[cg*4+1][r] = v.y;
            xT[cg*4+2][r] = v.z; xT[cg*4+3][r] = v.w;
        }
        #pragma unroll
        for (int l = 0; l < 4; l++) {
            int f = tid + l * 256;
            int sr = f >> 3, cg = f & 7;
            float sv = Sc[sr];
            float4 v = *(const float4*)(Zc + (size_t)sr * HH + k0 + cg * 4);
            wT[cg*4+0][sr] = v.x * sv; wT[cg*4+1][sr] = v.y * sv;
            wT[cg*4+2][sr] = v.z * sv; wT[cg*4+3][sr] = v.w * sv;
        }
        __syncthreads();
        #pragma unroll
        for (int kk = 0; kk < 32; kk++) {
            float2 xv = *(const float2*)&xT[kk][ty * 2];
            float4 w0 = *(const float4*)&wT[kk][tx * 8];
            float4 w1 = *(const float4*)&wT[kk][tx * 8 + 4];
            float xa[2] = {xv.x, xv.y};
            float wa[8] = {w0.x, w0.y, w0.z, w0.w, w1.x, w1.y, w1.z, w1.w};
            #pragma unroll
            for (int i = 0; i < 2; i++)
                #pragma unroll
                for (int j = 0; j < 8; j++)
                    acc[i][j] += xa[i] * wa[j];
        }
        __syncthreads();
    }
    #pragma unroll
    for (int i = 0; i < 2; i++) {
        int tl = t0 + ty * 2 + i;
        float m[8];
        #pragma unroll
        for (int j = 0; j < 8; j++)
            m[j] = (tx * 8 + j <= tl) ? acc[i][j] : 0.f;
        float4 o0 = {m[0], m[1], m[2], m[3]};
        float4 o1 = {m[4], m[5], m[6], m[7]};
        *(float4*)&S[ty*2+i][tx*8]     = o0;
        *(float4*)&S[ty*2+i][tx*8 + 4] = o1;
    }

    // ---- phase 2: acc = Q @ Mpre^T
    #pragma unroll
    for (int i = 0; i < 2; i++)
        #pragma unroll
        for (int j = 0; j < 8; j++) acc[i][j] = 0.f;
    for (int k0 = 0; k0 < HH; k0 += 32) {
        {   int r = tid >> 3, cg = tid & 7;
            float4 v = *(const float4*)(Qc + (size_t)(t0 + r) * HH + k0 + cg * 4);
            xT[cg*4+0][r] = v.x; xT[cg*4+1][r] = v.y;
            xT[cg*4+2][r] = v.z; xT[cg*4+3][r] = v.w;
        }
        #pragma unroll
        for (int l = 0; l < 4; l++) {
            int f = tid + l * 256;
            int h = f >> 3, cg = f & 7;
            float4 v = *(const float4*)(Mp + (size_t)h * HH + k0 + cg * 4);
            wT[cg*4+0][h] = v.x; wT[cg*4+1][h] = v.y;
            wT[cg*4+2][h] = v.z; wT[cg*4+3][h] = v.w;
        }
        __syncthreads();
        #pragma unroll
        for (int kk = 0; kk < 32; kk++) {
            float2 xv = *(const float2*)&xT[kk][ty * 2];
            float4 w0 = *(const float4*)&wT[kk][tx * 8];
            float4 w1 = *(const float4*)&wT[kk][tx * 8 + 4];
            float xa[2] = {xv.x, xv.y};
            float wa[8] = {w0.x, w0.y, w0.z, w0.w, w1.x, w1.y, w1.z, w1.w};
            #pragma unroll
            for (int i = 0; i < 2; i++)
                #pragma unroll
                for (int j = 0; j < 8; j++)
                    acc[i][j] += xa[i] * wa[j];
        }
        __syncthreads();
    }

    // ---- phase 3: acc += S @ V
    for (int s0 = 0; s0 < CC; s0 += 32) {
        #pragma unroll
        for (int l = 0; l < 4; l++) {
            int f = tid + l * 256;
            int sr = f >> 5, cc = f & 31;
            float4 v = *(const float4*)(Vc + (size_t)(s0 + sr) * HH + cc * 4);
            *(float4*)&wT[sr][cc * 4] = v;
        }
        __syncthreads();
        #pragma unroll
        for (int ss = 0; ss < 32; ss++) {
            float4 w0 = *(const float4*)&wT[ss][tx * 8];
            float4 w1 = *(const float4*)&wT[ss][tx * 8 + 4];
            float wa[8] = {w0.x, w0.y, w0.z, w0.w, w1.x, w1.y, w1.z, w1.w};
            float sv[2] = {S[ty*2][s0 + ss], S[ty*2+1][s0 + ss]};
            #pragma unroll
            for (int i = 0; i < 2; i++)
                #pragma unroll
                for (int j = 0; j < 8; j++)
                    acc[i][j] += sv[i] * wa[j];
        }
        __syncthreads();
    }

    #pragma unroll
    for (int i = 0; i < 2; i++) {
        float* op = Oc + (size_t)(t0 + ty * 2 + i) * HH + tx * 8;
        float4 o0 = {acc[i][0], acc[i][1], acc[i][2], acc[i][3]};
        float4 o1 = {acc[i][4], acc[i][5], acc[i][6], acc[i][7]};
        *(float4*)op       = o0;
        *(float4*)(op + 4) = o1;
    }
}

// ---------------------------------------------------------------------------
// Output (v14-verified): out = O Wo^T + bo.
// ---------------------------------------------------------------------------
__global__ __launch_bounds__(256) void out_kernel(
    const float* __restrict__ O, const float* __restrict__ Wo,
    const float* __restrict__ bo, float* __restrict__ out)
{
    const int row0 = blockIdx.x * 64;
    const int d0   = blockIdx.y * 128;

    __shared__ float oT[32][68];
    __shared__ float woT[32][132];

    const int tid = threadIdx.x;
    const int tx = tid & 15;
    const int ty = tid >> 4;

    float acc[4][8];
    #pragma unroll
    for (int i = 0; i < 4; i++)
        #pragma unroll
        for (int j = 0; j < 8; j++) acc[i][j] = 0.f;

    for (int k0 = 0; k0 < HH; k0 += 32) {
        #pragma unroll
        for (int l = 0; l < 2; l++) {
            int f = tid + l * 256;
            int r = f >> 3;
            int cg = f & 7;
            float4 v = *(const float4*)(O + (size_t)(row0 + r) * HH + k0 + cg * 4);
            oT[cg*4+0][r] = v.x; oT[cg*4+1][r] = v.y;
            oT[cg*4+2][r] = v.z; oT[cg*4+3][r] = v.w;
        }
        #pragma unroll
        for (int l = 0; l < 4; l++) {
            int f = tid + l * 256;
            int d = f >> 3;
            int cg = f & 7;
            float4 v = *(const float4*)(Wo + (size_t)(d0 + d) * HH + k0 + cg * 4);
            woT[cg*4+0][d] = v.x; woT[cg*4+1][d] = v.y;
            woT[cg*4+2][d] = v.z; woT[cg*4+3][d] = v.w;
        }
        __syncthreads();
        #pragma unroll
        for (int kk = 0; kk < 32; kk++) {
            float4 ov = *(const float4*)&oT[kk][ty * 4];
            float4 w0 = *(const float4*)&woT[kk][tx * 8];
            float4 w1 = *(const float4*)&woT[kk][tx * 8 + 4];
            float oa[4] = {ov.x, ov.y, ov.z, ov.w};
            float wa[8] = {w0.x, w0.y, w0.z, w0.w, w1.x, w1.y, w1.z, w1.w};
            #pragma unroll
            for (int i = 0; i < 4; i++)
                #pragma unroll
                for (int j = 0; j < 8; j++)
                    acc[i][j] += oa[i] * wa[j];
        }
        __syncthreads();
    }

    #pragma unroll
    for (int i = 0; i < 4; i++) {
        int row = row0 + ty * 4 + i;
        #pragma unroll
        for (int j = 0; j < 8; j++) acc[i][j] += bo[d0 + tx * 8 + j];
        float4 o0 = {acc[i][0], acc[i][1], acc[i][2], acc[i][3]};
        float4 o1 = {acc[i][4], acc[i][5], acc[i][6], acc[i][7]};
        *(float4*)(out + (size_t)row * DD + d0 + tx * 8)     = o0;
        *(float4*)(out + (size_t)row * DD + d0 + tx * 8 + 4) = o1;
    }
}

extern "C" void kernel_launch(void* const* d_in, const int* in_sizes, int n_in,
                              void* d_out, int out_size, void* d_ws, size_t ws_size,
                              hipStream_t stream) {
    const float* x  = (const float*)d_in[0];
    const float* Wq = (const float*)d_in[1];
    const float* bq = (const float*)d_in[2];
    const float* Wk = (const float*)d_in[3];
    const float* bk = (const float*)d_in[4];
    const float* Wv = (const float*)d_in[5];
    const float* bv = (const float*)d_in[6];
    const float* Wo = (const float*)d_in[7];
    const float* bo = (const float*)d_in[8];
    float* out = (float*)d_out;

    float* ws = (float*)d_ws;
    float* Q = ws;
    float* K = ws + (size_t)BT * HH;
    float* V = ws + (size_t)2 * BT * HH;
    float* O = ws + (size_t)3 * BT * HH;

    // d_out scratch (32 MB), all dead before out_kernel writes out:
    //   rn @0 | Sarr @32KB | Z @1MB | G @8MB | Mpre @12MB | H @16MB
    //   Bmat @20MB | Ainv @24MB
    float* db   = (float*)d_out;
    float* rn   = db;
    float* Sarr = db + BT;
    float* Z    = db + (size_t)(1u << 18);
    float* G    = db + (size_t)(1u << 21);
    float* Mpre = db + (size_t)3 * (1u << 20);
    float* H    = db + (size_t)4 * (1u << 20);
    float* Bmat = db + (size_t)5 * (1u << 20);
    float* Ainv = db + (size_t)6 * (1u << 20);

    // 1. K projection (+rn)
    projk_kernel<<<BT / 32, 256, 0, stream>>>(x, Wk, bk, K, rn);

    // 2. chunk-start inverse-Gram pipeline: H -> B_start -> A_start
    dim3 hg(NSCAN, 4);
    ugram_kernel<<<hg, 256, 0, stream>>>(K, rn, H);
    dim3 bp(BB, HH * HH / 256);
    bprefix_kernel<<<bp, 256, 0, stream>>>(H, Bmat);
    invert_kernel<<<NSCAN, 256, 0, stream>>>(Bmat, Ainv);

    // 3. 64 parallel chunk-scans + Q/V projection workers
    scanqv_kernel<<<256, 512, 0, stream>>>(
        x, Wq, bq, Wv, bv, K, rn, Ainv, Q, V, Sarr, Z);

    // 4. phase-2 (alpha = s*z folded into staging) + output
    dim3 gg(NSCAN, 4);
    gram_kernel<<<gg, 256, 0, stream>>>(V, Z, Sarr, G);
    prefix_kernel<<<bp, 256, 0, stream>>>(G, Mpre);
    dim3 cg(NSCAN, 4);
    ochunk_kernel<<<cg, 256, 0, stream>>>(Q, Z, Sarr, V, Mpre, O);
    dim3 og(BT / 64, DD / 128);
    out_kernel<<<og, 256, 0, stream>>>(O, Wo, bo, out);
}

// Round 18
// 459.768 us; speedup vs baseline: 2.6633x; 1.0875x over previous
//
#include <hip/hip_runtime.h>
#include <math.h>

#define BB 4
#define TT 2048
#define DD 1024
#define HH 128
#define EPSF 1e-6f
#define BT (BB*TT)   // 8192
#define CC 128       // chunk length
#define NCH (TT/CC)  // 16 chunks per batch
#define NIC (CC/2)   // 64 double-steps per chunk
#define NSCAN (BB*NCH)  // 64 chunk-scan blocks

typedef float f32x2 __attribute__((ext_vector_type(2)));

// 8-lane butterfly sum, pure DPP/VALU (no DS pipe)
__device__ __forceinline__ float red8(float x) {
    x += __int_as_float(__builtin_amdgcn_mov_dpp(__float_as_int(x), 0xB1,  0xF, 0xF, true));
    x += __int_as_float(__builtin_amdgcn_mov_dpp(__float_as_int(x), 0x4E,  0xF, 0xF, true));
    x += __int_as_float(__builtin_amdgcn_mov_dpp(__float_as_int(x), 0x141, 0xF, 0xF, true));
    return x;
}
// 16-lane butterfly sum (adds ROW_MIRROR)
__device__ __forceinline__ float red16(float x) {
    x = red8(x);
    x += __int_as_float(__builtin_amdgcn_mov_dpp(__float_as_int(x), 0x140, 0xF, 0xF, true));
    return x;
}

// ---------------------------------------------------------------------------
// K projection + rn epilogue (verified): 256 blocks x 256 threads.
// ---------------------------------------------------------------------------
__global__ __launch_bounds__(256) void projk_kernel(
    const float* __restrict__ x, const float* __restrict__ Wk,
    const float* __restrict__ bk, float* __restrict__ K,
    float* __restrict__ rn)
{
    const int row0 = blockIdx.x * 32;

    __shared__ float xT[32][36];
    __shared__ float wT[32][132];

    const int tid = threadIdx.x;
    const int tx = tid & 15;
    const int ty = tid >> 4;       // 0..15, rows ty*2..+2

    float acc[2][8];
    #pragma unroll
    for (int i = 0; i < 2; i++)
        #pragma unroll
        for (int j = 0; j < 8; j++) acc[i][j] = 0.f;

    for (int k0 = 0; k0 < DD; k0 += 32) {
        {   int r = tid >> 3, cg = tid & 7;
            float4 v = *(const float4*)(x + (size_t)(row0 + r) * DD + k0 + cg * 4);
            xT[cg*4+0][r] = v.x; xT[cg*4+1][r] = v.y;
            xT[cg*4+2][r] = v.z; xT[cg*4+3][r] = v.w;
        }
        #pragma unroll
        for (int l = 0; l < 4; l++) {
            int f = tid + l * 256;
            int h = f >> 3, cg = f & 7;
            float4 v = *(const float4*)(Wk + (size_t)h * DD + k0 + cg * 4);
            wT[cg*4+0][h] = v.x; wT[cg*4+1][h] = v.y;
            wT[cg*4+2][h] = v.z; wT[cg*4+3][h] = v.w;
        }
        __syncthreads();
        #pragma unroll
        for (int kk = 0; kk < 32; kk++) {
            float2 xv = *(const float2*)&xT[kk][ty * 2];
            float4 w0 = *(const float4*)&wT[kk][tx * 8];
            float4 w1 = *(const float4*)&wT[kk][tx * 8 + 4];
            float xa[2] = {xv.x, xv.y};
            float wa[8] = {w0.x, w0.y, w0.z, w0.w, w1.x, w1.y, w1.z, w1.w};
            #pragma unroll
            for (int i = 0; i < 2; i++)
                #pragma unroll
                for (int j = 0; j < 8; j++)
                    acc[i][j] += xa[i] * wa[j];
        }
        __syncthreads();
    }

    #pragma unroll
    for (int i = 0; i < 2; i++) {
        int row = row0 + ty * 2 + i;
        #pragma unroll
        for (int j = 0; j < 8; j++) acc[i][j] += bk[tx * 8 + j];
        float4 o0 = {acc[i][0], acc[i][1], acc[i][2], acc[i][3]};
        float4 o1 = {acc[i][4], acc[i][5], acc[i][6], acc[i][7]};
        *(float4*)(K + (size_t)row * HH + tx * 8)     = o0;
        *(float4*)(K + (size_t)row * HH + tx * 8 + 4) = o1;
        float p = 0.f;
        #pragma unroll
        for (int j = 0; j < 8; j++) p += acc[i][j] * acc[i][j];
        p = red16(p);
        if (tx == 0) rn[row] = 1.0f / (sqrtf(p) + EPSF);
    }
}

// ---------------------------------------------------------------------------
// Q and V projection, FULL-GPU: grid (256, 2), 256 threads, 32-row tiles
// (projk's verified shape; 2x better FMA:DS ratio than proj512).
// blockIdx.y == 0 -> Q (+ s = q.k epilogue); == 1 -> V.
// ---------------------------------------------------------------------------
__global__ __launch_bounds__(256) void projqv_kernel(
    const float* __restrict__ x,
    const float* __restrict__ Wq, const float* __restrict__ bq,
    const float* __restrict__ Wv, const float* __restrict__ bv,
    const float* __restrict__ K,
    float* __restrict__ Q, float* __restrict__ V,
    float* __restrict__ Sarr)
{
    const int row0  = blockIdx.x * 32;
    const int isv   = blockIdx.y;
    const float* W    = isv ? Wv : Wq;
    const float* bias = isv ? bv : bq;
    float* P          = isv ? V  : Q;

    __shared__ float xT[32][36];
    __shared__ float wT[32][132];

    const int tid = threadIdx.x;
    const int tx = tid & 15;
    const int ty = tid >> 4;       // 0..15, rows ty*2..+2

    float acc[2][8];
    #pragma unroll
    for (int i = 0; i < 2; i++)
        #pragma unroll
        for (int j = 0; j < 8; j++) acc[i][j] = 0.f;

    for (int k0 = 0; k0 < DD; k0 += 32) {
        {   int r = tid >> 3, cg = tid & 7;
            float4 v = *(const float4*)(x + (size_t)(row0 + r) * DD + k0 + cg * 4);
            xT[cg*4+0][r] = v.x; xT[cg*4+1][r] = v.y;
            xT[cg*4+2][r] = v.z; xT[cg*4+3][r] = v.w;
        }
        #pragma unroll
        for (int l = 0; l < 4; l++) {
            int f = tid + l * 256;
            int h = f >> 3, cg = f & 7;
            float4 v = *(const float4*)(W + (size_t)h * DD + k0 + cg * 4);
            wT[cg*4+0][h] = v.x; wT[cg*4+1][h] = v.y;
            wT[cg*4+2][h] = v.z; wT[cg*4+3][h] = v.w;
        }
        __syncthreads();
        #pragma unroll
        for (int kk = 0; kk < 32; kk++) {
            float2 xv = *(const float2*)&xT[kk][ty * 2];
            float4 w0 = *(const float4*)&wT[kk][tx * 8];
            float4 w1 = *(const float4*)&wT[kk][tx * 8 + 4];
            float xa[2] = {xv.x, xv.y};
            float wa[8] = {w0.x, w0.y, w0.z, w0.w, w1.x, w1.y, w1.z, w1.w};
            #pragma unroll
            for (int i = 0; i < 2; i++)
                #pragma unroll
                for (int j = 0; j < 8; j++)
                    acc[i][j] += xa[i] * wa[j];
        }
        __syncthreads();
    }

    #pragma unroll
    for (int i = 0; i < 2; i++) {
        int row = row0 + ty * 2 + i;
        #pragma unroll
        for (int j = 0; j < 8; j++) acc[i][j] += bias[tx * 8 + j];
        float4 o0 = {acc[i][0], acc[i][1], acc[i][2], acc[i][3]};
        float4 o1 = {acc[i][4], acc[i][5], acc[i][6], acc[i][7]};
        *(float4*)(P + (size_t)row * HH + tx * 8)     = o0;
        *(float4*)(P + (size_t)row * HH + tx * 8 + 4) = o1;
    }

    if (!isv) {   // s = q . k epilogue
        #pragma unroll
        for (int i = 0; i < 2; i++) {
            int row = row0 + ty * 2 + i;
            float4 ka = *(const float4*)(K + (size_t)row * HH + tx * 8);
            float4 kb = *(const float4*)(K + (size_t)row * HH + tx * 8 + 4);
            float p = acc[i][0]*ka.x + acc[i][1]*ka.y + acc[i][2]*ka.z + acc[i][3]*ka.w
                    + acc[i][4]*kb.x + acc[i][5]*kb.y + acc[i][6]*kb.z + acc[i][7]*kb.w;
            p = red16(p);
            if (tx == 0) Sarr[row] = p;
        }
    }
}

// ---------------------------------------------------------------------------
// H[b][c] = sum_{t in chunk} (rn k)(rn k)^T. Grid (64, 4), 32 rows/block.
// ---------------------------------------------------------------------------
__global__ __launch_bounds__(256) void ugram_kernel(
    const float* __restrict__ K, const float* __restrict__ rn,
    float* __restrict__ H)
{
    const int bi = blockIdx.x;
    const int r0 = blockIdx.y * 32;

    const float* Kc = K + (size_t)bi * CC * HH;
    const float* Rc = rn + (size_t)bi * CC;

    __shared__ float vT[32][36];
    __shared__ float aT[32][132];

    const int tid = threadIdx.x;
    const int tx = tid & 15, ty = tid >> 4;

    float acc[2][8];
    #pragma unroll
    for (int i = 0; i < 2; i++)
        #pragma unroll
        for (int j = 0; j < 8; j++) acc[i][j] = 0.f;

    for (int s0 = 0; s0 < CC; s0 += 32) {
        {   int sr = tid >> 3, rc4 = tid & 7;
            float sc = Rc[s0 + sr];
            float4 v = *(const float4*)(Kc + (size_t)(s0 + sr) * HH + r0 + rc4 * 4);
            v.x *= sc; v.y *= sc; v.z *= sc; v.w *= sc;
            *(float4*)&vT[sr][rc4 * 4] = v;
        }
        #pragma unroll
        for (int l = 0; l < 4; l++) {
            int f = tid + l * 256;
            int sr = f >> 5, cc = f & 31;
            float sc = Rc[s0 + sr];
            float4 v = *(const float4*)(Kc + (size_t)(s0 + sr) * HH + cc * 4);
            v.x *= sc; v.y *= sc; v.z *= sc; v.w *= sc;
            *(float4*)&aT[sr][cc * 4] = v;
        }
        __syncthreads();
        #pragma unroll
        for (int ss = 0; ss < 32; ss++) {
            float2 vv = *(const float2*)&vT[ss][ty * 2];
            float4 a0 = *(const float4*)&aT[ss][tx * 8];
            float4 a1 = *(const float4*)&aT[ss][tx * 8 + 4];
            float va[2] = {vv.x, vv.y};
            float aa[8] = {a0.x, a0.y, a0.z, a0.w, a1.x, a1.y, a1.z, a1.w};
            #pragma unroll
            for (int i = 0; i < 2; i++)
                #pragma unroll
                for (int j = 0; j < 8; j++)
                    acc[i][j] += va[i] * aa[j];
        }
        __syncthreads();
    }

    #pragma unroll
    for (int i = 0; i < 2; i++) {
        float* hp = H + ((size_t)bi * HH + r0 + ty * 2 + i) * HH + tx * 8;
        float4 o0 = {acc[i][0], acc[i][1], acc[i][2], acc[i][3]};
        float4 o1 = {acc[i][4], acc[i][5], acc[i][6], acc[i][7]};
        *(float4*)hp       = o0;
        *(float4*)(hp + 4) = o1;
    }
}

// ---------------------------------------------------------------------------
// B_start(c) = I + sum_{c'<c} H[c'] (lambda0 = 1). Exclusive prefix.
// ---------------------------------------------------------------------------
__global__ __launch_bounds__(256) void bprefix_kernel(
    const float* __restrict__ H, float* __restrict__ Bm)
{
    const int b   = blockIdx.x;
    const int idx = blockIdx.y * 256 + threadIdx.x;
    const int row = idx >> 7, col = idx & 127;
    float run = (row == col) ? 1.0f : 0.0f;
    for (int i = 0; i < NCH; i++) {
        size_t off = ((size_t)b * NCH + i) * HH * HH + idx;
        Bm[off] = run;
        run += H[off];
    }
}

// ---------------------------------------------------------------------------
// Invert 128x128 SPD B -> Ainv (v19-verified, static-indexed GJ).
// ---------------------------------------------------------------------------
__global__ __launch_bounds__(256) void invert_kernel(
    const float* __restrict__ Bm, float* __restrict__ Ainv)
{
    const int bi  = blockIdx.x;
    const int tid = threadIdx.x;
    const int tr  = tid >> 4;      // row block 0..15
    const int tc  = tid & 15;      // col block 0..15
    const float* Bp = Bm  + (size_t)bi * HH * HH;
    float*       Ap = Ainv + (size_t)bi * HH * HH;

    __shared__ float rowk[HH];
    __shared__ float colk[HH];
    __shared__ float dsh;

    float M[8][8];
    #pragma unroll
    for (int ii = 0; ii < 8; ii++) {
        float4 a = *(const float4*)(Bp + (size_t)(tr*8+ii) * HH + tc*8);
        float4 b = *(const float4*)(Bp + (size_t)(tr*8+ii) * HH + tc*8 + 4);
        M[ii][0]=a.x; M[ii][1]=a.y; M[ii][2]=a.z; M[ii][3]=a.w;
        M[ii][4]=b.x; M[ii][5]=b.y; M[ii][6]=b.z; M[ii][7]=b.w;
    }

    for (int krb = 0; krb < 16; krb++) {
        const bool myrow = (tr == krb);
        const bool mycol = (tc == krb);
        #pragma unroll
        for (int kl = 0; kl < 8; kl++) {
            if (myrow && mycol) dsh = M[kl][kl];
            __syncthreads();
            const float ip = 1.0f / dsh;
            if (myrow) {               // scale row k + publish
                #pragma unroll
                for (int jj = 0; jj < 8; jj++) {
                    float v = (mycol && jj == kl) ? ip : M[kl][jj] * ip;
                    M[kl][jj] = v;
                    rowk[tc*8 + jj] = v;
                }
            }
            if (mycol) {               // publish pre-update column k entries
                #pragma unroll
                for (int ii = 0; ii < 8; ii++)
                    colk[tr*8 + ii] = M[ii][kl];
            }
            __syncthreads();
            float rk[8];
            #pragma unroll
            for (int jj = 0; jj < 8; jj++) rk[jj] = rowk[tc*8 + jj];
            #pragma unroll
            for (int ii = 0; ii < 8; ii++) {
                const bool isk = myrow && (ii == kl);   // row k already final
                const float f = colk[tr*8 + ii];
                #pragma unroll
                for (int jj = 0; jj < 8; jj++) {
                    float upd = (mycol && jj == kl)
                              ? (-f * ip)
                              : fmaf(-f, rk[jj], M[ii][jj]);
                    M[ii][jj] = isk ? M[ii][jj] : upd;
                }
            }
            __syncthreads();
        }
    }

    #pragma unroll
    for (int ii = 0; ii < 8; ii++) {
        float4 a = {M[ii][0], M[ii][1], M[ii][2], M[ii][3]};
        float4 b = {M[ii][4], M[ii][5], M[ii][6], M[ii][7]};
        *(float4*)(Ap + (size_t)(tr*8+ii) * HH + tc*8)     = a;
        *(float4*)(Ap + (size_t)(tr*8+ii) * HH + tc*8 + 4) = b;
    }
}

// ---------------------------------------------------------------------------
// scan_kernel: 64 PARALLEL chunk-scans (v8 double-step body, verified;
// 64 steps each; A initialized from Ainv = B_start^{-1}).
// ---------------------------------------------------------------------------
__global__ __launch_bounds__(512, 1) void scan_kernel(
    const float* __restrict__ K, const float* __restrict__ rn,
    const float* __restrict__ Ainv, float* __restrict__ Z)
{
    __shared__ float Ybc[2][2][8 * 20];   // [buf][y1/y2], padded
    __shared__ float kst[2][2][8 * 20];   // [buf][k1/k2], padded

    const int bi  = blockIdx.x;          // b*NCH + c
    const int tid = threadIdx.x;
    const int r2  = tid >> 3;
    const int o8  = tid & 7;
    const int c0  = o8 * 16;
    const int r0  = 2 * r2, r1 = r0 + 1;

    const float* Kb   = K  + (size_t)bi * CC * HH;
    float*       Zb   = Z  + (size_t)bi * CC * HH;
    const float* rn_b = rn + (size_t)bi * CC;
    const float* Ap   = Ainv + (size_t)bi * HH * HH;

    f32x2 Ar0[8], Ar1[8];
    #pragma unroll
    for (int j = 0; j < 4; j++) {
        float4 a0 = *(const float4*)(Ap + (size_t)r0 * HH + c0 + 4 * j);
        float4 a1 = *(const float4*)(Ap + (size_t)r1 * HH + c0 + 4 * j);
        Ar0[2*j] = (f32x2){a0.x, a0.y}; Ar0[2*j+1] = (f32x2){a0.z, a0.w};
        Ar1[2*j] = (f32x2){a1.x, a1.y}; Ar1[2*j+1] = (f32x2){a1.z, a1.w};
    }

    const int woff = (r0 >> 4) * 20 + (r0 & 15);
    const int roff = o8 * 20;

    const bool ldr    = tid < 64;
    const int  whichk = tid >> 5;
    const int  l32    = tid & 31;
    const int  lpoff  = (l32 >> 2) * 20 + (l32 & 3) * 4;   // v8 8x20 mapping

    float4 pld = {0.f, 0.f, 0.f, 0.f};
    if (ldr) {
        float4 d0 = *(const float4*)(Kb + (size_t)whichk * HH + l32 * 4);
        *(float4*)&kst[0][whichk][lpoff] = d0;
        pld = *(const float4*)(Kb + (size_t)(2 + whichk) * HH + l32 * 4);
    }
    float2 rs_cur = ((const float2*)rn_b)[0];
    float2 rs_nxt = ((const float2*)rn_b)[1];
    __syncthreads();

    f32x2 k1[8], k2[8];
    #pragma unroll
    for (int j = 0; j < 4; j++) {
        float4 t1 = *(const float4*)&kst[0][0][roff + 4 * j];
        float4 t2 = *(const float4*)&kst[0][1][roff + 4 * j];
        k1[2*j] = (f32x2){t1.x, t1.y}; k1[2*j+1] = (f32x2){t1.z, t1.w};
        k2[2*j] = (f32x2){t2.x, t2.y}; k2[2*j+1] = (f32x2){t2.z, t2.w};
    }

    for (int i = 0; i < NIC; ++i) {
        const int yb = i & 1;
        const int nk = (i + 1) & 1;

        f32x2 y10 = {0,0}, y11 = {0,0}, y20 = {0,0}, y21 = {0,0};
        #pragma unroll
        for (int j = 0; j < 8; j++) {
            y10 += Ar0[j] * k1[j];
            y11 += Ar1[j] * k1[j];
            y20 += Ar0[j] * k2[j];
            y21 += Ar1[j] * k2[j];
        }
        float y1r0 = red8(y10.x + y10.y);
        float y1r1 = red8(y11.x + y11.y);
        float y2r0 = red8(y20.x + y20.y);
        float y2r1 = red8(y21.x + y21.y);
        if (o8 == 0) {
            *(float2*)&Ybc[yb][0][woff] = make_float2(y1r0, y1r1);
            *(float2*)&Ybc[yb][1][woff] = make_float2(y2r0, y2r1);
        }

        if (ldr && i + 1 < NIC) {
            *(float4*)&kst[nk][whichk][lpoff] = pld;
            if (i + 2 < NIC)
                pld = *(const float4*)(Kb + (size_t)(2*(i+2) + whichk) * HH + l32 * 4);
        }

        __syncthreads();

        f32x2 av1[8], av2[8];
        #pragma unroll
        for (int j = 0; j < 4; j++) {
            float4 t1 = *(const float4*)&Ybc[yb][0][roff + 4 * j];
            float4 t2 = *(const float4*)&Ybc[yb][1][roff + 4 * j];
            av1[2*j] = (f32x2){t1.x, t1.y}; av1[2*j+1] = (f32x2){t1.z, t1.w};
            av2[2*j] = (f32x2){t2.x, t2.y}; av2[2*j+1] = (f32x2){t2.z, t2.w};
        }

        f32x2 e11v = {0,0}, e21v = {0,0}, e22v = {0,0};
        #pragma unroll
        for (int j = 0; j < 8; j++) {
            e11v += av1[j] * k1[j];
            e21v += av1[j] * k2[j];
            e22v += av2[j] * k2[j];
        }
        float e11 = red8(e11v.x + e11v.y);
        float e21 = red8(e21v.x + e21v.y);
        float e22 = red8(e22v.x + e22v.y);

        #pragma unroll
        for (int j = 0; j < 4; j++) {
            float4 t1 = *(const float4*)&kst[nk][0][roff + 4 * j];
            float4 t2 = *(const float4*)&kst[nk][1][roff + 4 * j];
            k1[2*j] = (f32x2){t1.x, t1.y}; k1[2*j+1] = (f32x2){t1.z, t1.w};
            k2[2*j] = (f32x2){t2.x, t2.y}; k2[2*j+1] = (f32x2){t2.z, t2.w};
        }

        const float rn1 = rs_cur.x, rn2 = rs_cur.y;
        const float rn1sq = rn1 * rn1;
        const float rn2sq = rn2 * rn2;
        const float i1   = __builtin_amdgcn_rcpf(1.0f + rn1sq * e11);
        const float beta = rn1sq * e21 * i1;
        const float i2   = __builtin_amdgcn_rcpf(1.0f + rn2sq * (e22 - beta * e21));
        const float p2r0 = y2r0 - beta * y1r0;
        const float p2r1 = y2r1 - beta * y1r1;
        const float za1  = rn1 * i1;
        const float za2  = rn2 * i2;
        if (o8 == 0) {
            *(float2*)(Zb + (size_t)(2*i)     * HH + r0) =
                make_float2(za1 * y1r0, za1 * y1r1);
            *(float2*)(Zb + (size_t)(2*i + 1) * HH + r0) =
                make_float2(za2 * p2r0, za2 * p2r1);
        }

        const float cA1 = rn1sq * i1, cA2 = rn2sq * i2;
        const f32x2 u10 = {cA1 * y1r0, cA1 * y1r0};
        const f32x2 u11 = {cA1 * y1r1, cA1 * y1r1};
        const f32x2 u20 = {cA2 * p2r0, cA2 * p2r0};
        const f32x2 u21 = {cA2 * p2r1, cA2 * p2r1};
        const f32x2 bbv = {beta, beta};
        #pragma unroll
        for (int j = 0; j < 8; j++) {
            f32x2 pp = av2[j] - bbv * av1[j];
            Ar0[j] = Ar0[j] - u10 * av1[j] - u20 * pp;
            Ar1[j] = Ar1[j] - u11 * av1[j] - u21 * pp;
        }

        rs_cur = rs_nxt;
        if (i + 2 < NIC) rs_nxt = ((const float2*)rn_b)[i + 2];
    }
}

// ---------------------------------------------------------------------------
// Phase 2a (verified): G[b][c] = V_chunk^T @ (diag(s) Z_chunk).
// ---------------------------------------------------------------------------
__global__ __launch_bounds__(256) void gram_kernel(
    const float* __restrict__ V, const float* __restrict__ Z,
    const float* __restrict__ Sarr, float* __restrict__ G)
{
    const int bi = blockIdx.x;
    const int r0 = blockIdx.y * 32;

    const float* Vc = V + (size_t)bi * CC * HH;
    const float* Zc = Z + (size_t)bi * CC * HH;
    const float* Sc = Sarr + (size_t)bi * CC;

    __shared__ float vT[32][36];
    __shared__ float aT[32][132];

    const int tid = threadIdx.x;
    const int tx = tid & 15, ty = tid >> 4;

    float acc[2][8];
    #pragma unroll
    for (int i = 0; i < 2; i++)
        #pragma unroll
        for (int j = 0; j < 8; j++) acc[i][j] = 0.f;

    for (int s0 = 0; s0 < CC; s0 += 32) {
        {   int sr = tid >> 3, rc = tid & 7;
            float4 v = *(const float4*)(Vc + (size_t)(s0 + sr) * HH + r0 + rc * 4);
            *(float4*)&vT[sr][rc * 4] = v;
        }
        #pragma unroll
        for (int l = 0; l < 4; l++) {
            int f = tid + l * 256;
            int sr = f >> 5, cc = f & 31;
            float sv = Sc[s0 + sr];
            float4 v = *(const float4*)(Zc + (size_t)(s0 + sr) * HH + cc * 4);
            v.x *= sv; v.y *= sv; v.z *= sv; v.w *= sv;
            *(float4*)&aT[sr][cc * 4] = v;
        }
        __syncthreads();
        #pragma unroll
        for (int ss = 0; ss < 32; ss++) {
            float2 vv = *(const float2*)&vT[ss][ty * 2];
            float4 a0 = *(const float4*)&aT[ss][tx * 8];
            float4 a1 = *(const float4*)&aT[ss][tx * 8 + 4];
            float va[2] = {vv.x, vv.y};
            float aa[8] = {a0.x, a0.y, a0.z, a0.w, a1.x, a1.y, a1.z, a1.w};
            #pragma unroll
            for (int i = 0; i < 2; i++)
                #pragma unroll
                for (int j = 0; j < 8; j++)
                    acc[i][j] += va[i] * aa[j];
        }
        __syncthreads();
    }

    #pragma unroll
    for (int i = 0; i < 2; i++) {
        float* gp = G + ((size_t)bi * HH + r0 + ty * 2 + i) * HH + tx * 8;
        float4 o0 = {acc[i][0], acc[i][1], acc[i][2], acc[i][3]};
        float4 o1 = {acc[i][4], acc[i][5], acc[i][6], acc[i][7]};
        *(float4*)gp       = o0;
        *(float4*)(gp + 4) = o1;
    }
}

// ---------------------------------------------------------------------------
// Phase 2b (verified): exclusive prefix Mpre.
// ---------------------------------------------------------------------------
__global__ __launch_bounds__(256) void prefix_kernel(
    const float* __restrict__ G, float* __restrict__ Mpre)
{
    const int b   = blockIdx.x;
    const int idx = blockIdx.y * 256 + threadIdx.x;
    float run = 0.f;
    for (int i = 0; i < NCH; i++) {
        size_t off = ((size_t)b * NCH + i) * HH * HH + idx;
        Mpre[off] = run;
        run += G[off];
    }
}

// ---------------------------------------------------------------------------
// Phase 2c (verified): O = Q Mpre^T + tril(Q (sZ)^T) V. Grid (64,4).
// ---------------------------------------------------------------------------
__global__ __launch_bounds__(256) void ochunk_kernel(
    const float* __restrict__ Q, const float* __restrict__ Z,
    const float* __restrict__ Sarr, const float* __restrict__ V,
    const float* __restrict__ Mpre, float* __restrict__ O)
{
    const int bi = blockIdx.x;
    const int t0 = blockIdx.y * 32;

    const float* Qc = Q    + (size_t)bi * CC * HH;
    const float* Zc = Z    + (size_t)bi * CC * HH;
    const float* Vc = V    + (size_t)bi * CC * HH;
    const float* Sc = Sarr + (size_t)bi * CC;
    const float* Mp = Mpre + (size_t)bi * HH * HH;
    float*       Oc = O    + (size_t)bi * CC * HH;

    __shared__ float S[32][132];
    __shared__ float xT[32][36];
    __shared__ float wT[32][132];

    const int tid = threadIdx.x;
    const int tx = tid & 15, ty = tid >> 4;

    float acc[2][8];

    // ---- phase 1: S = tril(Q (sZ)^T)
    #pragma unroll
    for (int i = 0; i < 2; i++)
        #pragma unroll
        for (int j = 0; j < 8; j++) acc[i][j] = 0.f;
    for (int k0 = 0; k0 < HH; k0 += 32) {
        {   int r = tid >> 3, cg = tid & 7;
            float4 v = *(const float4*)(Qc + (size_t)(t0 + r) * HH + k0 + cg * 4);
            xT[cg*4+0][r] = v.x; xT[cg*4+1][r] = v.y;
            xT[cg*4+2][r] = v.z; xT[cg*4+3][r] = v.w;
        }
        #pragma unroll
        for (int l = 0; l < 4; l++) {
            int f = tid + l * 256;
            int sr = f >> 3, cg = f & 7;
            float sv = Sc[sr];
            float4 v = *(const float4*)(Zc + (size_t)sr * HH + k0 + cg * 4);
            wT[cg*4+0][sr] = v.x * sv; wT[cg*4+1][sr] = v.y * sv;
            wT[cg*4+2][sr] = v.z * sv; wT[cg*4+3][sr] = v.w * sv;
        }
        __syncthreads();
        #pragma unroll
        for (int kk = 0; kk < 32; kk++) {
            float2 xv = *(const float2*)&xT[kk][ty * 2];
            float4 w0 = *(const float4*)&wT[kk][tx * 8];
            float4 w1 = *(const float4*)&wT[kk][tx * 8 + 4];
            float xa[2] = {xv.x, xv.y};
            float wa[8] = {w0.x, w0.y, w0.z, w0.w, w1.x, w1.y, w1.z, w1.w};
            #pragma unroll
            for (int i = 0; i < 2; i++)
                #pragma unroll
                for (int j = 0; j < 8; j++)
                    acc[i][j] += xa[i] * wa[j];
        }
        __syncthreads();
    }
    #pragma unroll
    for (int i = 0; i < 2; i++) {
        int tl = t0 + ty * 2 + i;
        float m[8];
        #pragma unroll
        for (int j = 0; j < 8; j++)
            m[j] = (tx * 8 + j <= tl) ? acc[i][j] : 0.f;
        float4 o0 = {m[0], m[1], m[2], m[3]};
        float4 o1 = {m[4], m[5], m[6], m[7]};
        *(float4*)&S[ty*2+i][tx*8]     = o0;
        *(float4*)&S[ty*2+i][tx*8 + 4] = o1;
    }

    // ---- phase 2: acc = Q @ Mpre^T
    #pragma unroll
    for (int i = 0; i < 2; i++)
        #pragma unroll
        for (int j = 0; j < 8; j++) acc[i][j] = 0.f;
    for (int k0 = 0; k0 < HH; k0 += 32) {
        {   int r = tid >> 3, cg = tid & 7;
            float4 v = *(const float4*)(Qc + (size_t)(t0 + r) * HH + k0 + cg * 4);
            xT[cg*4+0][r] = v.x; xT[cg*4+1][r] = v.y;
            xT[cg*4+2][r] = v.z; xT[cg*4+3][r] = v.w;
        }
        #pragma unroll
        for (int l = 0; l < 4; l++) {
            int f = tid + l * 256;
            int h = f >> 3, cg = f & 7;
            float4 v = *(const float4*)(Mp + (size_t)h * HH + k0 + cg * 4);
            wT[cg*4+0][h] = v.x; wT[cg*4+1][h] = v.y;
            wT[cg*4+2][h] = v.z; wT[cg*4+3][h] = v.w;
        }
        __syncthreads();
        #pragma unroll
        for (int kk = 0; kk < 32; kk++) {
            float2 xv = *(const float2*)&xT[kk][ty * 2];
            float4 w0 = *(const float4*)&wT[kk][tx * 8];
            float4 w1 = *(const float4*)&wT[kk][tx * 8 + 4];
            float xa[2] = {xv.x, xv.y};
            float wa[8] = {w0.x, w0.y, w0.z, w0.w, w1.x, w1.y, w1.z, w1.w};
            #pragma unroll
            for (int i = 0; i < 2; i++)
                #pragma unroll
                for (int j = 0; j < 8; j++)
                    acc[i][j] += xa[i] * wa[j];
        }
        __syncthreads();
    }

    // ---- phase 3: acc += S @ V
    for (int s0 = 0; s0 < CC; s0 += 32) {
        #pragma unroll
        for (int l = 0; l < 4; l++) {
            int f = tid + l * 256;
            int sr = f >> 5, cc = f & 31;
            float4 v = *(const float4*)(Vc + (size_t)(s0 + sr) * HH + cc * 4);
            *(float4*)&wT[sr][cc * 4] = v;
        }
        __syncthreads();
        #pragma unroll
        for (int ss = 0; ss < 32; ss++) {
            float4 w0 = *(const float4*)&wT[ss][tx * 8];
            float4 w1 = *(const float4*)&wT[ss][tx * 8 + 4];
            float wa[8] = {w0.x, w0.y, w0.z, w0.w, w1.x, w1.y, w1.z, w1.w};
            float sv[2] = {S[ty*2][s0 + ss], S[ty*2+1][s0 + ss]};
            #pragma unroll
            for (int i = 0; i < 2; i++)
                #pragma unroll
                for (int j = 0; j < 8; j++)
                    acc[i][j] += sv[i] * wa[j];
        }
        __syncthreads();
    }

    #pragma unroll
    for (int i = 0; i < 2; i++) {
        float* op = Oc + (size_t)(t0 + ty * 2 + i) * HH + tx * 8;
        float4 o0 = {acc[i][0], acc[i][1], acc[i][2], acc[i][3]};
        float4 o1 = {acc[i][4], acc[i][5], acc[i][6], acc[i][7]};
        *(float4*)op       = o0;
        *(float4*)(op + 4) = o1;
    }
}

// ---------------------------------------------------------------------------
// Output (verified): out = O Wo^T + bo.
// ---------------------------------------------------------------------------
__global__ __launch_bounds__(256) void out_kernel(
    const float* __restrict__ O, const float* __restrict__ Wo,
    const float* __restrict__ bo, float* __restrict__ out)
{
    const int row0 = blockIdx.x * 64;
    const int d0   = blockIdx.y * 128;

    __shared__ float oT[32][68];
    __shared__ float woT[32][132];

    const int tid = threadIdx.x;
    const int tx = tid & 15;
    const int ty = tid >> 4;

    float acc[4][8];
    #pragma unroll
    for (int i = 0; i < 4; i++)
        #pragma unroll
        for (int j = 0; j < 8; j++) acc[i][j] = 0.f;

    for (int k0 = 0; k0 < HH; k0 += 32) {
        #pragma unroll
        for (int l = 0; l < 2; l++) {
            int f = tid + l * 256;
            int r = f >> 3;
            int cg = f & 7;
            float4 v = *(const float4*)(O + (size_t)(row0 + r) * HH + k0 + cg * 4);
            oT[cg*4+0][r] = v.x; oT[cg*4+1][r] = v.y;
            oT[cg*4+2][r] = v.z; oT[cg*4+3][r] = v.w;
        }
        #pragma unroll
        for (int l = 0; l < 4; l++) {
            int f = tid + l * 256;
            int d = f >> 3;
            int cg = f & 7;
            float4 v = *(const float4*)(Wo + (size_t)(d0 + d) * HH + k0 + cg * 4);
            woT[cg*4+0][d] = v.x; woT[cg*4+1][d] = v.y;
            woT[cg*4+2][d] = v.z; woT[cg*4+3][d] = v.w;
        }
        __syncthreads();
        #pragma unroll
        for (int kk = 0; kk < 32; kk++) {
            float4 ov = *(const float4*)&oT[kk][ty * 4];
            float4 w0 = *(const float4*)&woT[kk][tx * 8];
            float4 w1 = *(const float4*)&woT[kk][tx * 8 + 4];
            float oa[4] = {ov.x, ov.y, ov.z, ov.w};
            float wa[8] = {w0.x, w0.y, w0.z, w0.w, w1.x, w1.y, w1.z, w1.w};
            #pragma unroll
            for (int i = 0; i < 4; i++)
                #pragma unroll
                for (int j = 0; j < 8; j++)
                    acc[i][j] += oa[i] * wa[j];
        }
        __syncthreads();
    }

    #pragma unroll
    for (int i = 0; i < 4; i++) {
        int row = row0 + ty * 4 + i;
        #pragma unroll
        for (int j = 0; j < 8; j++) acc[i][j] += bo[d0 + tx * 8 + j];
        float4 o0 = {acc[i][0], acc[i][1], acc[i][2], acc[i][3]};
        float4 o1 = {acc[i][4], acc[i][5], acc[i][6], acc[i][7]};
        *(float4*)(out + (size_t)row * DD + d0 + tx * 8)     = o0;
        *(float4*)(out + (size_t)row * DD + d0 + tx * 8 + 4) = o1;
    }
}

extern "C" void kernel_launch(void* const* d_in, const int* in_sizes, int n_in,
                              void* d_out, int out_size, void* d_ws, size_t ws_size,
                              hipStream_t stream) {
    const float* x  = (const float*)d_in[0];
    const float* Wq = (const float*)d_in[1];
    const float* bq = (const float*)d_in[2];
    const float* Wk = (const float*)d_in[3];
    const float* bk = (const float*)d_in[4];
    const float* Wv = (const float*)d_in[5];
    const float* bv = (const float*)d_in[6];
    const float* Wo = (const float*)d_in[7];
    const float* bo = (const float*)d_in[8];
    float* out = (float*)d_out;

    float* ws = (float*)d_ws;
    float* Q = ws;
    float* K = ws + (size_t)BT * HH;
    float* V = ws + (size_t)2 * BT * HH;
    float* O = ws + (size_t)3 * BT * HH;

    // d_out scratch (32 MB), all dead before out_kernel writes out:
    //   rn @0 | Sarr @32KB | Z @1MB | G @8MB | Mpre @12MB | H @16MB
    //   Bmat @20MB | Ainv @24MB
    float* db   = (float*)d_out;
    float* rn   = db;
    float* Sarr = db + BT;
    float* Z    = db + (size_t)(1u << 18);
    float* G    = db + (size_t)(1u << 21);
    float* Mpre = db + (size_t)3 * (1u << 20);
    float* H    = db + (size_t)4 * (1u << 20);
    float* Bmat = db + (size_t)5 * (1u << 20);
    float* Ainv = db + (size_t)6 * (1u << 20);

    // 1. K projection (+rn)
    projk_kernel<<<BT / 32, 256, 0, stream>>>(x, Wk, bk, K, rn);

    // 2. Q/V projection (full-GPU; Q half computes s = q.k)
    dim3 qvg(BT / 32, 2);
    projqv_kernel<<<qvg, 256, 0, stream>>>(x, Wq, bq, Wv, bv, K, Q, V, Sarr);

    // 3. chunk-start inverse-Gram pipeline: H -> B_start -> A_start
    dim3 hg(NSCAN, 4);
    ugram_kernel<<<hg, 256, 0, stream>>>(K, rn, H);
    dim3 bp(BB, HH * HH / 256);
    bprefix_kernel<<<bp, 256, 0, stream>>>(H, Bmat);
    invert_kernel<<<NSCAN, 256, 0, stream>>>(Bmat, Ainv);

    // 4. 64 parallel chunk-scans
    scan_kernel<<<NSCAN, 512, 0, stream>>>(K, rn, Ainv, Z);

    // 5. phase-2 (alpha = s*z folded into staging) + output
    dim3 gg(NSCAN, 4);
    gram_kernel<<<gg, 256, 0, stream>>>(V, Z, Sarr, G);
    prefix_kernel<<<bp, 256, 0, stream>>>(G, Mpre);
    dim3 cg(NSCAN, 4);
    ochunk_kernel<<<cg, 256, 0, stream>>>(Q, Z, Sarr, V, Mpre, O);
    dim3 og(BT / 64, DD / 128);
    out_kernel<<<og, 256, 0, stream>>>(O, Wo, bo, out);
}

// Round 19
// 457.205 us; speedup vs baseline: 2.6782x; 1.0056x over previous
//
#include <hip/hip_runtime.h>
#include <math.h>

#define BB 4
#define TT 2048
#define DD 1024
#define HH 128
#define EPSF 1e-6f
#define BT (BB*TT)   // 8192
#define CC 128       // chunk length
#define NCH (TT/CC)  // 16 chunks per batch
#define NIC (CC/2)   // 64 double-steps per chunk
#define NSCAN (BB*NCH)  // 64 chunk-scan blocks
#define WPAD 140     // gapped row stride: col h stored at h + (h>>5)*4

typedef float f32x2 __attribute__((ext_vector_type(2)));

// gap-insertion column map: spreads stride-8 float4 reads across all banks
// (read bank-starts become 2-way aliased = free per m136, vs 4-way before)
__device__ __forceinline__ int gcol(int h) { return h + ((h >> 5) << 2); }

// 8-lane butterfly sum, pure DPP/VALU (no DS pipe)
__device__ __forceinline__ float red8(float x) {
    x += __int_as_float(__builtin_amdgcn_mov_dpp(__float_as_int(x), 0xB1,  0xF, 0xF, true));
    x += __int_as_float(__builtin_amdgcn_mov_dpp(__float_as_int(x), 0x4E,  0xF, 0xF, true));
    x += __int_as_float(__builtin_amdgcn_mov_dpp(__float_as_int(x), 0x141, 0xF, 0xF, true));
    return x;
}
// 16-lane butterfly sum (adds ROW_MIRROR)
__device__ __forceinline__ float red16(float x) {
    x = red8(x);
    x += __int_as_float(__builtin_amdgcn_mov_dpp(__float_as_int(x), 0x140, 0xF, 0xF, true));
    return x;
}

// ---------------------------------------------------------------------------
// K projection + rn epilogue: 256 blocks x 256 threads, gapped wT.
// ---------------------------------------------------------------------------
__global__ __launch_bounds__(256) void projk_kernel(
    const float* __restrict__ x, const float* __restrict__ Wk,
    const float* __restrict__ bk, float* __restrict__ K,
    float* __restrict__ rn)
{
    const int row0 = blockIdx.x * 32;

    __shared__ float xT[32][36];
    __shared__ float wT[32][WPAD];

    const int tid = threadIdx.x;
    const int tx = tid & 15;
    const int ty = tid >> 4;       // 0..15, rows ty*2..+2
    const int gx = tx * 8 + ((tx >> 2) << 2);

    float acc[2][8];
    #pragma unroll
    for (int i = 0; i < 2; i++)
        #pragma unroll
        for (int j = 0; j < 8; j++) acc[i][j] = 0.f;

    for (int k0 = 0; k0 < DD; k0 += 32) {
        {   int r = tid >> 3, cg = tid & 7;
            float4 v = *(const float4*)(x + (size_t)(row0 + r) * DD + k0 + cg * 4);
            xT[cg*4+0][r] = v.x; xT[cg*4+1][r] = v.y;
            xT[cg*4+2][r] = v.z; xT[cg*4+3][r] = v.w;
        }
        #pragma unroll
        for (int l = 0; l < 4; l++) {
            int f = tid + l * 256;
            int h = f >> 3, cg = f & 7;
            int gc = gcol(h);
            float4 v = *(const float4*)(Wk + (size_t)h * DD + k0 + cg * 4);
            wT[cg*4+0][gc] = v.x; wT[cg*4+1][gc] = v.y;
            wT[cg*4+2][gc] = v.z; wT[cg*4+3][gc] = v.w;
        }
        __syncthreads();
        #pragma unroll
        for (int kk = 0; kk < 32; kk++) {
            float2 xv = *(const float2*)&xT[kk][ty * 2];
            float4 w0 = *(const float4*)&wT[kk][gx];
            float4 w1 = *(const float4*)&wT[kk][gx + 4];
            float xa[2] = {xv.x, xv.y};
            float wa[8] = {w0.x, w0.y, w0.z, w0.w, w1.x, w1.y, w1.z, w1.w};
            #pragma unroll
            for (int i = 0; i < 2; i++)
                #pragma unroll
                for (int j = 0; j < 8; j++)
                    acc[i][j] += xa[i] * wa[j];
        }
        __syncthreads();
    }

    #pragma unroll
    for (int i = 0; i < 2; i++) {
        int row = row0 + ty * 2 + i;
        #pragma unroll
        for (int j = 0; j < 8; j++) acc[i][j] += bk[tx * 8 + j];
        float4 o0 = {acc[i][0], acc[i][1], acc[i][2], acc[i][3]};
        float4 o1 = {acc[i][4], acc[i][5], acc[i][6], acc[i][7]};
        *(float4*)(K + (size_t)row * HH + tx * 8)     = o0;
        *(float4*)(K + (size_t)row * HH + tx * 8 + 4) = o1;
        float p = 0.f;
        #pragma unroll
        for (int j = 0; j < 8; j++) p += acc[i][j] * acc[i][j];
        p = red16(p);
        if (tx == 0) rn[row] = 1.0f / (sqrtf(p) + EPSF);
    }
}

// ---------------------------------------------------------------------------
// Q/V projection, FULL-GPU: grid (256, 2), gapped wT.
// blockIdx.y == 0 -> Q (+ s = q.k epilogue); == 1 -> V.
// ---------------------------------------------------------------------------
__global__ __launch_bounds__(256) void projqv_kernel(
    const float* __restrict__ x,
    const float* __restrict__ Wq, const float* __restrict__ bq,
    const float* __restrict__ Wv, const float* __restrict__ bv,
    const float* __restrict__ K,
    float* __restrict__ Q, float* __restrict__ V,
    float* __restrict__ Sarr)
{
    const int row0  = blockIdx.x * 32;
    const int isv   = blockIdx.y;
    const float* W    = isv ? Wv : Wq;
    const float* bias = isv ? bv : bq;
    float* P          = isv ? V  : Q;

    __shared__ float xT[32][36];
    __shared__ float wT[32][WPAD];

    const int tid = threadIdx.x;
    const int tx = tid & 15;
    const int ty = tid >> 4;
    const int gx = tx * 8 + ((tx >> 2) << 2);

    float acc[2][8];
    #pragma unroll
    for (int i = 0; i < 2; i++)
        #pragma unroll
        for (int j = 0; j < 8; j++) acc[i][j] = 0.f;

    for (int k0 = 0; k0 < DD; k0 += 32) {
        {   int r = tid >> 3, cg = tid & 7;
            float4 v = *(const float4*)(x + (size_t)(row0 + r) * DD + k0 + cg * 4);
            xT[cg*4+0][r] = v.x; xT[cg*4+1][r] = v.y;
            xT[cg*4+2][r] = v.z; xT[cg*4+3][r] = v.w;
        }
        #pragma unroll
        for (int l = 0; l < 4; l++) {
            int f = tid + l * 256;
            int h = f >> 3, cg = f & 7;
            int gc = gcol(h);
            float4 v = *(const float4*)(W + (size_t)h * DD + k0 + cg * 4);
            wT[cg*4+0][gc] = v.x; wT[cg*4+1][gc] = v.y;
            wT[cg*4+2][gc] = v.z; wT[cg*4+3][gc] = v.w;
        }
        __syncthreads();
        #pragma unroll
        for (int kk = 0; kk < 32; kk++) {
            float2 xv = *(const float2*)&xT[kk][ty * 2];
            float4 w0 = *(const float4*)&wT[kk][gx];
            float4 w1 = *(const float4*)&wT[kk][gx + 4];
            float xa[2] = {xv.x, xv.y};
            float wa[8] = {w0.x, w0.y, w0.z, w0.w, w1.x, w1.y, w1.z, w1.w};
            #pragma unroll
            for (int i = 0; i < 2; i++)
                #pragma unroll
                for (int j = 0; j < 8; j++)
                    acc[i][j] += xa[i] * wa[j];
        }
        __syncthreads();
    }

    #pragma unroll
    for (int i = 0; i < 2; i++) {
        int row = row0 + ty * 2 + i;
        #pragma unroll
        for (int j = 0; j < 8; j++) acc[i][j] += bias[tx * 8 + j];
        float4 o0 = {acc[i][0], acc[i][1], acc[i][2], acc[i][3]};
        float4 o1 = {acc[i][4], acc[i][5], acc[i][6], acc[i][7]};
        *(float4*)(P + (size_t)row * HH + tx * 8)     = o0;
        *(float4*)(P + (size_t)row * HH + tx * 8 + 4) = o1;
    }

    if (!isv) {   // s = q . k epilogue
        #pragma unroll
        for (int i = 0; i < 2; i++) {
            int row = row0 + ty * 2 + i;
            float4 ka = *(const float4*)(K + (size_t)row * HH + tx * 8);
            float4 kb = *(const float4*)(K + (size_t)row * HH + tx * 8 + 4);
            float p = acc[i][0]*ka.x + acc[i][1]*ka.y + acc[i][2]*ka.z + acc[i][3]*ka.w
                    + acc[i][4]*kb.x + acc[i][5]*kb.y + acc[i][6]*kb.z + acc[i][7]*kb.w;
            p = red16(p);
            if (tx == 0) Sarr[row] = p;
        }
    }
}

// ---------------------------------------------------------------------------
// H[b][c] = sum_{t in chunk} (rn k)(rn k)^T. Grid (64, 4), gapped aT.
// ---------------------------------------------------------------------------
__global__ __launch_bounds__(256) void ugram_kernel(
    const float* __restrict__ K, const float* __restrict__ rn,
    float* __restrict__ H)
{
    const int bi = blockIdx.x;
    const int r0 = blockIdx.y * 32;

    const float* Kc = K + (size_t)bi * CC * HH;
    const float* Rc = rn + (size_t)bi * CC;

    __shared__ float vT[32][36];
    __shared__ float aT[32][WPAD];

    const int tid = threadIdx.x;
    const int tx = tid & 15, ty = tid >> 4;
    const int gx = tx * 8 + ((tx >> 2) << 2);

    float acc[2][8];
    #pragma unroll
    for (int i = 0; i < 2; i++)
        #pragma unroll
        for (int j = 0; j < 8; j++) acc[i][j] = 0.f;

    for (int s0 = 0; s0 < CC; s0 += 32) {
        {   int sr = tid >> 3, rc4 = tid & 7;
            float sc = Rc[s0 + sr];
            float4 v = *(const float4*)(Kc + (size_t)(s0 + sr) * HH + r0 + rc4 * 4);
            v.x *= sc; v.y *= sc; v.z *= sc; v.w *= sc;
            *(float4*)&vT[sr][rc4 * 4] = v;
        }
        #pragma unroll
        for (int l = 0; l < 4; l++) {
            int f = tid + l * 256;
            int sr = f >> 5, cc = f & 31;
            float sc = Rc[s0 + sr];
            int gc = cc * 4 + ((cc >> 3) << 2);
            float4 v = *(const float4*)(Kc + (size_t)(s0 + sr) * HH + cc * 4);
            v.x *= sc; v.y *= sc; v.z *= sc; v.w *= sc;
            *(float4*)&aT[sr][gc] = v;
        }
        __syncthreads();
        #pragma unroll
        for (int ss = 0; ss < 32; ss++) {
            float2 vv = *(const float2*)&vT[ss][ty * 2];
            float4 a0 = *(const float4*)&aT[ss][gx];
            float4 a1 = *(const float4*)&aT[ss][gx + 4];
            float va[2] = {vv.x, vv.y};
            float aa[8] = {a0.x, a0.y, a0.z, a0.w, a1.x, a1.y, a1.z, a1.w};
            #pragma unroll
            for (int i = 0; i < 2; i++)
                #pragma unroll
                for (int j = 0; j < 8; j++)
                    acc[i][j] += va[i] * aa[j];
        }
        __syncthreads();
    }

    #pragma unroll
    for (int i = 0; i < 2; i++) {
        float* hp = H + ((size_t)bi * HH + r0 + ty * 2 + i) * HH + tx * 8;
        float4 o0 = {acc[i][0], acc[i][1], acc[i][2], acc[i][3]};
        float4 o1 = {acc[i][4], acc[i][5], acc[i][6], acc[i][7]};
        *(float4*)hp       = o0;
        *(float4*)(hp + 4) = o1;
    }
}

// ---------------------------------------------------------------------------
// B_start(c) = I + sum_{c'<c} H[c'] (lambda0 = 1). Exclusive prefix.
// ---------------------------------------------------------------------------
__global__ __launch_bounds__(256) void bprefix_kernel(
    const float* __restrict__ H, float* __restrict__ Bm)
{
    const int b   = blockIdx.x;
    const int idx = blockIdx.y * 256 + threadIdx.x;
    const int row = idx >> 7, col = idx & 127;
    float run = (row == col) ? 1.0f : 0.0f;
    for (int i = 0; i < NCH; i++) {
        size_t off = ((size_t)b * NCH + i) * HH * HH + idx;
        Bm[off] = run;
        run += H[off];
    }
}

// ---------------------------------------------------------------------------
// Invert 128x128 SPD B -> Ainv (v19-verified, static-indexed GJ).
// ---------------------------------------------------------------------------
__global__ __launch_bounds__(256) void invert_kernel(
    const float* __restrict__ Bm, float* __restrict__ Ainv)
{
    const int bi  = blockIdx.x;
    const int tid = threadIdx.x;
    const int tr  = tid >> 4;      // row block 0..15
    const int tc  = tid & 15;      // col block 0..15
    const float* Bp = Bm  + (size_t)bi * HH * HH;
    float*       Ap = Ainv + (size_t)bi * HH * HH;

    __shared__ float rowk[HH];
    __shared__ float colk[HH];
    __shared__ float dsh;

    float M[8][8];
    #pragma unroll
    for (int ii = 0; ii < 8; ii++) {
        float4 a = *(const float4*)(Bp + (size_t)(tr*8+ii) * HH + tc*8);
        float4 b = *(const float4*)(Bp + (size_t)(tr*8+ii) * HH + tc*8 + 4);
        M[ii][0]=a.x; M[ii][1]=a.y; M[ii][2]=a.z; M[ii][3]=a.w;
        M[ii][4]=b.x; M[ii][5]=b.y; M[ii][6]=b.z; M[ii][7]=b.w;
    }

    for (int krb = 0; krb < 16; krb++) {
        const bool myrow = (tr == krb);
        const bool mycol = (tc == krb);
        #pragma unroll
        for (int kl = 0; kl < 8; kl++) {
            if (myrow && mycol) dsh = M[kl][kl];
            __syncthreads();
            const float ip = 1.0f / dsh;
            if (myrow) {               // scale row k + publish
                #pragma unroll
                for (int jj = 0; jj < 8; jj++) {
                    float v = (mycol && jj == kl) ? ip : M[kl][jj] * ip;
                    M[kl][jj] = v;
                    rowk[tc*8 + jj] = v;
                }
            }
            if (mycol) {               // publish pre-update column k entries
                #pragma unroll
                for (int ii = 0; ii < 8; ii++)
                    colk[tr*8 + ii] = M[ii][kl];
            }
            __syncthreads();
            float rk[8];
            #pragma unroll
            for (int jj = 0; jj < 8; jj++) rk[jj] = rowk[tc*8 + jj];
            #pragma unroll
            for (int ii = 0; ii < 8; ii++) {
                const bool isk = myrow && (ii == kl);   // row k already final
                const float f = colk[tr*8 + ii];
                #pragma unroll
                for (int jj = 0; jj < 8; jj++) {
                    float upd = (mycol && jj == kl)
                              ? (-f * ip)
                              : fmaf(-f, rk[jj], M[ii][jj]);
                    M[ii][jj] = isk ? M[ii][jj] : upd;
                }
            }
            __syncthreads();
        }
    }

    #pragma unroll
    for (int ii = 0; ii < 8; ii++) {
        float4 a = {M[ii][0], M[ii][1], M[ii][2], M[ii][3]};
        float4 b = {M[ii][4], M[ii][5], M[ii][6], M[ii][7]};
        *(float4*)(Ap + (size_t)(tr*8+ii) * HH + tc*8)     = a;
        *(float4*)(Ap + (size_t)(tr*8+ii) * HH + tc*8 + 4) = b;
    }
}

// ---------------------------------------------------------------------------
// scan_kernel: 64 PARALLEL chunk-scans (v8 double-step body, verified).
// ---------------------------------------------------------------------------
__global__ __launch_bounds__(512, 1) void scan_kernel(
    const float* __restrict__ K, const float* __restrict__ rn,
    const float* __restrict__ Ainv, float* __restrict__ Z)
{
    __shared__ float Ybc[2][2][8 * 20];   // [buf][y1/y2], padded
    __shared__ float kst[2][2][8 * 20];   // [buf][k1/k2], padded

    const int bi  = blockIdx.x;          // b*NCH + c
    const int tid = threadIdx.x;
    const int r2  = tid >> 3;
    const int o8  = tid & 7;
    const int c0  = o8 * 16;
    const int r0  = 2 * r2, r1 = r0 + 1;

    const float* Kb   = K  + (size_t)bi * CC * HH;
    float*       Zb   = Z  + (size_t)bi * CC * HH;
    const float* rn_b = rn + (size_t)bi * CC;
    const float* Ap   = Ainv + (size_t)bi * HH * HH;

    f32x2 Ar0[8], Ar1[8];
    #pragma unroll
    for (int j = 0; j < 4; j++) {
        float4 a0 = *(const float4*)(Ap + (size_t)r0 * HH + c0 + 4 * j);
        float4 a1 = *(const float4*)(Ap + (size_t)r1 * HH + c0 + 4 * j);
        Ar0[2*j] = (f32x2){a0.x, a0.y}; Ar0[2*j+1] = (f32x2){a0.z, a0.w};
        Ar1[2*j] = (f32x2){a1.x, a1.y}; Ar1[2*j+1] = (f32x2){a1.z, a1.w};
    }

    const int woff = (r0 >> 4) * 20 + (r0 & 15);
    const int roff = o8 * 20;

    const bool ldr    = tid < 64;
    const int  whichk = tid >> 5;
    const int  l32    = tid & 31;
    const int  lpoff  = (l32 >> 2) * 20 + (l32 & 3) * 4;   // v8 8x20 mapping

    float4 pld = {0.f, 0.f, 0.f, 0.f};
    if (ldr) {
        float4 d0 = *(const float4*)(Kb + (size_t)whichk * HH + l32 * 4);
        *(float4*)&kst[0][whichk][lpoff] = d0;
        pld = *(const float4*)(Kb + (size_t)(2 + whichk) * HH + l32 * 4);
    }
    float2 rs_cur = ((const float2*)rn_b)[0];
    float2 rs_nxt = ((const float2*)rn_b)[1];
    __syncthreads();

    f32x2 k1[8], k2[8];
    #pragma unroll
    for (int j = 0; j < 4; j++) {
        float4 t1 = *(const float4*)&kst[0][0][roff + 4 * j];
        float4 t2 = *(const float4*)&kst[0][1][roff + 4 * j];
        k1[2*j] = (f32x2){t1.x, t1.y}; k1[2*j+1] = (f32x2){t1.z, t1.w};
        k2[2*j] = (f32x2){t2.x, t2.y}; k2[2*j+1] = (f32x2){t2.z, t2.w};
    }

    for (int i = 0; i < NIC; ++i) {
        const int yb = i & 1;
        const int nk = (i + 1) & 1;

        f32x2 y10 = {0,0}, y11 = {0,0}, y20 = {0,0}, y21 = {0,0};
        #pragma unroll
        for (int j = 0; j < 8; j++) {
            y10 += Ar0[j] * k1[j];
            y11 += Ar1[j] * k1[j];
            y20 += Ar0[j] * k2[j];
            y21 += Ar1[j] * k2[j];
        }
        float y1r0 = red8(y10.x + y10.y);
        float y1r1 = red8(y11.x + y11.y);
        float y2r0 = red8(y20.x + y20.y);
        float y2r1 = red8(y21.x + y21.y);
        if (o8 == 0) {
            *(float2*)&Ybc[yb][0][woff] = make_float2(y1r0, y1r1);
            *(float2*)&Ybc[yb][1][woff] = make_float2(y2r0, y2r1);
        }

        if (ldr && i + 1 < NIC) {
            *(float4*)&kst[nk][whichk][lpoff] = pld;
            if (i + 2 < NIC)
                pld = *(const float4*)(Kb + (size_t)(2*(i+2) + whichk) * HH + l32 * 4);
        }

        __syncthreads();

        f32x2 av1[8], av2[8];
        #pragma unroll
        for (int j = 0; j < 4; j++) {
            float4 t1 = *(const float4*)&Ybc[yb][0][roff + 4 * j];
            float4 t2 = *(const float4*)&Ybc[yb][1][roff + 4 * j];
            av1[2*j] = (f32x2){t1.x, t1.y}; av1[2*j+1] = (f32x2){t1.z, t1.w};
            av2[2*j] = (f32x2){t2.x, t2.y}; av2[2*j+1] = (f32x2){t2.z, t2.w};
        }

        f32x2 e11v = {0,0}, e21v = {0,0}, e22v = {0,0};
        #pragma unroll
        for (int j = 0; j < 8; j++) {
            e11v += av1[j] * k1[j];
            e21v += av1[j] * k2[j];
            e22v += av2[j] * k2[j];
        }
        float e11 = red8(e11v.x + e11v.y);
        float e21 = red8(e21v.x + e21v.y);
        float e22 = red8(e22v.x + e22v.y);

        #pragma unroll
        for (int j = 0; j < 4; j++) {
            float4 t1 = *(const float4*)&kst[nk][0][roff + 4 * j];
            float4 t2 = *(const float4*)&kst[nk][1][roff + 4 * j];
            k1[2*j] = (f32x2){t1.x, t1.y}; k1[2*j+1] = (f32x2){t1.z, t1.w};
            k2[2*j] = (f32x2){t2.x, t2.y}; k2[2*j+1] = (f32x2){t2.z, t2.w};
        }

        const float rn1 = rs_cur.x, rn2 = rs_cur.y;
        const float rn1sq = rn1 * rn1;
        const float rn2sq = rn2 * rn2;
        const float i1   = __builtin_amdgcn_rcpf(1.0f + rn1sq * e11);
        const float beta = rn1sq * e21 * i1;
        const float i2   = __builtin_amdgcn_rcpf(1.0f + rn2sq * (e22 - beta * e21));
        const float p2r0 = y2r0 - beta * y1r0;
        const float p2r1 = y2r1 - beta * y1r1;
        const float za1  = rn1 * i1;
        const float za2  = rn2 * i2;
        if (o8 == 0) {
            *(float2*)(Zb + (size_t)(2*i)     * HH + r0) =
                make_float2(za1 * y1r0, za1 * y1r1);
            *(float2*)(Zb + (size_t)(2*i + 1) * HH + r0) =
                make_float2(za2 * p2r0, za2 * p2r1);
        }

        const float cA1 = rn1sq * i1, cA2 = rn2sq * i2;
        const f32x2 u10 = {cA1 * y1r0, cA1 * y1r0};
        const f32x2 u11 = {cA1 * y1r1, cA1 * y1r1};
        const f32x2 u20 = {cA2 * p2r0, cA2 * p2r0};
        const f32x2 u21 = {cA2 * p2r1, cA2 * p2r1};
        const f32x2 bbv = {beta, beta};
        #pragma unroll
        for (int j = 0; j < 8; j++) {
            f32x2 pp = av2[j] - bbv * av1[j];
            Ar0[j] = Ar0[j] - u10 * av1[j] - u20 * pp;
            Ar1[j] = Ar1[j] - u11 * av1[j] - u21 * pp;
        }

        rs_cur = rs_nxt;
        if (i + 2 < NIC) rs_nxt = ((const float2*)rn_b)[i + 2];
    }
}

// ---------------------------------------------------------------------------
// Phase 2a: G[b][c] = V_chunk^T @ (diag(s) Z_chunk). Gapped aT.
// ---------------------------------------------------------------------------
__global__ __launch_bounds__(256) void gram_kernel(
    const float* __restrict__ V, const float* __restrict__ Z,
    const float* __restrict__ Sarr, float* __restrict__ G)
{
    const int bi = blockIdx.x;
    const int r0 = blockIdx.y * 32;

    const float* Vc = V + (size_t)bi * CC * HH;
    const float* Zc = Z + (size_t)bi * CC * HH;
    const float* Sc = Sarr + (size_t)bi * CC;

    __shared__ float vT[32][36];
    __shared__ float aT[32][WPAD];

    const int tid = threadIdx.x;
    const int tx = tid & 15, ty = tid >> 4;
    const int gx = tx * 8 + ((tx >> 2) << 2);

    float acc[2][8];
    #pragma unroll
    for (int i = 0; i < 2; i++)
        #pragma unroll
        for (int j = 0; j < 8; j++) acc[i][j] = 0.f;

    for (int s0 = 0; s0 < CC; s0 += 32) {
        {   int sr = tid >> 3, rc = tid & 7;
            float4 v = *(const float4*)(Vc + (size_t)(s0 + sr) * HH + r0 + rc * 4);
            *(float4*)&vT[sr][rc * 4] = v;
        }
        #pragma unroll
        for (int l = 0; l < 4; l++) {
            int f = tid + l * 256;
            int sr = f >> 5, cc = f & 31;
            float sv = Sc[s0 + sr];
            int gc = cc * 4 + ((cc >> 3) << 2);
            float4 v = *(const float4*)(Zc + (size_t)(s0 + sr) * HH + cc * 4);
            v.x *= sv; v.y *= sv; v.z *= sv; v.w *= sv;
            *(float4*)&aT[sr][gc] = v;
        }
        __syncthreads();
        #pragma unroll
        for (int ss = 0; ss < 32; ss++) {
            float2 vv = *(const float2*)&vT[ss][ty * 2];
            float4 a0 = *(const float4*)&aT[ss][gx];
            float4 a1 = *(const float4*)&aT[ss][gx + 4];
            float va[2] = {vv.x, vv.y};
            float aa[8] = {a0.x, a0.y, a0.z, a0.w, a1.x, a1.y, a1.z, a1.w};
            #pragma unroll
            for (int i = 0; i < 2; i++)
                #pragma unroll
                for (int j = 0; j < 8; j++)
                    acc[i][j] += va[i] * aa[j];
        }
        __syncthreads();
    }

    #pragma unroll
    for (int i = 0; i < 2; i++) {
        float* gp = G + ((size_t)bi * HH + r0 + ty * 2 + i) * HH + tx * 8;
        float4 o0 = {acc[i][0], acc[i][1], acc[i][2], acc[i][3]};
        float4 o1 = {acc[i][4], acc[i][5], acc[i][6], acc[i][7]};
        *(float4*)gp       = o0;
        *(float4*)(gp + 4) = o1;
    }
}

// ---------------------------------------------------------------------------
// Phase 2b: exclusive prefix Mpre.
// ---------------------------------------------------------------------------
__global__ __launch_bounds__(256) void prefix_kernel(
    const float* __restrict__ G, float* __restrict__ Mpre)
{
    const int b   = blockIdx.x;
    const int idx = blockIdx.y * 256 + threadIdx.x;
    float run = 0.f;
    for (int i = 0; i < NCH; i++) {
        size_t off = ((size_t)b * NCH + i) * HH * HH + idx;
        Mpre[off] = run;
        run += G[off];
    }
}

// ---------------------------------------------------------------------------
// Phase 2c: O = Q Mpre^T + tril(Q (sZ)^T) V. Grid (64,4). Gapped wT/S.
// ---------------------------------------------------------------------------
__global__ __launch_bounds__(256) void ochunk_kernel(
    const float* __restrict__ Q, const float* __restrict__ Z,
    const float* __restrict__ Sarr, const float* __restrict__ V,
    const float* __restrict__ Mpre, float* __restrict__ O)
{
    const int bi = blockIdx.x;
    const int t0 = blockIdx.y * 32;

    const float* Qc = Q    + (size_t)bi * CC * HH;
    const float* Zc = Z    + (size_t)bi * CC * HH;
    const float* Vc = V    + (size_t)bi * CC * HH;
    const float* Sc = Sarr + (size_t)bi * CC;
    const float* Mp = Mpre + (size_t)bi * HH * HH;
    float*       Oc = O    + (size_t)bi * CC * HH;

    __shared__ float S[32][WPAD];
    __shared__ float xT[32][36];
    __shared__ float wT[32][WPAD];

    const int tid = threadIdx.x;
    const int tx = tid & 15, ty = tid >> 4;
    const int gx = tx * 8 + ((tx >> 2) << 2);

    float acc[2][8];

    // ---- phase 1: S = tril(Q (sZ)^T)
    #pragma unroll
    for (int i = 0; i < 2; i++)
        #pragma unroll
        for (int j = 0; j < 8; j++) acc[i][j] = 0.f;
    for (int k0 = 0; k0 < HH; k0 += 32) {
        {   int r = tid >> 3, cg = tid & 7;
            float4 v = *(const float4*)(Qc + (size_t)(t0 + r) * HH + k0 + cg * 4);
            xT[cg*4+0][r] = v.x; xT[cg*4+1][r] = v.y;
            xT[cg*4+2][r] = v.z; xT[cg*4+3][r] = v.w;
        }
        #pragma unroll
        for (int l = 0; l < 4; l++) {
            int f = tid + l * 256;
            int sr = f >> 3, cg = f & 7;
            float sv = Sc[sr];
            int gc = gcol(sr);
            float4 v = *(const float4*)(Zc + (size_t)sr * HH + k0 + cg * 4);
            wT[cg*4+0][gc] = v.x * sv; wT[cg*4+1][gc] = v.y * sv;
            wT[cg*4+2][gc] = v.z * sv; wT[cg*4+3][gc] = v.w * sv;
        }
        __syncthreads();
        #pragma unroll
        for (int kk = 0; kk < 32; kk++) {
            float2 xv = *(const float2*)&xT[kk][ty * 2];
            float4 w0 = *(const float4*)&wT[kk][gx];
            float4 w1 = *(const float4*)&wT[kk][gx + 4];
            float xa[2] = {xv.x, xv.y};
            float wa[8] = {w0.x, w0.y, w0.z, w0.w, w1.x, w1.y, w1.z, w1.w};
            #pragma unroll
            for (int i = 0; i < 2; i++)
                #pragma unroll
                for (int j = 0; j < 8; j++)
                    acc[i][j] += xa[i] * wa[j];
        }
        __syncthreads();
    }
    #pragma unroll
    for (int i = 0; i < 2; i++) {
        int tl = t0 + ty * 2 + i;
        float m[8];
        #pragma unroll
        for (int j = 0; j < 8; j++)
            m[j] = (tx * 8 + j <= tl) ? acc[i][j] : 0.f;
        float4 o0 = {m[0], m[1], m[2], m[3]};
        float4 o1 = {m[4], m[5], m[6], m[7]};
        *(float4*)&S[ty*2+i][gx]     = o0;
        *(float4*)&S[ty*2+i][gx + 4] = o1;
    }

    // ---- phase 2: acc = Q @ Mpre^T
    #pragma unroll
    for (int i = 0; i < 2; i++)
        #pragma unroll
        for (int j = 0; j < 8; j++) acc[i][j] = 0.f;
    for (int k0 = 0; k0 < HH; k0 += 32) {
        {   int r = tid >> 3, cg = tid & 7;
            float4 v = *(const float4*)(Qc + (size_t)(t0 + r) * HH + k0 + cg * 4);
            xT[cg*4+0][r] = v.x; xT[cg*4+1][r] = v.y;
            xT[cg*4+2][r] = v.z; xT[cg*4+3][r] = v.w;
        }
        #pragma unroll
        for (int l = 0; l < 4; l++) {
            int f = tid + l * 256;
            int h = f >> 3, cg = f & 7;
            int gc = gcol(h);
            float4 v = *(const float4*)(Mp + (size_t)h * HH + k0 + cg * 4);
            wT[cg*4+0][gc] = v.x; wT[cg*4+1][gc] = v.y;
            wT[cg*4+2][gc] = v.z; wT[cg*4+3][gc] = v.w;
        }
        __syncthreads();
        #pragma unroll
        for (int kk = 0; kk < 32; kk++) {
            float2 xv = *(const float2*)&xT[kk][ty * 2];
            float4 w0 = *(const float4*)&wT[kk][gx];
            float4 w1 = *(const float4*)&wT[kk][gx + 4];
            float xa[2] = {xv.x, xv.y};
            float wa[8] = {w0.x, w0.y, w0.z, w0.w, w1.x, w1.y, w1.z, w1.w};
            #pragma unroll
            for (int i = 0; i < 2; i++)
                #pragma unroll
                for (int j = 0; j < 8; j++)
                    acc[i][j] += xa[i] * wa[j];
        }
        __syncthreads();
    }

    // ---- phase 3: acc += S @ V
    for (int s0 = 0; s0 < CC; s0 += 32) {
        #pragma unroll
        for (int l = 0; l < 4; l++) {
            int f = tid + l * 256;
            int sr = f >> 5, cc = f & 31;
            int gc = cc * 4 + ((cc >> 3) << 2);
            float4 v = *(const float4*)(Vc + (size_t)(s0 + sr) * HH + cc * 4);
            *(float4*)&wT[sr][gc] = v;
        }
        __syncthreads();
        #pragma unroll
        for (int ss = 0; ss < 32; ss++) {
            float4 w0 = *(const float4*)&wT[ss][gx];
            float4 w1 = *(const float4*)&wT[ss][gx + 4];
            float wa[8] = {w0.x, w0.y, w0.z, w0.w, w1.x, w1.y, w1.z, w1.w};
            int sgc = gcol(s0 + ss);
            float sv[2] = {S[ty*2][sgc], S[ty*2+1][sgc]};
            #pragma unroll
            for (int i = 0; i < 2; i++)
                #pragma unroll
                for (int j = 0; j < 8; j++)
                    acc[i][j] += sv[i] * wa[j];
        }
        __syncthreads();
    }

    #pragma unroll
    for (int i = 0; i < 2; i++) {
        float* op = Oc + (size_t)(t0 + ty * 2 + i) * HH + tx * 8;
        float4 o0 = {acc[i][0], acc[i][1], acc[i][2], acc[i][3]};
        float4 o1 = {acc[i][4], acc[i][5], acc[i][6], acc[i][7]};
        *(float4*)op       = o0;
        *(float4*)(op + 4) = o1;
    }
}

// ---------------------------------------------------------------------------
// Output: out = O Wo^T + bo. Gapped woT.
// ---------------------------------------------------------------------------
__global__ __launch_bounds__(256) void out_kernel(
    const float* __restrict__ O, const float* __restrict__ Wo,
    const float* __restrict__ bo, float* __restrict__ out)
{
    const int row0 = blockIdx.x * 64;
    const int d0   = blockIdx.y * 128;

    __shared__ float oT[32][68];
    __shared__ float woT[32][WPAD];

    const int tid = threadIdx.x;
    const int tx = tid & 15;
    const int ty = tid >> 4;
    const int gx = tx * 8 + ((tx >> 2) << 2);

    float acc[4][8];
    #pragma unroll
    for (int i = 0; i < 4; i++)
        #pragma unroll
        for (int j = 0; j < 8; j++) acc[i][j] = 0.f;

    for (int k0 = 0; k0 < HH; k0 += 32) {
        #pragma unroll
        for (int l = 0; l < 2; l++) {
            int f = tid + l * 256;
            int r = f >> 3;
            int cg = f & 7;
            float4 v = *(const float4*)(O + (size_t)(row0 + r) * HH + k0 + cg * 4);
            oT[cg*4+0][r] = v.x; oT[cg*4+1][r] = v.y;
            oT[cg*4+2][r] = v.z; oT[cg*4+3][r] = v.w;
        }
        #pragma unroll
        for (int l = 0; l < 4; l++) {
            int f = tid + l * 256;
            int d = f >> 3;
            int cg = f & 7;
            int gc = gcol(d);
            float4 v = *(const float4*)(Wo + (size_t)(d0 + d) * HH + k0 + cg * 4);
            woT[cg*4+0][gc] = v.x; woT[cg*4+1][gc] = v.y;
            woT[cg*4+2][gc] = v.z; woT[cg*4+3][gc] = v.w;
        }
        __syncthreads();
        #pragma unroll
        for (int kk = 0; kk < 32; kk++) {
            float4 ov = *(const float4*)&oT[kk][ty * 4];
            float4 w0 = *(const float4*)&woT[kk][gx];
            float4 w1 = *(const float4*)&woT[kk][gx + 4];
            float oa[4] = {ov.x, ov.y, ov.z, ov.w};
            float wa[8] = {w0.x, w0.y, w0.z, w0.w, w1.x, w1.y, w1.z, w1.w};
            #pragma unroll
            for (int i = 0; i < 4; i++)
                #pragma unroll
                for (int j = 0; j < 8; j++)
                    acc[i][j] += oa[i] * wa[j];
        }
        __syncthreads();
    }

    #pragma unroll
    for (int i = 0; i < 4; i++) {
        int row = row0 + ty * 4 + i;
        #pragma unroll
        for (int j = 0; j < 8; j++) acc[i][j] += bo[d0 + tx * 8 + j];
        float4 o0 = {acc[i][0], acc[i][1], acc[i][2], acc[i][3]};
        float4 o1 = {acc[i][4], acc[i][5], acc[i][6], acc[i][7]};
        *(float4*)(out + (size_t)row * DD + d0 + tx * 8)     = o0;
        *(float4*)(out + (size_t)row * DD + d0 + tx * 8 + 4) = o1;
    }
}

extern "C" void kernel_launch(void* const* d_in, const int* in_sizes, int n_in,
                              void* d_out, int out_size, void* d_ws, size_t ws_size,
                              hipStream_t stream) {
    const float* x  = (const float*)d_in[0];
    const float* Wq = (const float*)d_in[1];
    const float* bq = (const float*)d_in[2];
    const float* Wk = (const float*)d_in[3];
    const float* bk = (const float*)d_in[4];
    const float* Wv = (const float*)d_in[5];
    const float* bv = (const float*)d_in[6];
    const float* Wo = (const float*)d_in[7];
    const float* bo = (const float*)d_in[8];
    float* out = (float*)d_out;

    float* ws = (float*)d_ws;
    float* Q = ws;
    float* K = ws + (size_t)BT * HH;
    float* V = ws + (size_t)2 * BT * HH;
    float* O = ws + (size_t)3 * BT * HH;

    // d_out scratch (32 MB), all dead before out_kernel writes out:
    float* db   = (float*)d_out;
    float* rn   = db;
    float* Sarr = db + BT;
    float* Z    = db + (size_t)(1u << 18);
    float* G    = db + (size_t)(1u << 21);
    float* Mpre = db + (size_t)3 * (1u << 20);
    float* H    = db + (size_t)4 * (1u << 20);
    float* Bmat = db + (size_t)5 * (1u << 20);
    float* Ainv = db + (size_t)6 * (1u << 20);

    // 1. K projection (+rn)
    projk_kernel<<<BT / 32, 256, 0, stream>>>(x, Wk, bk, K, rn);

    // 2. Q/V projection (full-GPU; Q half computes s = q.k)
    dim3 qvg(BT / 32, 2);
    projqv_kernel<<<qvg, 256, 0, stream>>>(x, Wq, bq, Wv, bv, K, Q, V, Sarr);

    // 3. chunk-start inverse-Gram pipeline: H -> B_start -> A_start
    dim3 hg(NSCAN, 4);
    ugram_kernel<<<hg, 256, 0, stream>>>(K, rn, H);
    dim3 bp(BB, HH * HH / 256);
    bprefix_kernel<<<bp, 256, 0, stream>>>(H, Bmat);
    invert_kernel<<<NSCAN, 256, 0, stream>>>(Bmat, Ainv);

    // 4. 64 parallel chunk-scans
    scan_kernel<<<NSCAN, 512, 0, stream>>>(K, rn, Ainv, Z);

    // 5. phase-2 (alpha = s*z folded into staging) + output
    dim3 gg(NSCAN, 4);
    gram_kernel<<<gg, 256, 0, stream>>>(V, Z, Sarr, G);
    prefix_kernel<<<bp, 256, 0, stream>>>(G, Mpre);
    dim3 cg(NSCAN, 4);
    ochunk_kernel<<<cg, 256, 0, stream>>>(Q, Z, Sarr, V, Mpre, O);
    dim3 og(BT / 64, DD / 128);
    out_kernel<<<og, 256, 0, stream>>>(O, Wo, bo, out);
}

// Round 21
// 392.705 us; speedup vs baseline: 3.1181x; 1.1642x over previous
//
#include <hip/hip_runtime.h>
#include <math.h>

#define BB 4
#define TT 2048
#define DD 1024
#define HH 128
#define EPSF 1e-6f
#define BT (BB*TT)   // 8192
#define CC 128       // chunk length
#define NCH (TT/CC)  // 16 chunks per batch
#define NIC (CC/2)   // 64 double-steps per chunk
#define NSCAN (BB*NCH)  // 64 chunk-scan blocks
#define WPAD 140     // gapped row stride: col h stored at h + (h>>5)*4

typedef float f32x2 __attribute__((ext_vector_type(2)));

// gap-insertion column map (reads 2-way bank-aliased = free)
__device__ __forceinline__ int gcol(int h) { return h + ((h >> 5) << 2); }

// 8-lane butterfly sum, pure DPP/VALU (no DS pipe)
__device__ __forceinline__ float red8(float x) {
    x += __int_as_float(__builtin_amdgcn_mov_dpp(__float_as_int(x), 0xB1,  0xF, 0xF, true));
    x += __int_as_float(__builtin_amdgcn_mov_dpp(__float_as_int(x), 0x4E,  0xF, 0xF, true));
    x += __int_as_float(__builtin_amdgcn_mov_dpp(__float_as_int(x), 0x141, 0xF, 0xF, true));
    return x;
}
// 16-lane butterfly sum (adds ROW_MIRROR)
__device__ __forceinline__ float red16(float x) {
    x = red8(x);
    x += __int_as_float(__builtin_amdgcn_mov_dpp(__float_as_int(x), 0x140, 0xF, 0xF, true));
    return x;
}

// ---------------------------------------------------------------------------
// proj3: all three projections, k-split. Grid (BT/64, 6): blockIdx.y ->
// which = y>>1 (0=K,1=Q,2=V), half = y&1 (k in [half*512, half*512+512)).
// 64-row tiles, acc[4][8] (3 DS reads / 32 FMA), packed f32x2 FMA.
// BUGFIX vs R20: xT must be [32][68] for the 64-row tile (was [32][36],
// projk's 32-row size -> staging overflow -> absmax 747).
// Writes k-half partial sums (no bias) to Pp[(which*2+half)*BT*HH + ...].
// ---------------------------------------------------------------------------
__global__ __launch_bounds__(256) void proj3_kernel(
    const float* __restrict__ x,
    const float* __restrict__ Wk, const float* __restrict__ Wq,
    const float* __restrict__ Wv, float* __restrict__ Pp)
{
    const int row0  = blockIdx.x * 64;
    const int which = blockIdx.y >> 1;
    const int half  = blockIdx.y & 1;
    const float* W = (which == 0) ? Wk : (which == 1) ? Wq : Wv;

    __shared__ float xT[32][68];
    __shared__ float wT[32][WPAD];

    const int tid = threadIdx.x;
    const int tx = tid & 15;
    const int ty = tid >> 4;       // 0..15, rows ty*4..+4
    const int gx = tx * 8 + ((tx >> 2) << 2);

    f32x2 acc2[4][4];
    #pragma unroll
    for (int i = 0; i < 4; i++)
        #pragma unroll
        for (int jp = 0; jp < 4; jp++) acc2[i][jp] = (f32x2){0.f, 0.f};

    const int kbase = half * (DD / 2);
    for (int k0 = kbase; k0 < kbase + DD / 2; k0 += 32) {
        #pragma unroll
        for (int l = 0; l < 2; l++) {    // xT: 64 rows x 32 k (transposed)
            int f = tid + l * 256;
            int r = f >> 3, cg = f & 7;
            float4 v = *(const float4*)(x + (size_t)(row0 + r) * DD + k0 + cg * 4);
            xT[cg*4+0][r] = v.x; xT[cg*4+1][r] = v.y;
            xT[cg*4+2][r] = v.z; xT[cg*4+3][r] = v.w;
        }
        #pragma unroll
        for (int l = 0; l < 4; l++) {    // wT: 128 h x 32 k (gapped)
            int f = tid + l * 256;
            int h = f >> 3, cg = f & 7;
            int gc = gcol(h);
            float4 v = *(const float4*)(W + (size_t)h * DD + k0 + cg * 4);
            wT[cg*4+0][gc] = v.x; wT[cg*4+1][gc] = v.y;
            wT[cg*4+2][gc] = v.z; wT[cg*4+3][gc] = v.w;
        }
        __syncthreads();
        #pragma unroll
        for (int kk = 0; kk < 32; kk++) {
            float4 xv = *(const float4*)&xT[kk][ty * 4];
            float4 w0 = *(const float4*)&wT[kk][gx];
            float4 w1 = *(const float4*)&wT[kk][gx + 4];
            f32x2 wa[4] = {{w0.x, w0.y}, {w0.z, w0.w},
                           {w1.x, w1.y}, {w1.z, w1.w}};
            float xa[4] = {xv.x, xv.y, xv.z, xv.w};
            #pragma unroll
            for (int i = 0; i < 4; i++) {
                const f32x2 xb = {xa[i], xa[i]};
                #pragma unroll
                for (int jp = 0; jp < 4; jp++)
                    acc2[i][jp] += xb * wa[jp];
            }
        }
        __syncthreads();
    }

    float* Pd = Pp + (size_t)(which * 2 + half) * BT * HH;
    #pragma unroll
    for (int i = 0; i < 4; i++) {
        int row = row0 + ty * 4 + i;
        float4 o0 = {acc2[i][0].x, acc2[i][0].y, acc2[i][1].x, acc2[i][1].y};
        float4 o1 = {acc2[i][2].x, acc2[i][2].y, acc2[i][3].x, acc2[i][3].y};
        *(float4*)(Pd + (size_t)row * HH + tx * 8)     = o0;
        *(float4*)(Pd + (size_t)row * HH + tx * 8 + 4) = o1;
    }
}

// ---------------------------------------------------------------------------
// combine: P = part0 + part1 + bias for K,Q,V; epilogues rn = 1/(||k||+eps)
// and s = q.k. Memory-bound (36 MB). Grid BT/32, 256 threads.
// ---------------------------------------------------------------------------
__global__ __launch_bounds__(256) void combine_kernel(
    const float* __restrict__ Pp,
    const float* __restrict__ bk, const float* __restrict__ bq,
    const float* __restrict__ bv,
    float* __restrict__ K, float* __restrict__ Q, float* __restrict__ V,
    float* __restrict__ rn, float* __restrict__ Sarr)
{
    const int row0 = blockIdx.x * 32;
    const int tid = threadIdx.x;
    const int tx = tid & 15;
    const int ty = tid >> 4;       // rows ty*2..+2

    #pragma unroll
    for (int i = 0; i < 2; i++) {
        const int row = row0 + ty * 2 + i;
        const size_t base = (size_t)row * HH + tx * 8;

        float kv[8], qv[8], vv[8];
        #pragma unroll
        for (int w = 0; w < 3; w++) {
            const float* p0 = Pp + (size_t)(w * 2)     * BT * HH + base;
            const float* p1 = Pp + (size_t)(w * 2 + 1) * BT * HH + base;
            const float* bias = (w == 0) ? bk : (w == 1) ? bq : bv;
            float* dst = (w == 0) ? (kv) : (w == 1) ? (qv) : (vv);
            float4 a0 = *(const float4*)p0;
            float4 a1 = *(const float4*)(p0 + 4);
            float4 c0 = *(const float4*)p1;
            float4 c1 = *(const float4*)(p1 + 4);
            dst[0] = a0.x + c0.x + bias[tx*8+0];
            dst[1] = a0.y + c0.y + bias[tx*8+1];
            dst[2] = a0.z + c0.z + bias[tx*8+2];
            dst[3] = a0.w + c0.w + bias[tx*8+3];
            dst[4] = a1.x + c1.x + bias[tx*8+4];
            dst[5] = a1.y + c1.y + bias[tx*8+5];
            dst[6] = a1.z + c1.z + bias[tx*8+6];
            dst[7] = a1.w + c1.w + bias[tx*8+7];
        }

        float4 k0 = {kv[0], kv[1], kv[2], kv[3]};
        float4 k1 = {kv[4], kv[5], kv[6], kv[7]};
        float4 q0 = {qv[0], qv[1], qv[2], qv[3]};
        float4 q1 = {qv[4], qv[5], qv[6], qv[7]};
        float4 v0 = {vv[0], vv[1], vv[2], vv[3]};
        float4 v1 = {vv[4], vv[5], vv[6], vv[7]};
        *(float4*)(K + base)     = k0;
        *(float4*)(K + base + 4) = k1;
        *(float4*)(Q + base)     = q0;
        *(float4*)(Q + base + 4) = q1;
        *(float4*)(V + base)     = v0;
        *(float4*)(V + base + 4) = v1;

        float p2 = 0.f, pkq = 0.f;
        #pragma unroll
        for (int j = 0; j < 8; j++) {
            p2  += kv[j] * kv[j];
            pkq += qv[j] * kv[j];
        }
        p2  = red16(p2);
        pkq = red16(pkq);
        if (tx == 0) {
            rn[row]   = 1.0f / (sqrtf(p2) + EPSF);
            Sarr[row] = pkq;
        }
    }
}

// ---------------------------------------------------------------------------
// H[b][c] = sum_{t in chunk} (rn k)(rn k)^T. Grid (64, 4), gapped aT.
// ---------------------------------------------------------------------------
__global__ __launch_bounds__(256) void ugram_kernel(
    const float* __restrict__ K, const float* __restrict__ rn,
    float* __restrict__ H)
{
    const int bi = blockIdx.x;
    const int r0 = blockIdx.y * 32;

    const float* Kc = K + (size_t)bi * CC * HH;
    const float* Rc = rn + (size_t)bi * CC;

    __shared__ float vT[32][36];
    __shared__ float aT[32][WPAD];

    const int tid = threadIdx.x;
    const int tx = tid & 15, ty = tid >> 4;
    const int gx = tx * 8 + ((tx >> 2) << 2);

    float acc[2][8];
    #pragma unroll
    for (int i = 0; i < 2; i++)
        #pragma unroll
        for (int j = 0; j < 8; j++) acc[i][j] = 0.f;

    for (int s0 = 0; s0 < CC; s0 += 32) {
        {   int sr = tid >> 3, rc4 = tid & 7;
            float sc = Rc[s0 + sr];
            float4 v = *(const float4*)(Kc + (size_t)(s0 + sr) * HH + r0 + rc4 * 4);
            v.x *= sc; v.y *= sc; v.z *= sc; v.w *= sc;
            *(float4*)&vT[sr][rc4 * 4] = v;
        }
        #pragma unroll
        for (int l = 0; l < 4; l++) {
            int f = tid + l * 256;
            int sr = f >> 5, cc = f & 31;
            float sc = Rc[s0 + sr];
            int gc = cc * 4 + ((cc >> 3) << 2);
            float4 v = *(const float4*)(Kc + (size_t)(s0 + sr) * HH + cc * 4);
            v.x *= sc; v.y *= sc; v.z *= sc; v.w *= sc;
            *(float4*)&aT[sr][gc] = v;
        }
        __syncthreads();
        #pragma unroll
        for (int ss = 0; ss < 32; ss++) {
            float2 vv = *(const float2*)&vT[ss][ty * 2];
            float4 a0 = *(const float4*)&aT[ss][gx];
            float4 a1 = *(const float4*)&aT[ss][gx + 4];
            float va[2] = {vv.x, vv.y};
            float aa[8] = {a0.x, a0.y, a0.z, a0.w, a1.x, a1.y, a1.z, a1.w};
            #pragma unroll
            for (int i = 0; i < 2; i++)
                #pragma unroll
                for (int j = 0; j < 8; j++)
                    acc[i][j] += va[i] * aa[j];
        }
        __syncthreads();
    }

    #pragma unroll
    for (int i = 0; i < 2; i++) {
        float* hp = H + ((size_t)bi * HH + r0 + ty * 2 + i) * HH + tx * 8;
        float4 o0 = {acc[i][0], acc[i][1], acc[i][2], acc[i][3]};
        float4 o1 = {acc[i][4], acc[i][5], acc[i][6], acc[i][7]};
        *(float4*)hp       = o0;
        *(float4*)(hp + 4) = o1;
    }
}

// ---------------------------------------------------------------------------
// B_start(c) = I + sum_{c'<c} H[c']. Exclusive prefix.
// ---------------------------------------------------------------------------
__global__ __launch_bounds__(256) void bprefix_kernel(
    const float* __restrict__ H, float* __restrict__ Bm)
{
    const int b   = blockIdx.x;
    const int idx = blockIdx.y * 256 + threadIdx.x;
    const int row = idx >> 7, col = idx & 127;
    float run = (row == col) ? 1.0f : 0.0f;
    for (int i = 0; i < NCH; i++) {
        size_t off = ((size_t)b * NCH + i) * HH * HH + idx;
        Bm[off] = run;
        run += H[off];
    }
}

// ---------------------------------------------------------------------------
// Invert 128x128 SPD B -> Ainv (static-indexed GJ, verified).
// ---------------------------------------------------------------------------
__global__ __launch_bounds__(256) void invert_kernel(
    const float* __restrict__ Bm, float* __restrict__ Ainv)
{
    const int bi  = blockIdx.x;
    const int tid = threadIdx.x;
    const int tr  = tid >> 4;      // row block 0..15
    const int tc  = tid & 15;      // col block 0..15
    const float* Bp = Bm  + (size_t)bi * HH * HH;
    float*       Ap = Ainv + (size_t)bi * HH * HH;

    __shared__ float rowk[HH];
    __shared__ float colk[HH];
    __shared__ float dsh;

    float M[8][8];
    #pragma unroll
    for (int ii = 0; ii < 8; ii++) {
        float4 a = *(const float4*)(Bp + (size_t)(tr*8+ii) * HH + tc*8);
        float4 b = *(const float4*)(Bp + (size_t)(tr*8+ii) * HH + tc*8 + 4);
        M[ii][0]=a.x; M[ii][1]=a.y; M[ii][2]=a.z; M[ii][3]=a.w;
        M[ii][4]=b.x; M[ii][5]=b.y; M[ii][6]=b.z; M[ii][7]=b.w;
    }

    for (int krb = 0; krb < 16; krb++) {
        const bool myrow = (tr == krb);
        const bool mycol = (tc == krb);
        #pragma unroll
        for (int kl = 0; kl < 8; kl++) {
            if (myrow && mycol) dsh = M[kl][kl];
            __syncthreads();
            const float ip = 1.0f / dsh;
            if (myrow) {
                #pragma unroll
                for (int jj = 0; jj < 8; jj++) {
                    float v = (mycol && jj == kl) ? ip : M[kl][jj] * ip;
                    M[kl][jj] = v;
                    rowk[tc*8 + jj] = v;
                }
            }
            if (mycol) {
                #pragma unroll
                for (int ii = 0; ii < 8; ii++)
                    colk[tr*8 + ii] = M[ii][kl];
            }
            __syncthreads();
            float rk[8];
            #pragma unroll
            for (int jj = 0; jj < 8; jj++) rk[jj] = rowk[tc*8 + jj];
            #pragma unroll
            for (int ii = 0; ii < 8; ii++) {
                const bool isk = myrow && (ii == kl);
                const float f = colk[tr*8 + ii];
                #pragma unroll
                for (int jj = 0; jj < 8; jj++) {
                    float upd = (mycol && jj == kl)
                              ? (-f * ip)
                              : fmaf(-f, rk[jj], M[ii][jj]);
                    M[ii][jj] = isk ? M[ii][jj] : upd;
                }
            }
            __syncthreads();
        }
    }

    #pragma unroll
    for (int ii = 0; ii < 8; ii++) {
        float4 a = {M[ii][0], M[ii][1], M[ii][2], M[ii][3]};
        float4 b = {M[ii][4], M[ii][5], M[ii][6], M[ii][7]};
        *(float4*)(Ap + (size_t)(tr*8+ii) * HH + tc*8)     = a;
        *(float4*)(Ap + (size_t)(tr*8+ii) * HH + tc*8 + 4) = b;
    }
}

// ---------------------------------------------------------------------------
// scan_kernel: 64 PARALLEL chunk-scans (v8 double-step body, verified).
// ---------------------------------------------------------------------------
__global__ __launch_bounds__(512, 1) void scan_kernel(
    const float* __restrict__ K, const float* __restrict__ rn,
    const float* __restrict__ Ainv, float* __restrict__ Z)
{
    __shared__ float Ybc[2][2][8 * 20];   // [buf][y1/y2], padded
    __shared__ float kst[2][2][8 * 20];   // [buf][k1/k2], padded

    const int bi  = blockIdx.x;          // b*NCH + c
    const int tid = threadIdx.x;
    const int r2  = tid >> 3;
    const int o8  = tid & 7;
    const int c0  = o8 * 16;
    const int r0  = 2 * r2, r1 = r0 + 1;

    const float* Kb   = K  + (size_t)bi * CC * HH;
    float*       Zb   = Z  + (size_t)bi * CC * HH;
    const float* rn_b = rn + (size_t)bi * CC;
    const float* Ap   = Ainv + (size_t)bi * HH * HH;

    f32x2 Ar0[8], Ar1[8];
    #pragma unroll
    for (int j = 0; j < 4; j++) {
        float4 a0 = *(const float4*)(Ap + (size_t)r0 * HH + c0 + 4 * j);
        float4 a1 = *(const float4*)(Ap + (size_t)r1 * HH + c0 + 4 * j);
        Ar0[2*j] = (f32x2){a0.x, a0.y}; Ar0[2*j+1] = (f32x2){a0.z, a0.w};
        Ar1[2*j] = (f32x2){a1.x, a1.y}; Ar1[2*j+1] = (f32x2){a1.z, a1.w};
    }

    const int woff = (r0 >> 4) * 20 + (r0 & 15);
    const int roff = o8 * 20;

    const bool ldr    = tid < 64;
    const int  whichk = tid >> 5;
    const int  l32    = tid & 31;
    const int  lpoff  = (l32 >> 2) * 20 + (l32 & 3) * 4;   // v8 8x20 mapping

    float4 pld = {0.f, 0.f, 0.f, 0.f};
    if (ldr) {
        float4 d0 = *(const float4*)(Kb + (size_t)whichk * HH + l32 * 4);
        *(float4*)&kst[0][whichk][lpoff] = d0;
        pld = *(const float4*)(Kb + (size_t)(2 + whichk) * HH + l32 * 4);
    }
    float2 rs_cur = ((const float2*)rn_b)[0];
    float2 rs_nxt = ((const float2*)rn_b)[1];
    __syncthreads();

    f32x2 k1[8], k2[8];
    #pragma unroll
    for (int j = 0; j < 4; j++) {
        float4 t1 = *(const float4*)&kst[0][0][roff + 4 * j];
        float4 t2 = *(const float4*)&kst[0][1][roff + 4 * j];
        k1[2*j] = (f32x2){t1.x, t1.y}; k1[2*j+1] = (f32x2){t1.z, t1.w};
        k2[2*j] = (f32x2){t2.x, t2.y}; k2[2*j+1] = (f32x2){t2.z, t2.w};
    }

    for (int i = 0; i < NIC; ++i) {
        const int yb = i & 1;
        const int nk = (i + 1) & 1;

        f32x2 y10 = {0,0}, y11 = {0,0}, y20 = {0,0}, y21 = {0,0};
        #pragma unroll
        for (int j = 0; j < 8; j++) {
            y10 += Ar0[j] * k1[j];
            y11 += Ar1[j] * k1[j];
            y20 += Ar0[j] * k2[j];
            y21 += Ar1[j] * k2[j];
        }
        float y1r0 = red8(y10.x + y10.y);
        float y1r1 = red8(y11.x + y11.y);
        float y2r0 = red8(y20.x + y20.y);
        float y2r1 = red8(y21.x + y21.y);
        if (o8 == 0) {
            *(float2*)&Ybc[yb][0][woff] = make_float2(y1r0, y1r1);
            *(float2*)&Ybc[yb][1][woff] = make_float2(y2r0, y2r1);
        }

        if (ldr && i + 1 < NIC) {
            *(float4*)&kst[nk][whichk][lpoff] = pld;
            if (i + 2 < NIC)
                pld = *(const float4*)(Kb + (size_t)(2*(i+2) + whichk) * HH + l32 * 4);
        }

        __syncthreads();

        f32x2 av1[8], av2[8];
        #pragma unroll
        for (int j = 0; j < 4; j++) {
            float4 t1 = *(const float4*)&Ybc[yb][0][roff + 4 * j];
            float4 t2 = *(const float4*)&Ybc[yb][1][roff + 4 * j];
            av1[2*j] = (f32x2){t1.x, t1.y}; av1[2*j+1] = (f32x2){t1.z, t1.w};
            av2[2*j] = (f32x2){t2.x, t2.y}; av2[2*j+1] = (f32x2){t2.z, t2.w};
        }

        f32x2 e11v = {0,0}, e21v = {0,0}, e22v = {0,0};
        #pragma unroll
        for (int j = 0; j < 8; j++) {
            e11v += av1[j] * k1[j];
            e21v += av1[j] * k2[j];
            e22v += av2[j] * k2[j];
        }
        float e11 = red8(e11v.x + e11v.y);
        float e21 = red8(e21v.x + e21v.y);
        float e22 = red8(e22v.x + e22v.y);

        #pragma unroll
        for (int j = 0; j < 4; j++) {
            float4 t1 = *(const float4*)&kst[nk][0][roff + 4 * j];
            float4 t2 = *(const float4*)&kst[nk][1][roff + 4 * j];
            k1[2*j] = (f32x2){t1.x, t1.y}; k1[2*j+1] = (f32x2){t1.z, t1.w};
            k2[2*j] = (f32x2){t2.x, t2.y}; k2[2*j+1] = (f32x2){t2.z, t2.w};
        }

        const float rn1 = rs_cur.x, rn2 = rs_cur.y;
        const float rn1sq = rn1 * rn1;
        const float rn2sq = rn2 * rn2;
        const float i1   = __builtin_amdgcn_rcpf(1.0f + rn1sq * e11);
        const float beta = rn1sq * e21 * i1;
        const float i2   = __builtin_amdgcn_rcpf(1.0f + rn2sq * (e22 - beta * e21));
        const float p2r0 = y2r0 - beta * y1r0;
        const float p2r1 = y2r1 - beta * y1r1;
        const float za1  = rn1 * i1;
        const float za2  = rn2 * i2;
        if (o8 == 0) {
            *(float2*)(Zb + (size_t)(2*i)     * HH + r0) =
                make_float2(za1 * y1r0, za1 * y1r1);
            *(float2*)(Zb + (size_t)(2*i + 1) * HH + r0) =
                make_float2(za2 * p2r0, za2 * p2r1);
        }

        const float cA1 = rn1sq * i1, cA2 = rn2sq * i2;
        const f32x2 u10 = {cA1 * y1r0, cA1 * y1r0};
        const f32x2 u11 = {cA1 * y1r1, cA1 * y1r1};
        const f32x2 u20 = {cA2 * p2r0, cA2 * p2r0};
        const f32x2 u21 = {cA2 * p2r1, cA2 * p2r1};
        const f32x2 bbv = {beta, beta};
        #pragma unroll
        for (int j = 0; j < 8; j++) {
            f32x2 pp = av2[j] - bbv * av1[j];
            Ar0[j] = Ar0[j] - u10 * av1[j] - u20 * pp;
            Ar1[j] = Ar1[j] - u11 * av1[j] - u21 * pp;
        }

        rs_cur = rs_nxt;
        if (i + 2 < NIC) rs_nxt = ((const float2*)rn_b)[i + 2];
    }
}

// ---------------------------------------------------------------------------
// Phase 2a: G[b][c] = V_chunk^T @ (diag(s) Z_chunk). Gapped aT.
// ---------------------------------------------------------------------------
__global__ __launch_bounds__(256) void gram_kernel(
    const float* __restrict__ V, const float* __restrict__ Z,
    const float* __restrict__ Sarr, float* __restrict__ G)
{
    const int bi = blockIdx.x;
    const int r0 = blockIdx.y * 32;

    const float* Vc = V + (size_t)bi * CC * HH;
    const float* Zc = Z + (size_t)bi * CC * HH;
    const float* Sc = Sarr + (size_t)bi * CC;

    __shared__ float vT[32][36];
    __shared__ float aT[32][WPAD];

    const int tid = threadIdx.x;
    const int tx = tid & 15, ty = tid >> 4;
    const int gx = tx * 8 + ((tx >> 2) << 2);

    float acc[2][8];
    #pragma unroll
    for (int i = 0; i < 2; i++)
        #pragma unroll
        for (int j = 0; j < 8; j++) acc[i][j] = 0.f;

    for (int s0 = 0; s0 < CC; s0 += 32) {
        {   int sr = tid >> 3, rc = tid & 7;
            float4 v = *(const float4*)(Vc + (size_t)(s0 + sr) * HH + r0 + rc * 4);
            *(float4*)&vT[sr][rc * 4] = v;
        }
        #pragma unroll
        for (int l = 0; l < 4; l++) {
            int f = tid + l * 256;
            int sr = f >> 5, cc = f & 31;
            float sv = Sc[s0 + sr];
            int gc = cc * 4 + ((cc >> 3) << 2);
            float4 v = *(const float4*)(Zc + (size_t)(s0 + sr) * HH + cc * 4);
            v.x *= sv; v.y *= sv; v.z *= sv; v.w *= sv;
            *(float4*)&aT[sr][gc] = v;
        }
        __syncthreads();
        #pragma unroll
        for (int ss = 0; ss < 32; ss++) {
            float2 vv = *(const float2*)&vT[ss][ty * 2];
            float4 a0 = *(const float4*)&aT[ss][gx];
            float4 a1 = *(const float4*)&aT[ss][gx + 4];
            float va[2] = {vv.x, vv.y};
            float aa[8] = {a0.x, a0.y, a0.z, a0.w, a1.x, a1.y, a1.z, a1.w};
            #pragma unroll
            for (int i = 0; i < 2; i++)
                #pragma unroll
                for (int j = 0; j < 8; j++)
                    acc[i][j] += va[i] * aa[j];
        }
        __syncthreads();
    }

    #pragma unroll
    for (int i = 0; i < 2; i++) {
        float* gp = G + ((size_t)bi * HH + r0 + ty * 2 + i) * HH + tx * 8;
        float4 o0 = {acc[i][0], acc[i][1], acc[i][2], acc[i][3]};
        float4 o1 = {acc[i][4], acc[i][5], acc[i][6], acc[i][7]};
        *(float4*)gp       = o0;
        *(float4*)(gp + 4) = o1;
    }
}

// ---------------------------------------------------------------------------
// Phase 2b: exclusive prefix Mpre.
// ---------------------------------------------------------------------------
__global__ __launch_bounds__(256) void prefix_kernel(
    const float* __restrict__ G, float* __restrict__ Mpre)
{
    const int b   = blockIdx.x;
    const int idx = blockIdx.y * 256 + threadIdx.x;
    float run = 0.f;
    for (int i = 0; i < NCH; i++) {
        size_t off = ((size_t)b * NCH + i) * HH * HH + idx;
        Mpre[off] = run;
        run += G[off];
    }
}

// ---------------------------------------------------------------------------
// Phase 2c: O = Q Mpre^T + tril(Q (sZ)^T) V. Grid (64,4). Gapped wT/S.
// ---------------------------------------------------------------------------
__global__ __launch_bounds__(256) void ochunk_kernel(
    const float* __restrict__ Q, const float* __restrict__ Z,
    const float* __restrict__ Sarr, const float* __restrict__ V,
    const float* __restrict__ Mpre, float* __restrict__ O)
{
    const int bi = blockIdx.x;
    const int t0 = blockIdx.y * 32;

    const float* Qc = Q    + (size_t)bi * CC * HH;
    const float* Zc = Z    + (size_t)bi * CC * HH;
    const float* Vc = V    + (size_t)bi * CC * HH;
    const float* Sc = Sarr + (size_t)bi * CC;
    const float* Mp = Mpre + (size_t)bi * HH * HH;
    float*       Oc = O    + (size_t)bi * CC * HH;

    __shared__ float S[32][WPAD];
    __shared__ float xT[32][36];
    __shared__ float wT[32][WPAD];

    const int tid = threadIdx.x;
    const int tx = tid & 15, ty = tid >> 4;
    const int gx = tx * 8 + ((tx >> 2) << 2);

    float acc[2][8];

    // ---- phase 1: S = tril(Q (sZ)^T)
    #pragma unroll
    for (int i = 0; i < 2; i++)
        #pragma unroll
        for (int j = 0; j < 8; j++) acc[i][j] = 0.f;
    for (int k0 = 0; k0 < HH; k0 += 32) {
        {   int r = tid >> 3, cg = tid & 7;
            float4 v = *(const float4*)(Qc + (size_t)(t0 + r) * HH + k0 + cg * 4);
            xT[cg*4+0][r] = v.x; xT[cg*4+1][r] = v.y;
            xT[cg*4+2][r] = v.z; xT[cg*4+3][r] = v.w;
        }
        #pragma unroll
        for (int l = 0; l < 4; l++) {
            int f = tid + l * 256;
            int sr = f >> 3, cg = f & 7;
            float sv = Sc[sr];
            int gc = gcol(sr);
            float4 v = *(const float4*)(Zc + (size_t)sr * HH + k0 + cg * 4);
            wT[cg*4+0][gc] = v.x * sv; wT[cg*4+1][gc] = v.y * sv;
            wT[cg*4+2][gc] = v.z * sv; wT[cg*4+3][gc] = v.w * sv;
        }
        __syncthreads();
        #pragma unroll
        for (int kk = 0; kk < 32; kk++) {
            float2 xv = *(const float2*)&xT[kk][ty * 2];
            float4 w0 = *(const float4*)&wT[kk][gx];
            float4 w1 = *(const float4*)&wT[kk][gx + 4];
            float xa[2] = {xv.x, xv.y};
            float wa[8] = {w0.x, w0.y, w0.z, w0.w, w1.x, w1.y, w1.z, w1.w};
            #pragma unroll
            for (int i = 0; i < 2; i++)
                #pragma unroll
                for (int j = 0; j < 8; j++)
                    acc[i][j] += xa[i] * wa[j];
        }
        __syncthreads();
    }
    #pragma unroll
    for (int i = 0; i < 2; i++) {
        int tl = t0 + ty * 2 + i;
        float m[8];
        #pragma unroll
        for (int j = 0; j < 8; j++)
            m[j] = (tx * 8 + j <= tl) ? acc[i][j] : 0.f;
        float4 o0 = {m[0], m[1], m[2], m[3]};
        float4 o1 = {m[4], m[5], m[6], m[7]};
        *(float4*)&S[ty*2+i][gx]     = o0;
        *(float4*)&S[ty*2+i][gx + 4] = o1;
    }

    // ---- phase 2: acc = Q @ Mpre^T
    #pragma unroll
    for (int i = 0; i < 2; i++)
        #pragma unroll
        for (int j = 0; j < 8; j++) acc[i][j] = 0.f;
    for (int k0 = 0; k0 < HH; k0 += 32) {
        {   int r = tid >> 3, cg = tid & 7;
            float4 v = *(const float4*)(Qc + (size_t)(t0 + r) * HH + k0 + cg * 4);
            xT[cg*4+0][r] = v.x; xT[cg*4+1][r] = v.y;
            xT[cg*4+2][r] = v.z; xT[cg*4+3][r] = v.w;
        }
        #pragma unroll
        for (int l = 0; l < 4; l++) {
            int f = tid + l * 256;
            int h = f >> 3, cg = f & 7;
            int gc = gcol(h);
            float4 v = *(const float4*)(Mp + (size_t)h * HH + k0 + cg * 4);
            wT[cg*4+0][gc] = v.x; wT[cg*4+1][gc] = v.y;
            wT[cg*4+2][gc] = v.z; wT[cg*4+3][gc] = v.w;
        }
        __syncthreads();
        #pragma unroll
        for (int kk = 0; kk < 32; kk++) {
            float2 xv = *(const float2*)&xT[kk][ty * 2];
            float4 w0 = *(const float4*)&wT[kk][gx];
            float4 w1 = *(const float4*)&wT[kk][gx + 4];
            float xa[2] = {xv.x, xv.y};
            float wa[8] = {w0.x, w0.y, w0.z, w0.w, w1.x, w1.y, w1.z, w1.w};
            #pragma unroll
            for (int i = 0; i < 2; i++)
                #pragma unroll
                for (int j = 0; j < 8; j++)
                    acc[i][j] += xa[i] * wa[j];
        }
        __syncthreads();
    }

    // ---- phase 3: acc += S @ V
    for (int s0 = 0; s0 < CC; s0 += 32) {
        #pragma unroll
        for (int l = 0; l < 4; l++) {
            int f = tid + l * 256;
            int sr = f >> 5, cc = f & 31;
            int gc = cc * 4 + ((cc >> 3) << 2);
            float4 v = *(const float4*)(Vc + (size_t)(s0 + sr) * HH + cc * 4);
            *(float4*)&wT[sr][gc] = v;
        }
        __syncthreads();
        #pragma unroll
        for (int ss = 0; ss < 32; ss++) {
            float4 w0 = *(const float4*)&wT[ss][gx];
            float4 w1 = *(const float4*)&wT[ss][gx + 4];
            float wa[8] = {w0.x, w0.y, w0.z, w0.w, w1.x, w1.y, w1.z, w1.w};
            int sgc = gcol(s0 + ss);
            float sv[2] = {S[ty*2][sgc], S[ty*2+1][sgc]};
            #pragma unroll
            for (int i = 0; i < 2; i++)
                #pragma unroll
                for (int j = 0; j < 8; j++)
                    acc[i][j] += sv[i] * wa[j];
        }
        __syncthreads();
    }

    #pragma unroll
    for (int i = 0; i < 2; i++) {
        float* op = Oc + (size_t)(t0 + ty * 2 + i) * HH + tx * 8;
        float4 o0 = {acc[i][0], acc[i][1], acc[i][2], acc[i][3]};
        float4 o1 = {acc[i][4], acc[i][5], acc[i][6], acc[i][7]};
        *(float4*)op       = o0;
        *(float4*)(op + 4) = o1;
    }
}

// ---------------------------------------------------------------------------
// Output: out = O Wo^T + bo. Gapped woT.
// ---------------------------------------------------------------------------
__global__ __launch_bounds__(256) void out_kernel(
    const float* __restrict__ O, const float* __restrict__ Wo,
    const float* __restrict__ bo, float* __restrict__ out)
{
    const int row0 = blockIdx.x * 64;
    const int d0   = blockIdx.y * 128;

    __shared__ float oT[32][68];
    __shared__ float woT[32][WPAD];

    const int tid = threadIdx.x;
    const int tx = tid & 15;
    const int ty = tid >> 4;
    const int gx = tx * 8 + ((tx >> 2) << 2);

    float acc[4][8];
    #pragma unroll
    for (int i = 0; i < 4; i++)
        #pragma unroll
        for (int j = 0; j < 8; j++) acc[i][j] = 0.f;

    for (int k0 = 0; k0 < HH; k0 += 32) {
        #pragma unroll
        for (int l = 0; l < 2; l++) {
            int f = tid + l * 256;
            int r = f >> 3;
            int cg = f & 7;
            float4 v = *(const float4*)(O + (size_t)(row0 + r) * HH + k0 + cg * 4);
            oT[cg*4+0][r] = v.x; oT[cg*4+1][r] = v.y;
            oT[cg*4+2][r] = v.z; oT[cg*4+3][r] = v.w;
        }
        #pragma unroll
        for (int l = 0; l < 4; l++) {
            int f = tid + l * 256;
            int d = f >> 3;
            int cg = f & 7;
            int gc = gcol(d);
            float4 v = *(const float4*)(Wo + (size_t)(d0 + d) * HH + k0 + cg * 4);
            woT[cg*4+0][gc] = v.x; woT[cg*4+1][gc] = v.y;
            woT[cg*4+2][gc] = v.z; woT[cg*4+3][gc] = v.w;
        }
        __syncthreads();
        #pragma unroll
        for (int kk = 0; kk < 32; kk++) {
            float4 ov = *(const float4*)&oT[kk][ty * 4];
            float4 w0 = *(const float4*)&woT[kk][gx];
            float4 w1 = *(const float4*)&woT[kk][gx + 4];
            float oa[4] = {ov.x, ov.y, ov.z, ov.w};
            float wa[8] = {w0.x, w0.y, w0.z, w0.w, w1.x, w1.y, w1.z, w1.w};
            #pragma unroll
            for (int i = 0; i < 4; i++)
                #pragma unroll
                for (int j = 0; j < 8; j++)
                    acc[i][j] += oa[i] * wa[j];
        }
        __syncthreads();
    }

    #pragma unroll
    for (int i = 0; i < 4; i++) {
        int row = row0 + ty * 4 + i;
        #pragma unroll
        for (int j = 0; j < 8; j++) acc[i][j] += bo[d0 + tx * 8 + j];
        float4 o0 = {acc[i][0], acc[i][1], acc[i][2], acc[i][3]};
        float4 o1 = {acc[i][4], acc[i][5], acc[i][6], acc[i][7]};
        *(float4*)(out + (size_t)row * DD + d0 + tx * 8)     = o0;
        *(float4*)(out + (size_t)row * DD + d0 + tx * 8 + 4) = o1;
    }
}

extern "C" void kernel_launch(void* const* d_in, const int* in_sizes, int n_in,
                              void* d_out, int out_size, void* d_ws, size_t ws_size,
                              hipStream_t stream) {
    const float* x  = (const float*)d_in[0];
    const float* Wq = (const float*)d_in[1];
    const float* bq = (const float*)d_in[2];
    const float* Wk = (const float*)d_in[3];
    const float* bk = (const float*)d_in[4];
    const float* Wv = (const float*)d_in[5];
    const float* bv = (const float*)d_in[6];
    const float* Wo = (const float*)d_in[7];
    const float* bo = (const float*)d_in[8];
    float* out = (float*)d_out;

    float* ws = (float*)d_ws;
    float* Q = ws;
    float* K = ws + (size_t)BT * HH;
    float* V = ws + (size_t)2 * BT * HH;
    float* O = ws + (size_t)3 * BT * HH;

    // d_out scratch (32 MB), float offsets (1<<20 floats = 4 MB each buf):
    //   Pp @0 (6 x 1M floats = 24 MB): proj3 -> combine, then DEAD.
    //   H @0, Bmat @1M, Ainv @2M, Z @3M, G @4M, Mpre @5M   (reuse Pp space)
    //   rn @6M floats (24 MB), Sarr just after.
    // All dead before out_kernel overwrites d_out.
    float* db   = (float*)d_out;
    float* Pp   = db;
    float* H    = db;
    float* Bmat = db + (size_t)1 * (1u << 20);
    float* Ainv = db + (size_t)2 * (1u << 20);
    float* Z    = db + (size_t)3 * (1u << 20);
    float* G    = db + (size_t)4 * (1u << 20);
    float* Mpre = db + (size_t)5 * (1u << 20);
    float* rn   = db + (size_t)6 * (1u << 20);
    float* Sarr = rn + BT;

    // 1. all three projections, k-split partials (768 blocks, 3/CU)
    dim3 pg(BT / 64, 6);
    proj3_kernel<<<pg, 256, 0, stream>>>(x, Wk, Wq, Wv, Pp);

    // 2. combine halves + bias; rn & s epilogues (memory-bound)
    combine_kernel<<<BT / 32, 256, 0, stream>>>(
        Pp, bk, bq, bv, K, Q, V, rn, Sarr);

    // 3. chunk-start inverse-Gram pipeline: H -> B_start -> A_start
    dim3 hg(NSCAN, 4);
    ugram_kernel<<<hg, 256, 0, stream>>>(K, rn, H);
    dim3 bp(BB, HH * HH / 256);
    bprefix_kernel<<<bp, 256, 0, stream>>>(H, Bmat);
    invert_kernel<<<NSCAN, 256, 0, stream>>>(Bmat, Ainv);

    // 4. 64 parallel chunk-scans
    scan_kernel<<<NSCAN, 512, 0, stream>>>(K, rn, Ainv, Z);

    // 5. phase-2 (alpha = s*z folded into staging) + output
    dim3 gg(NSCAN, 4);
    gram_kernel<<<gg, 256, 0, stream>>>(V, Z, Sarr, G);
    prefix_kernel<<<bp, 256, 0, stream>>>(G, Mpre);
    dim3 cg(NSCAN, 4);
    ochunk_kernel<<<cg, 256, 0, stream>>>(Q, Z, Sarr, V, Mpre, O);
    dim3 og(BT / 64, DD / 128);
    out_kernel<<<og, 256, 0, stream>>>(O, Wo, bo, out);
}